// Round 17
// baseline (385.639 us; speedup 1.0000x reference)
//
#include <hip/hip_runtime.h>
#include <hip/hip_bf16.h>
#include <stdint.h>

namespace {

constexpr int kT   = 2048;
constexpr int kHid = 2048;
constexpr int kH   = 16;
constexpr int kHK  = 8;
constexpr int kD   = 128;
constexpr int kFF  = 6144;

using bf16x8 = __attribute__((ext_vector_type(8))) short;
using f32x4  = __attribute__((ext_vector_type(4))) float;

__device__ __forceinline__ float bf2f(unsigned short u) {
    return __uint_as_float(((unsigned)u) << 16);
}
__device__ __forceinline__ unsigned short f2bf(float f) {
    unsigned u = __float_as_uint(f);
    return (unsigned short)((u + 0x7fffu + ((u >> 16) & 1u)) >> 16);
}
__device__ __forceinline__ void gload_lds16(const void* g, void* l) {
    __builtin_amdgcn_global_load_lds(
        (__attribute__((address_space(1))) void*)g,
        (__attribute__((address_space(3))) void*)l, 16, 0, 0);
}
__device__ __forceinline__ f32x4 mf(bf16x8 a, bf16x8 b, f32x4 c) {
    return __builtin_amdgcn_mfma_f32_16x16x32_bf16(a, b, c, 0, 0, 0);
}

// One-shot fp32->bf16 conversion of all seven weight matrices into the
// contiguous ws prefix. Region boundaries in float4 units:
//   wq [0,1048576) wk [..,1572864) wv [..,2097152) wo [..,3145728)
//   wg [..,6291456) wu [..,9437184) wd [..,12582912)
__global__ __launch_bounds__(256)
void cvt_all(const float* __restrict__ wq, const float* __restrict__ wk,
             const float* __restrict__ wv, const float* __restrict__ wo,
             const float* __restrict__ wg, const float* __restrict__ wu,
             const float* __restrict__ wd, ushort4* __restrict__ dst) {
    int i = blockIdx.x * 256 + threadIdx.x;
    if (i >= 12582912) return;
    const float4* src;
    int base;
    if (i < 3145728) {
        if (i < 1048576)      { src = (const float4*)wq; base = 0; }
        else if (i < 1572864) { src = (const float4*)wk; base = 1048576; }
        else if (i < 2097152) { src = (const float4*)wv; base = 1572864; }
        else                  { src = (const float4*)wo; base = 2097152; }
    } else {
        if (i < 6291456)      { src = (const float4*)wg; base = 3145728; }
        else if (i < 9437184) { src = (const float4*)wu; base = 6291456; }
        else                  { src = (const float4*)wd; base = 9437184; }
    }
    float4 v = src[i - base];
    ushort4 o;
    o.x = f2bf(v.x); o.y = f2bf(v.y); o.z = f2bf(v.z); o.w = f2bf(v.w);
    dst[i] = o;
}

// out = p0+p1+p2+p3+res (all fp32), vectorized x4
__global__ __launch_bounds__(256)
void reduce4(const float* __restrict__ p0, const float* __restrict__ p1,
             const float* __restrict__ p2, const float* __restrict__ p3,
             const float* __restrict__ res, float* __restrict__ out, int n4) {
    int i = blockIdx.x * 256 + threadIdx.x;
    if (i < n4) {
        float4 a = ((const float4*)p0)[i];
        float4 b = ((const float4*)p1)[i];
        float4 c = ((const float4*)p2)[i];
        float4 d = ((const float4*)p3)[i];
        float4 r = ((const float4*)res)[i];
        float4 o;
        o.x = a.x + b.x + c.x + d.x + r.x;
        o.y = a.y + b.y + c.y + d.y + r.y;
        o.z = a.z + b.z + c.z + d.z + r.z;
        o.w = a.w + b.w + c.w + d.w + r.w;
        ((float4*)out)[i] = o;
    }
}

// RMSNorm over HID=2048, fp32 in -> bf16 out. 1 block per row.
__global__ __launch_bounds__(256)
void rmsnorm_k(const float* __restrict__ x, const float* __restrict__ w,
               unsigned short* __restrict__ out) {
    const int row = blockIdx.x;
    const int tid = threadIdx.x;
    const float4* xr = (const float4*)(x + (size_t)row * kHid);
    float4 v0 = xr[tid];
    float4 v1 = xr[tid + 256];
    float ss = v0.x*v0.x + v0.y*v0.y + v0.z*v0.z + v0.w*v0.w
             + v1.x*v1.x + v1.y*v1.y + v1.z*v1.z + v1.w*v1.w;
#pragma unroll
    for (int m = 1; m < 64; m <<= 1) ss += __shfl_xor(ss, m);
    __shared__ float red[4];
    if ((tid & 63) == 0) red[tid >> 6] = ss;
    __syncthreads();
    float tot = red[0] + red[1] + red[2] + red[3];
    float rs = rsqrtf(tot * (1.0f / kHid) + 1e-6f);
    const float4* wv = (const float4*)w;
    float4 w0 = wv[tid], w1 = wv[tid + 256];
    ushort4 o0, o1;
    o0.x = f2bf(v0.x * rs * w0.x); o0.y = f2bf(v0.y * rs * w0.y);
    o0.z = f2bf(v0.z * rs * w0.z); o0.w = f2bf(v0.w * rs * w0.w);
    o1.x = f2bf(v1.x * rs * w1.x); o1.y = f2bf(v1.y * rs * w1.y);
    o1.z = f2bf(v1.z * rs * w1.z); o1.w = f2bf(v1.w * rs * w1.w);
    ushort4* orow = (ushort4*)(out + (size_t)row * kHid);
    orow[tid] = o0;
    orow[tid + 256] = o1;
}

// Fused: h = p0+p1+p2+p3+res -> H1; XN2 = rmsnorm(h)*w (bf16). 1 block/row.
__global__ __launch_bounds__(256)
void rmsnorm_red4(const float* __restrict__ p0, const float* __restrict__ p1,
                  const float* __restrict__ p2, const float* __restrict__ p3,
                  const float* __restrict__ res, const float* __restrict__ w,
                  float* __restrict__ H, unsigned short* __restrict__ out) {
    const int row = blockIdx.x;
    const int tid = threadIdx.x;
    const size_t base = (size_t)row * kHid;
    float4 v0, v1;
    {
        const float4* a = (const float4*)(p0 + base);
        const float4* b = (const float4*)(p1 + base);
        const float4* c = (const float4*)(p2 + base);
        const float4* d = (const float4*)(p3 + base);
        const float4* r = (const float4*)(res + base);
        float4 a0 = a[tid], b0 = b[tid], c0 = c[tid], d0 = d[tid], r0 = r[tid];
        v0.x = a0.x + b0.x + c0.x + d0.x + r0.x;
        v0.y = a0.y + b0.y + c0.y + d0.y + r0.y;
        v0.z = a0.z + b0.z + c0.z + d0.z + r0.z;
        v0.w = a0.w + b0.w + c0.w + d0.w + r0.w;
        float4 a1 = a[tid + 256], b1 = b[tid + 256], c1 = c[tid + 256],
               d1 = d[tid + 256], r1 = r[tid + 256];
        v1.x = a1.x + b1.x + c1.x + d1.x + r1.x;
        v1.y = a1.y + b1.y + c1.y + d1.y + r1.y;
        v1.z = a1.z + b1.z + c1.z + d1.z + r1.z;
        v1.w = a1.w + b1.w + c1.w + d1.w + r1.w;
    }
    ((float4*)(H + base))[tid] = v0;
    ((float4*)(H + base))[tid + 256] = v1;
    float ss = v0.x*v0.x + v0.y*v0.y + v0.z*v0.z + v0.w*v0.w
             + v1.x*v1.x + v1.y*v1.y + v1.z*v1.z + v1.w*v1.w;
#pragma unroll
    for (int m = 1; m < 64; m <<= 1) ss += __shfl_xor(ss, m);
    __shared__ float red[4];
    if ((tid & 63) == 0) red[tid >> 6] = ss;
    __syncthreads();
    float tot = red[0] + red[1] + red[2] + red[3];
    float rs = rsqrtf(tot * (1.0f / kHid) + 1e-6f);
    const float4* wv = (const float4*)w;
    float4 w0 = wv[tid], w1 = wv[tid + 256];
    ushort4 o0, o1;
    o0.x = f2bf(v0.x * rs * w0.x); o0.y = f2bf(v0.y * rs * w0.y);
    o0.z = f2bf(v0.z * rs * w0.z); o0.w = f2bf(v0.w * rs * w0.w);
    o1.x = f2bf(v1.x * rs * w1.x); o1.y = f2bf(v1.y * rs * w1.y);
    o1.z = f2bf(v1.z * rs * w1.z); o1.w = f2bf(v1.w * rs * w1.w);
    ushort4* orow = (ushort4*)(out + base);
    orow[tid] = o0;
    orow[tid + 256] = o1;
}

// -------- 256x256 8-phase GEMM (proven; EPI4 split-K partials) --------------
template <int EPI>
__global__ __launch_bounds__(512, 2)
void gemm256(const unsigned short* __restrict__ A,
             const unsigned short* __restrict__ B,
             void* __restrict__ C,
             int M, int N, int K, int KS,
             float* __restrict__ p0, float* __restrict__ p1,
             float* __restrict__ p2, float* __restrict__ p3) {
    __shared__ unsigned short smem[2][4][128 * 64];  // 128 KiB

    const int tid  = threadIdx.x;
    const int lane = tid & 63;
    const int l15  = lane & 15;
    const int g4   = lane >> 4;
    const int wid  = tid >> 6;
    const int wr   = wid >> 2;
    const int wc   = wid & 3;
    const int bm   = blockIdx.y * 256;
    const int bn   = blockIdx.x * 256;
    const int kb   = (EPI == 4) ? blockIdx.z * KS : 0;
    const int NT   = ((EPI == 4) ? KS : K) >> 6;
    const int NI   = NT >> 1;

    f32x4 acc[8][4] = {};

    auto stage = [&](int b, int reg, int t) {
        const unsigned short* Base = (reg < 2) ? A : B;
        const int br = ((reg < 2) ? bm : bn) + (reg & 1) * 128;
#pragma unroll
        for (int i = 0; i < 2; ++i) {
            int ch   = tid + i * 512;
            int row  = ch >> 3;
            int slot = (ch & 7) ^ (row & 7);
            gload_lds16(Base + (size_t)(br + row) * K + kb + t * 64 + slot * 8,
                        (char*)&smem[b][reg][0] + ch * 16);
        }
    };
    auto rdA = [&](int b, int m, int ks) {
        int row = m * 16 + l15;
        return *(const bf16x8*)((const char*)&smem[b][wr][0]
               + row * 128 + (((ks * 4 + g4) ^ (row & 7)) * 16));
    };
    auto rdB = [&](int b, int n, int ks) {
        int row = wc * 64 + n * 16 + l15;
        return *(const bf16x8*)((const char*)&smem[b][2 + (row >> 7)][0]
               + (row & 127) * 128 + (((ks * 4 + g4) ^ (row & 7)) * 16));
    };

    stage(0, 2, 0); stage(0, 3, 0); stage(0, 0, 0); stage(0, 1, 0);
    stage(1, 2, 1); stage(1, 3, 1); stage(1, 0, 1);
    asm volatile("s_waitcnt vmcnt(6)" ::: "memory");
    __builtin_amdgcn_s_barrier();

    for (int i = 0; i < NI; ++i) {
        const int e  = 2 * i;
        const int o  = e + 1;
        const bool pf = (e + 2 < NT);
        bf16x8 af[4][2], bfr[4][2];

#pragma unroll
        for (int m = 0; m < 4; ++m) { af[m][0] = rdA(0, m, 0); af[m][1] = rdA(0, m, 1); }
#pragma unroll
        for (int n = 0; n < 4; ++n) { bfr[n][0] = rdB(0, n, 0); bfr[n][1] = rdB(0, n, 1); }
        stage(1, 1, o);
        __builtin_amdgcn_s_barrier();
        asm volatile("s_waitcnt lgkmcnt(0)" ::: "memory");
        __builtin_amdgcn_sched_barrier(0);
        __builtin_amdgcn_s_setprio(1);
#pragma unroll
        for (int m = 0; m < 4; ++m)
#pragma unroll
            for (int n = 0; n < 2; ++n) {
                acc[m][n] = mf(af[m][0], bfr[n][0], acc[m][n]);
                acc[m][n] = mf(af[m][1], bfr[n][1], acc[m][n]);
            }
        __builtin_amdgcn_s_setprio(0);
        __builtin_amdgcn_s_barrier();

        if (pf) stage(0, 2, e + 2);
        __builtin_amdgcn_s_barrier();
        __builtin_amdgcn_s_setprio(1);
#pragma unroll
        for (int m = 0; m < 4; ++m)
#pragma unroll
            for (int n = 2; n < 4; ++n) {
                acc[m][n] = mf(af[m][0], bfr[n][0], acc[m][n]);
                acc[m][n] = mf(af[m][1], bfr[n][1], acc[m][n]);
            }
        __builtin_amdgcn_s_setprio(0);
        __builtin_amdgcn_s_barrier();

#pragma unroll
        for (int m = 0; m < 4; ++m) { af[m][0] = rdA(0, 4 + m, 0); af[m][1] = rdA(0, 4 + m, 1); }
        if (pf) stage(0, 3, e + 2);
        __builtin_amdgcn_s_barrier();
        asm volatile("s_waitcnt lgkmcnt(0)" ::: "memory");
        __builtin_amdgcn_sched_barrier(0);
        __builtin_amdgcn_s_setprio(1);
#pragma unroll
        for (int m = 0; m < 4; ++m)
#pragma unroll
            for (int n = 0; n < 2; ++n) {
                acc[4 + m][n] = mf(af[m][0], bfr[n][0], acc[4 + m][n]);
                acc[4 + m][n] = mf(af[m][1], bfr[n][1], acc[4 + m][n]);
            }
        __builtin_amdgcn_s_setprio(0);
        __builtin_amdgcn_s_barrier();

        if (pf) stage(0, 0, e + 2);
        __builtin_amdgcn_s_barrier();
        __builtin_amdgcn_s_setprio(1);
#pragma unroll
        for (int m = 0; m < 4; ++m)
#pragma unroll
            for (int n = 2; n < 4; ++n) {
                acc[4 + m][n] = mf(af[m][0], bfr[n][0], acc[4 + m][n]);
                acc[4 + m][n] = mf(af[m][1], bfr[n][1], acc[4 + m][n]);
            }
        __builtin_amdgcn_s_setprio(0);
        if (pf) asm volatile("s_waitcnt vmcnt(6)" ::: "memory");
        else    asm volatile("s_waitcnt vmcnt(0)" ::: "memory");
        __builtin_amdgcn_s_barrier();

#pragma unroll
        for (int m = 0; m < 4; ++m) { af[m][0] = rdA(1, m, 0); af[m][1] = rdA(1, m, 1); }
#pragma unroll
        for (int n = 0; n < 4; ++n) { bfr[n][0] = rdB(1, n, 0); bfr[n][1] = rdB(1, n, 1); }
        if (pf) stage(0, 1, e + 2);
        __builtin_amdgcn_s_barrier();
        asm volatile("s_waitcnt lgkmcnt(0)" ::: "memory");
        __builtin_amdgcn_sched_barrier(0);
        __builtin_amdgcn_s_setprio(1);
#pragma unroll
        for (int m = 0; m < 4; ++m)
#pragma unroll
            for (int n = 0; n < 2; ++n) {
                acc[m][n] = mf(af[m][0], bfr[n][0], acc[m][n]);
                acc[m][n] = mf(af[m][1], bfr[n][1], acc[m][n]);
            }
        __builtin_amdgcn_s_setprio(0);
        __builtin_amdgcn_s_barrier();

        if (pf) stage(1, 2, o + 2);
        __builtin_amdgcn_s_barrier();
        __builtin_amdgcn_s_setprio(1);
#pragma unroll
        for (int m = 0; m < 4; ++m)
#pragma unroll
            for (int n = 2; n < 4; ++n) {
                acc[m][n] = mf(af[m][0], bfr[n][0], acc[m][n]);
                acc[m][n] = mf(af[m][1], bfr[n][1], acc[m][n]);
            }
        __builtin_amdgcn_s_setprio(0);
        __builtin_amdgcn_s_barrier();

#pragma unroll
        for (int m = 0; m < 4; ++m) { af[m][0] = rdA(1, 4 + m, 0); af[m][1] = rdA(1, 4 + m, 1); }
        if (pf) stage(1, 3, o + 2);
        __builtin_amdgcn_s_barrier();
        asm volatile("s_waitcnt lgkmcnt(0)" ::: "memory");
        __builtin_amdgcn_sched_barrier(0);
        __builtin_amdgcn_s_setprio(1);
#pragma unroll
        for (int m = 0; m < 4; ++m)
#pragma unroll
            for (int n = 0; n < 2; ++n) {
                acc[4 + m][n] = mf(af[m][0], bfr[n][0], acc[4 + m][n]);
                acc[4 + m][n] = mf(af[m][1], bfr[n][1], acc[4 + m][n]);
            }
        __builtin_amdgcn_s_setprio(0);
        __builtin_amdgcn_s_barrier();

        if (pf) stage(1, 0, o + 2);
        __builtin_amdgcn_s_barrier();
        __builtin_amdgcn_s_setprio(1);
#pragma unroll
        for (int m = 0; m < 4; ++m)
#pragma unroll
            for (int n = 2; n < 4; ++n) {
                acc[4 + m][n] = mf(af[m][0], bfr[n][0], acc[4 + m][n]);
                acc[4 + m][n] = mf(af[m][1], bfr[n][1], acc[4 + m][n]);
            }
        __builtin_amdgcn_s_setprio(0);
        if (pf) asm volatile("s_waitcnt vmcnt(6)" ::: "memory");
        __builtin_amdgcn_s_barrier();
    }

    float* P = nullptr;
    if (EPI == 4) {
        const int z = blockIdx.z;
        P = (z == 0) ? p0 : (z == 1) ? p1 : (z == 2) ? p2 : p3;
    }
#pragma unroll
    for (int m = 0; m < 8; ++m) {
#pragma unroll
        for (int n = 0; n < 4; ++n) {
            int row = bm + wr * 128 + m * 16 + g4 * 4;
            int col = bn + wc * 64 + n * 16 + l15;
#pragma unroll
            for (int r = 0; r < 4; ++r) {
                size_t idx = (size_t)(row + r) * N + col;
                float v = acc[m][n][r];
                if (EPI == 0) ((float*)C)[idx] = v;
                else          P[idx] = v;
            }
        }
    }
}

// -------- 128M x 256N 8-phase GEMM (proven; used for QKV) ------------------
// EPI: 0 = fp32 store, 1 = bf16 store, 4 = split-K2 fp32 partials.
template <int EPI>
__global__ __launch_bounds__(512, 2)
void gemm128(const unsigned short* __restrict__ A,
             const unsigned short* __restrict__ B,
             void* __restrict__ C,
             int M, int N, int K, int KS,
             float* __restrict__ p0, float* __restrict__ p1) {
    __shared__ unsigned short smem[2][3][128 * 64];  // 96 KiB

    const int tid  = threadIdx.x;
    const int lane = tid & 63;
    const int l15  = lane & 15;
    const int g4   = lane >> 4;
    const int wid  = tid >> 6;
    const int wr   = wid >> 2;
    const int wc   = wid & 3;
    const int bm   = blockIdx.y * 128;
    const int bn   = blockIdx.x * 256;
    const int kb   = (EPI == 4) ? blockIdx.z * KS : 0;
    const int NT   = ((EPI == 4) ? KS : K) >> 6;
    const int NI   = NT >> 1;

    f32x4 acc[4][4] = {};

    auto stage = [&](int b, int reg, int t) {
        const unsigned short* Base = (reg == 0) ? A : B;
        const int br = (reg == 0) ? bm : bn + (reg - 1) * 128;
#pragma unroll
        for (int i = 0; i < 2; ++i) {
            int ch   = tid + i * 512;
            int row  = ch >> 3;
            int slot = (ch & 7) ^ (row & 7);
            gload_lds16(Base + (size_t)(br + row) * K + kb + t * 64 + slot * 8,
                        (char*)&smem[b][reg][0] + ch * 16);
        }
    };
    auto rdA = [&](int b, int m, int ks) {
        int row = wr * 64 + m * 16 + l15;
        return *(const bf16x8*)((const char*)&smem[b][0][0]
               + row * 128 + (((ks * 4 + g4) ^ (row & 7)) * 16));
    };
    auto rdB = [&](int b, int n, int ks) {
        int row = wc * 64 + n * 16 + l15;
        return *(const bf16x8*)((const char*)&smem[b][1 + (row >> 7)][0]
               + (row & 127) * 128 + (((ks * 4 + g4) ^ (row & 7)) * 16));
    };

    stage(0, 1, 0); stage(0, 2, 0); stage(0, 0, 0);
    stage(1, 1, 1); stage(1, 2, 1);
    asm volatile("s_waitcnt vmcnt(4)" ::: "memory");
    __builtin_amdgcn_s_barrier();

    for (int i = 0; i < NI; ++i) {
        const int e  = 2 * i;
        const int o  = e + 1;
        const bool pf = (e + 2 < NT);
        bf16x8 af[4][2], bfr[4][2];

#pragma unroll
        for (int m = 0; m < 4; ++m) { af[m][0] = rdA(0, m, 0); af[m][1] = rdA(0, m, 1); }
#pragma unroll
        for (int n = 0; n < 4; ++n) { bfr[n][0] = rdB(0, n, 0); bfr[n][1] = rdB(0, n, 1); }
        stage(1, 0, o);
        __builtin_amdgcn_s_barrier();
        asm volatile("s_waitcnt lgkmcnt(0)" ::: "memory");
        __builtin_amdgcn_sched_barrier(0);
        __builtin_amdgcn_s_setprio(1);
#pragma unroll
        for (int m = 0; m < 4; ++m) {
            acc[m][0] = mf(af[m][0], bfr[0][0], acc[m][0]);
            acc[m][0] = mf(af[m][1], bfr[0][1], acc[m][0]);
        }
        __builtin_amdgcn_s_setprio(0);
        __builtin_amdgcn_s_barrier();

        if (pf) stage(0, 1, e + 2);
        __builtin_amdgcn_s_barrier();
        __builtin_amdgcn_s_setprio(1);
#pragma unroll
        for (int m = 0; m < 4; ++m) {
            acc[m][1] = mf(af[m][0], bfr[1][0], acc[m][1]);
            acc[m][1] = mf(af[m][1], bfr[1][1], acc[m][1]);
        }
        __builtin_amdgcn_s_setprio(0);
        __builtin_amdgcn_s_barrier();

        if (pf) stage(0, 2, e + 2);
        __builtin_amdgcn_s_barrier();
        __builtin_amdgcn_s_setprio(1);
#pragma unroll
        for (int m = 0; m < 4; ++m) {
            acc[m][2] = mf(af[m][0], bfr[2][0], acc[m][2]);
            acc[m][2] = mf(af[m][1], bfr[2][1], acc[m][2]);
        }
        __builtin_amdgcn_s_setprio(0);
        __builtin_amdgcn_s_barrier();

        __builtin_amdgcn_s_setprio(1);
#pragma unroll
        for (int m = 0; m < 4; ++m) {
            acc[m][3] = mf(af[m][0], bfr[3][0], acc[m][3]);
            acc[m][3] = mf(af[m][1], bfr[3][1], acc[m][3]);
        }
        __builtin_amdgcn_s_setprio(0);
        if (pf) asm volatile("s_waitcnt vmcnt(4)" ::: "memory");
        else    asm volatile("s_waitcnt vmcnt(0)" ::: "memory");
        __builtin_amdgcn_s_barrier();

#pragma unroll
        for (int m = 0; m < 4; ++m) { af[m][0] = rdA(1, m, 0); af[m][1] = rdA(1, m, 1); }
#pragma unroll
        for (int n = 0; n < 4; ++n) { bfr[n][0] = rdB(1, n, 0); bfr[n][1] = rdB(1, n, 1); }
        if (pf) stage(0, 0, e + 2);
        __builtin_amdgcn_s_barrier();
        asm volatile("s_waitcnt lgkmcnt(0)" ::: "memory");
        __builtin_amdgcn_sched_barrier(0);
        __builtin_amdgcn_s_setprio(1);
#pragma unroll
        for (int m = 0; m < 4; ++m) {
            acc[m][0] = mf(af[m][0], bfr[0][0], acc[m][0]);
            acc[m][0] = mf(af[m][1], bfr[0][1], acc[m][0]);
        }
        __builtin_amdgcn_s_setprio(0);
        __builtin_amdgcn_s_barrier();

        if (pf) stage(1, 1, o + 2);
        __builtin_amdgcn_s_barrier();
        __builtin_amdgcn_s_setprio(1);
#pragma unroll
        for (int m = 0; m < 4; ++m) {
            acc[m][1] = mf(af[m][0], bfr[1][0], acc[m][1]);
            acc[m][1] = mf(af[m][1], bfr[1][1], acc[m][1]);
        }
        __builtin_amdgcn_s_setprio(0);
        __builtin_amdgcn_s_barrier();

        if (pf) stage(1, 2, o + 2);
        __builtin_amdgcn_s_barrier();
        __builtin_amdgcn_s_setprio(1);
#pragma unroll
        for (int m = 0; m < 4; ++m) {
            acc[m][2] = mf(af[m][0], bfr[2][0], acc[m][2]);
            acc[m][2] = mf(af[m][1], bfr[2][1], acc[m][2]);
        }
        __builtin_amdgcn_s_setprio(0);
        __builtin_amdgcn_s_barrier();

        __builtin_amdgcn_s_setprio(1);
#pragma unroll
        for (int m = 0; m < 4; ++m) {
            acc[m][3] = mf(af[m][0], bfr[3][0], acc[m][3]);
            acc[m][3] = mf(af[m][1], bfr[3][1], acc[m][3]);
        }
        __builtin_amdgcn_s_setprio(0);
        if (pf) asm volatile("s_waitcnt vmcnt(4)" ::: "memory");
        __builtin_amdgcn_s_barrier();
    }

    float* P = nullptr;
    if (EPI == 4) P = (blockIdx.z == 0) ? p0 : p1;
#pragma unroll
    for (int m = 0; m < 4; ++m) {
#pragma unroll
        for (int n = 0; n < 4; ++n) {
            int row = bm + wr * 64 + m * 16 + g4 * 4;
            int col = bn + wc * 64 + n * 16 + l15;
#pragma unroll
            for (int r = 0; r < 4; ++r) {
                size_t idx = (size_t)(row + r) * N + col;
                float v = acc[m][n][r];
                if (EPI == 0)      ((float*)C)[idx] = v;
                else if (EPI == 1) ((unsigned short*)C)[idx] = f2bf(v);
                else               P[idx] = v;
            }
        }
    }
}

// -------- fused gate+up GEMM v2: tile 256M x 96FF (proven R11) -------------
__global__ __launch_bounds__(512, 2)
void gemm_gu(const unsigned short* __restrict__ A,
             const unsigned short* __restrict__ WGp,
             const unsigned short* __restrict__ WUp,
             unsigned short* __restrict__ OUT) {
    __shared__ unsigned short smem[2][28672];  // 112 KiB

    const int tid  = threadIdx.x;
    const int lane = tid & 63;
    const int l15  = lane & 15;
    const int g4   = lane >> 4;
    const int wid  = tid >> 6;   // 0..7
    const int wr   = wid >> 1;   // 0..3  (64-row slice)
    const int wc   = wid & 1;    // 0..1  (48-col slice)
    const int bm   = blockIdx.y * 256;
    const int bn   = blockIdx.x * 96;
    const int K    = kHid;
    const int NT   = K >> 6;     // 32
    const int NI   = NT >> 1;

    f32x4 accg[4][3] = {};
    f32x4 accu[4][3] = {};

    constexpr int OFF_A0 = 0;
    constexpr int OFF_A1 = 16384;
    constexpr int OFF_GU = 32768;

    auto stage_a = [&](int b, int half, int t) {
#pragma unroll
        for (int i = 0; i < 2; ++i) {
            int ch   = tid + i * 512;
            int row  = ch >> 3;
            int slot = (ch & 7) ^ (row & 7);
            gload_lds16(A + (size_t)(bm + half * 128 + row) * K + t * 64 + slot * 8,
                        (char*)&smem[b][0] + (half ? OFF_A1 : OFF_A0) + ch * 16);
        }
    };
    auto stage_gu = [&](int b, int t) {
#pragma unroll
        for (int i = 0; i < 3; ++i) {
            int ch   = tid + i * 512;
            int row  = ch >> 3;
            int slot = (ch & 7) ^ (row & 7);
            const unsigned short* Base = (row >= 96) ? WUp : WGp;
            int srow = bn + (row >= 96 ? row - 96 : row);
            gload_lds16(Base + (size_t)srow * K + t * 64 + slot * 8,
                        (char*)&smem[b][0] + OFF_GU + ch * 16);
        }
    };
    auto rdA = [&](int b, int m, int ks) {
        int rt  = wr * 64 + m * 16 + l15;
        int row = rt & 127;
        return *(const bf16x8*)((const char*)&smem[b][0]
               + (rt >> 7 ? OFF_A1 : OFF_A0)
               + row * 128 + (((ks * 4 + g4) ^ (row & 7)) * 16));
    };
    auto rdG = [&](int b, int n, int ks) {
        int row = wc * 48 + n * 16 + l15;
        return *(const bf16x8*)((const char*)&smem[b][0] + OFF_GU
               + row * 128 + (((ks * 4 + g4) ^ (row & 7)) * 16));
    };
    auto rdU = [&](int b, int n, int ks) {
        int row = 96 + wc * 48 + n * 16 + l15;
        return *(const bf16x8*)((const char*)&smem[b][0] + OFF_GU
               + row * 128 + (((ks * 4 + g4) ^ (row & 7)) * 16));
    };

    stage_a(0, 0, 0); stage_a(0, 1, 0); stage_gu(0, 0);
    stage_a(1, 0, 1); stage_a(1, 1, 1);
    asm volatile("s_waitcnt vmcnt(4)" ::: "memory");
    __builtin_amdgcn_s_barrier();

    for (int i = 0; i < NI; ++i) {
        const int e  = 2 * i;
        const int o  = e + 1;
        const bool pf = (e + 2 < NT);
        bf16x8 af[4][2], bg[3][2], bu[3][2];

#pragma unroll
        for (int m = 0; m < 4; ++m) { af[m][0] = rdA(0, m, 0); af[m][1] = rdA(0, m, 1); }
#pragma unroll
        for (int n = 0; n < 3; ++n) { bg[n][0] = rdG(0, n, 0); bg[n][1] = rdG(0, n, 1); }
        stage_gu(1, o);
        __builtin_amdgcn_s_barrier();
        asm volatile("s_waitcnt lgkmcnt(0)" ::: "memory");
        __builtin_amdgcn_sched_barrier(0);
        __builtin_amdgcn_s_setprio(1);
#pragma unroll
        for (int m = 0; m < 4; ++m)
#pragma unroll
            for (int n = 0; n < 3; ++n)
                accg[m][n] = mf(af[m][0], bg[n][0], accg[m][n]);
        __builtin_amdgcn_s_setprio(0);
        __builtin_amdgcn_s_barrier();

        if (pf) stage_a(0, 0, e + 2);
        __builtin_amdgcn_s_barrier();
        __builtin_amdgcn_s_setprio(1);
#pragma unroll
        for (int m = 0; m < 4; ++m)
#pragma unroll
            for (int n = 0; n < 3; ++n)
                accg[m][n] = mf(af[m][1], bg[n][1], accg[m][n]);
        __builtin_amdgcn_s_setprio(0);
        __builtin_amdgcn_s_barrier();

#pragma unroll
        for (int n = 0; n < 3; ++n) { bu[n][0] = rdU(0, n, 0); bu[n][1] = rdU(0, n, 1); }
        if (pf) stage_a(0, 1, e + 2);
        __builtin_amdgcn_s_barrier();
        asm volatile("s_waitcnt lgkmcnt(0)" ::: "memory");
        __builtin_amdgcn_sched_barrier(0);
        __builtin_amdgcn_s_setprio(1);
#pragma unroll
        for (int m = 0; m < 4; ++m)
#pragma unroll
            for (int n = 0; n < 3; ++n)
                accu[m][n] = mf(af[m][0], bu[n][0], accu[m][n]);
        __builtin_amdgcn_s_setprio(0);
        __builtin_amdgcn_s_barrier();

        if (pf) stage_gu(0, e + 2);
        __builtin_amdgcn_s_barrier();
        __builtin_amdgcn_s_setprio(1);
#pragma unroll
        for (int m = 0; m < 4; ++m)
#pragma unroll
            for (int n = 0; n < 3; ++n)
                accu[m][n] = mf(af[m][1], bu[n][1], accu[m][n]);
        __builtin_amdgcn_s_setprio(0);
        if (pf) asm volatile("s_waitcnt vmcnt(7)" ::: "memory");
        else    asm volatile("s_waitcnt vmcnt(0)" ::: "memory");
        __builtin_amdgcn_s_barrier();

#pragma unroll
        for (int m = 0; m < 4; ++m) { af[m][0] = rdA(1, m, 0); af[m][1] = rdA(1, m, 1); }
#pragma unroll
        for (int n = 0; n < 3; ++n) { bg[n][0] = rdG(1, n, 0); bg[n][1] = rdG(1, n, 1); }
        __builtin_amdgcn_s_barrier();
        asm volatile("s_waitcnt lgkmcnt(0)" ::: "memory");
        __builtin_amdgcn_sched_barrier(0);
        __builtin_amdgcn_s_setprio(1);
#pragma unroll
        for (int m = 0; m < 4; ++m)
#pragma unroll
            for (int n = 0; n < 3; ++n)
                accg[m][n] = mf(af[m][0], bg[n][0], accg[m][n]);
        __builtin_amdgcn_s_setprio(0);
        __builtin_amdgcn_s_barrier();

        if (pf) stage_a(1, 0, o + 2);
        __builtin_amdgcn_s_barrier();
        __builtin_amdgcn_s_setprio(1);
#pragma unroll
        for (int m = 0; m < 4; ++m)
#pragma unroll
            for (int n = 0; n < 3; ++n)
                accg[m][n] = mf(af[m][1], bg[n][1], accg[m][n]);
        __builtin_amdgcn_s_setprio(0);
        __builtin_amdgcn_s_barrier();

#pragma unroll
        for (int n = 0; n < 3; ++n) { bu[n][0] = rdU(1, n, 0); bu[n][1] = rdU(1, n, 1); }
        if (pf) stage_a(1, 1, o + 2);
        __builtin_amdgcn_s_barrier();
        asm volatile("s_waitcnt lgkmcnt(0)" ::: "memory");
        __builtin_amdgcn_sched_barrier(0);
        __builtin_amdgcn_s_setprio(1);
#pragma unroll
        for (int m = 0; m < 4; ++m)
#pragma unroll
            for (int n = 0; n < 3; ++n)
                accu[m][n] = mf(af[m][0], bu[n][0], accu[m][n]);
        __builtin_amdgcn_s_setprio(0);
        __builtin_amdgcn_s_barrier();

        __builtin_amdgcn_s_setprio(1);
#pragma unroll
        for (int m = 0; m < 4; ++m)
#pragma unroll
            for (int n = 0; n < 3; ++n)
                accu[m][n] = mf(af[m][1], bu[n][1], accu[m][n]);
        __builtin_amdgcn_s_setprio(0);
        if (pf) asm volatile("s_waitcnt vmcnt(4)" ::: "memory");
        __builtin_amdgcn_s_barrier();
    }

#pragma unroll
    for (int m = 0; m < 4; ++m) {
#pragma unroll
        for (int n = 0; n < 3; ++n) {
            int row = bm + wr * 64 + m * 16 + g4 * 4;
            int col = bn + wc * 48 + n * 16 + l15;
#pragma unroll
            for (int r = 0; r < 4; ++r) {
                float g = accg[m][n][r];
                float u = accu[m][n][r];
                OUT[(size_t)(row + r) * kFF + col] = f2bf(g / (1.0f + __expf(-g)) * u);
            }
        }
    }
}

// Fused per-head RMSNorm (D=128) + RoPE for q and k. Reads bf16 QKV.
__global__ __launch_bounds__(256)
void qknorm_rope(const unsigned short* __restrict__ qkv, const int* __restrict__ positions,
                 const float* __restrict__ qnw, const float* __restrict__ knw,
                 unsigned short* __restrict__ Qo, unsigned short* __restrict__ Ko) {
    const int t    = blockIdx.x;
    const int j    = blockIdx.y * 4 + (threadIdx.x >> 6);  // 0..23
    const int lane = threadIdx.x & 63;
    const unsigned short* src = qkv + (size_t)t * 4096 + j * 128;
    float x1 = bf2f(src[lane]);
    float x2 = bf2f(src[lane + 64]);
    float ss = x1 * x1 + x2 * x2;
#pragma unroll
    for (int m = 1; m < 64; m <<= 1) ss += __shfl_xor(ss, m);
    float rs = rsqrtf(ss * (1.0f / 128.0f) + 1e-6f);
    const float* w = (j < 16) ? qnw : knw;
    float n1 = x1 * rs * w[lane];
    float n2 = x2 * rs * w[lane + 64];
    float inv = powf(1.0e6f, -(float)lane * (1.0f / 64.0f));
    float fr = (float)positions[t] * inv;
    float sn, cs;
    sincosf(fr, &sn, &cs);
    float o1 = n1 * cs - n2 * sn;
    float o2 = n2 * cs + n1 * sn;
    if (j < 16) {
        unsigned short* d = Qo + (size_t)t * (kH * kD) + j * kD;
        d[lane] = f2bf(o1);
        d[lane + 64] = f2bf(o2);
    } else {
        unsigned short* d = Ko + (size_t)t * (kHK * kD) + (j - 16) * kD;
        d[lane] = f2bf(o1);
        d[lane + 64] = f2bf(o2);
    }
}

// V transpose: bf16 qkv v-part -> Vt bf16 (1024 x T), pure pass-through.
__global__ __launch_bounds__(256)
void vtrans(const unsigned short* __restrict__ qkv, unsigned short* __restrict__ Vt) {
    __shared__ unsigned short tile[32][33];
    const int t0 = blockIdx.x * 32;
    const int d0 = blockIdx.y * 32;
    const int tc = threadIdx.x & 31;
    const int tr = threadIdx.x >> 5;  // 0..7
#pragma unroll
    for (int i = 0; i < 4; ++i) {
        int trow = tr + i * 8;
        tile[trow][tc] = qkv[(size_t)(t0 + trow) * 4096 + 3072 + d0 + tc];
    }
    __syncthreads();
#pragma unroll
    for (int i = 0; i < 4; ++i) {
        int drow = tr + i * 8;
        Vt[(size_t)(d0 + drow) * kT + t0 + tc] = tile[tc][drow];
    }
}

// Causal flash attention v5: kv-split-2 with in-kernel merge (proven R8-R11).
__global__ __launch_bounds__(512, 4)
void attn_fwd5(const unsigned short* __restrict__ Q,   // T x (H*D)
               const unsigned short* __restrict__ Kc,  // T x (HK*D)
               const unsigned short* __restrict__ Vt,  // (HK*D) x T
               unsigned short* __restrict__ O) {       // T x (H*D)
    __shared__ unsigned short Kb[2][64 * 128];
    __shared__ unsigned short Vb[2][128 * 64];
    __shared__ float MergeML[4][2][64];

    const int tid  = threadIdx.x;
    const int lane = tid & 63;
    const int l15  = lane & 15;
    const int g4   = lane >> 4;
    const int wid  = tid >> 6;       // 0..7
    const int s    = wid & 1;        // kv split
    const int grp  = wid >> 1;       // 0..3 = (hs, qsub)
    const int hs   = grp >> 1;
    const int qsub = grp & 1;
    const int hkk  = blockIdx.x;
    const int h    = hkk * 2 + hs;
    const int nby  = gridDim.y;
    const int by   = blockIdx.y;
    const int byl  = (by & 1) ? (nby - 1 - (by >> 1)) : (by >> 1);
    const int q0   = byl * 32 + qsub * 16;
    const int nch  = byl / 2 + 1;
    const int c0   = (nch + 1) >> 1;
    const int myn  = s ? (nch - c0) : c0;
    const int qi   = q0 + l15;
    const int vt   = grp * 64 + lane;

    const int addrA = ((g4 & 1) * 32 + l15) * 4;
    const int addrB = addrA + 64;
    const int addrQ = g4 * 80;
    const bool hb   = (g4 >> 1) != 0;

    bf16x8 qf[4];
#pragma unroll
    for (int ks = 0; ks < 4; ++ks)
        qf[ks] = *(const bf16x8*)(Q + (size_t)(q0 + l15) * (kH * kD) + h * kD + ks * 32 + g4 * 8);

    f32x4 oacc[8] = {};
    float mrun = -3e38f, lrun = 0.f;
    const float scale = 0.08838834764831845f;  // 1/sqrt(128)

    auto stage = [&](int kv0) {
#pragma unroll
        for (int i = 0; i < 4; ++i) {
            int ch  = vt + i * 256;
            int row = ch >> 4;
            int c16 = ch & 15;
            gload_lds16(Kc + (size_t)(kv0 + row) * (kHK * kD) + hkk * kD
                            + ((c16 ^ (row & 7)) * 8),
                        (char*)Kb[s] + ch * 16);
        }
#pragma unroll
        for (int i = 0; i < 4; ++i) {
            int ch  = vt + i * 256;
            int row = ch >> 3;
            int c8  = ch & 7;
            gload_lds16(Vt + (size_t)(hkk * kD + row) * kT + kv0
                            + ((c8 ^ (row & 7)) * 8),
                        (char*)Vb[s] + ch * 16);
        }
    };

    for (int c = 0; c < c0; ++c) {
        const bool act = c < myn;
        const int kv0 = (s ? (c0 + c) : c) * 64;
        if (act) stage(kv0);
        asm volatile("s_waitcnt vmcnt(0)" ::: "memory");
        __builtin_amdgcn_s_barrier();
        __builtin_amdgcn_sched_barrier(0);

        if (act) {
            f32x4 sa[4] = {};
            __builtin_amdgcn_s_setprio(1);
#pragma unroll
            for (int hh = 0; hh < 4; ++hh) {
                const int row = hh * 16 + l15;
#pragma unroll
                for (int ks = 0; ks < 4; ++ks) {
                    bf16x8 kf = *(const bf16x8*)((const char*)Kb[s]
                                  + row * 256 + (((ks * 4 + g4) ^ (row & 7)) * 16));
                    sa[hh] = mf(kf, qf[ks], sa[hh]);
                }
            }
            __builtin_amdgcn_s_setprio(0);

            float sv[4][4];
#pragma unroll
            for (int hh = 0; hh < 4; ++hh)
#pragma unroll
                for (int r = 0; r < 4; ++r)
                    sv[hh][r] = sa[hh][r] * scale;
            if (kv0 + 63 > q0) {
#pragma unroll
                for (int hh = 0; hh < 4; ++hh)
#pragma unroll
                    for (int r = 0; r < 4; ++r) {
                        int ki = kv0 + hh * 16 + g4 * 4 + r;
                        if (ki > qi) sv[hh][r] = -3e38f;
                    }
            }

            float m16;
            {
                float a = fmaxf(fmaxf(sv[0][0], sv[0][1]), fmaxf(sv[0][2], sv[0][3]));
                float b2 = fmaxf(fmaxf(sv[1][0], sv[1][1]), fmaxf(sv[1][2], sv[1][3]));
                float c2 = fmaxf(fmaxf(sv[2][0], sv[2][1]), fmaxf(sv[2][2], sv[2][3]));
                float d2 = fmaxf(fmaxf(sv[3][0], sv[3][1]), fmaxf(sv[3][2], sv[3][3]));
                m16 = fmaxf(fmaxf(a, b2), fmaxf(c2, d2));
            }
            m16 = fmaxf(m16, __shfl_xor(m16, 16));
            m16 = fmaxf(m16, __shfl_xor(m16, 32));

            if (__any(m16 > mrun)) {
                float mnew = fmaxf(mrun, m16);
                float corr = __expf(mrun - mnew);
                mrun = mnew;
                lrun *= corr;
                float cr[4];
#pragma unroll
                for (int r = 0; r < 4; ++r)
                    cr[r] = __int_as_float(__builtin_amdgcn_ds_bpermute(
                                addrQ + 4 * r, __float_as_int(corr)));
#pragma unroll
                for (int c2 = 0; c2 < 8; ++c2)
#pragma unroll
                    for (int r = 0; r < 4; ++r)
                        oacc[c2][r] *= cr[r];
            }

            float p[4][4];
            float ps = 0.f;
#pragma unroll
            for (int hh = 0; hh < 4; ++hh)
#pragma unroll
                for (int r = 0; r < 4; ++r) {
                    float pe = __expf(sv[hh][r] - mrun);
                    p[hh][r] = pe;
                    ps += pe;
                }
            ps += __shfl_xor(ps, 16);
            ps += __shfl_xor(ps, 32);
            lrun += ps;

            unsigned pk[4][2];
#pragma unroll
            for (int hh = 0; hh < 4; ++hh) {
                asm("v_cvt_pk_bf16_f32 %0, %1, %2"
                    : "=v"(pk[hh][0]) : "v"(p[hh][0]), "v"(p[hh][1]));
                asm("v_cvt_pk_bf16_f32 %0, %1, %2"
                    : "=v"(pk[hh][1]) : "v"(p[hh][2]), "v"(p[hh][3]));
            }
            int ex[4][2][2];
#pragma unroll
            for (int hh = 0; hh < 4; ++hh)
#pragma unroll
                for (int ii = 0; ii < 2; ++ii) {
                    ex[hh][ii][0] = __builtin_amdgcn_ds_bpermute(addrA, (int)pk[hh][ii]);
                    ex[hh][ii][1] = __builtin_amdgcn_ds_bpermute(addrB, (int)pk[hh][ii]);
                }
            union { int w[4]; bf16x8 v; } pu0, pu1;
#pragma unroll
            for (int jw = 0; jw < 4; ++jw) {
                pu0.w[jw] = hb ? ex[1][jw & 1][jw >> 1] : ex[0][jw & 1][jw >> 1];
                pu1.w[jw] = hb ? ex[3][jw & 1][jw >> 1] : ex[2][jw & 1][jw >> 1];
            }
            bf16x8 pa0 = pu0.v;
            bf16x8 pa1 = pu1.v;

            __builtin_amdgcn_s_setprio(1);
#pragma unroll
            for (int c2 = 0; c2 < 8; ++c2) {
                const int d = c2 * 16 + l15;
                bf16x8 vf0 = *(const bf16x8*)((const char*)Vb[s]
                              + d * 128 + ((g4 ^ (d & 7)) * 16));
                oacc[c2] = mf(pa0, vf0, oacc[c2]);
                bf16x8 vf1 = *(const bf16x8*)((const char*)Vb[s]
                              + d * 128 + ((((4 + g4) ^ (d & 7))) * 16));
                oacc[c2] = mf(pa1, vf1, oacc[c2]);
            }
            __builtin_amdgcn_s_setprio(0);
        }
        __builtin_amdgcn_s_barrier();
    }

    float* KbF = (float*)&Kb[0][0];
    if (s == 1) {
        MergeML[grp][0][lane] = mrun;
        MergeML[grp][1][lane] = lrun;
#pragma unroll
        for (int c2 = 0; c2 < 8; ++c2)
#pragma unroll
            for (int r = 0; r < 4; ++r)
                KbF[grp * 2048 + (c2 * 4 + r) * 64 + lane] = oacc[c2][r];
    }
    asm volatile("s_waitcnt lgkmcnt(0)" ::: "memory");
    __builtin_amdgcn_s_barrier();

    if (s == 0) {
        float m1 = MergeML[grp][0][lane];
        float l1 = MergeML[grp][1][lane];
        float mg = fmaxf(mrun, m1);
        float a0 = __expf(mrun - mg);
        float a1 = __expf(m1 - mg);
        float L  = lrun * a0 + l1 * a1;
        float ar0[4], ar1[4], Lr[4];
#pragma unroll
        for (int r = 0; r < 4; ++r) {
            ar0[r] = __int_as_float(__builtin_amdgcn_ds_bpermute(
                         addrQ + 4 * r, __float_as_int(a0)));
            ar1[r] = __int_as_float(__builtin_amdgcn_ds_bpermute(
                         addrQ + 4 * r, __float_as_int(a1)));
            Lr[r]  = __int_as_float(__builtin_amdgcn_ds_bpermute(
                         addrQ + 4 * r, __float_as_int(L)));
        }
#pragma unroll
        for (int c2 = 0; c2 < 8; ++c2)
#pragma unroll
            for (int r = 0; r < 4; ++r) {
                float oex = KbF[grp * 2048 + (c2 * 4 + r) * 64 + lane];
                float v = (oacc[c2][r] * ar0[r] + oex * ar1[r]) / Lr[r];
                O[(size_t)(q0 + g4 * 4 + r) * (kH * kD) + h * kD + c2 * 16 + l15] = f2bf(v);
            }
    }
}

}  // namespace

extern "C" void kernel_launch(void* const* d_in, const int* in_sizes, int n_in,
                              void* d_out, int out_size, void* d_ws, size_t ws_size,
                              hipStream_t stream) {
    (void)in_sizes; (void)n_in; (void)out_size; (void)ws_size;

    const int*   positions = (const int*)  d_in[0];
    const float* hidden    = (const float*)d_in[1];
    const float* wq  = (const float*)d_in[2];
    const float* wk  = (const float*)d_in[3];
    const float* wv  = (const float*)d_in[4];
    const float* wo  = (const float*)d_in[5];
    const float* qnw = (const float*)d_in[6];
    const float* knw = (const float*)d_in[7];
    const float* ln1 = (const float*)d_in[8];
    const float* ln2 = (const float*)d_in[9];
    const float* wg  = (const float*)d_in[10];
    const float* wu  = (const float*)d_in[11];
    const float* wd  = (const float*)d_in[12];

    char* ws = (char*)d_ws;
    unsigned short* WQKV = (unsigned short*)(ws + 0);          // 4096x2048 bf16
    unsigned short* WO   = (unsigned short*)(ws + 16777216);   // 2048x2048
    unsigned short* WG   = (unsigned short*)(ws + 25165824);   // 6144x2048
    unsigned short* WU   = (unsigned short*)(ws + 50331648);   // 6144x2048
    unsigned short* WD   = (unsigned short*)(ws + 75497472);   // 2048x6144
    unsigned short* XN1  = (unsigned short*)(ws + 100663296);  // T x 2048
    unsigned short* OATT = (unsigned short*)(ws + 109051904);  // T x 2048
    float*          H1   = (float*)(ws + 117440512);           // T x 2048 fp32
    unsigned short* XN2  = (unsigned short*)(ws + 134217728);  // T x 2048
    unsigned short* QKVB = (unsigned short*)(ws + 142606336);  // T x 4096 bf16
    unsigned short* QB   = (unsigned short*)(ws + 176160768);  // T x 2048
    unsigned short* KB   = (unsigned short*)(ws + 184549376);  // T x 1024
    unsigned short* VT   = (unsigned short*)(ws + 188743680);  // 1024 x T
    unsigned short* ACT  = (unsigned short*)(ws + 167772160);  // T x 6144

    // O-proj split-K4 partials (QKVB span + QB/KB + WQKV dead at that point)
    float* OP0 = (float*)(ws + 142606336);
    float* OP1 = (float*)(ws + 159383552);
    float* OP2 = (float*)(ws + 176160768);
    float* OP3 = (float*)(ws + 0);
    // down split-K4 partials (WQKV / WO / WG-mid / OP0-span dead by then)
    float* DP0 = (float*)(ws + 0);
    float* DP1 = (float*)(ws + 16777216);
    float* DP2 = (float*)(ws + 33554432);
    float* DP3 = (float*)(ws + 142606336);

    // single fused weight conversion (wq|wk|wv|wo|wg|wu|wd -> ws bf16 prefix)
    cvt_all<<<dim3(49152), dim3(256), 0, stream>>>(
        wq, wk, wv, wo, wg, wu, wd, (ushort4*)ws);

    rmsnorm_k<<<dim3(kT), dim3(256), 0, stream>>>(hidden, ln1, XN1);

    // QKV GEMM: 128x256 tile, grid 16x16 = 256 exact, bf16 output
    gemm128<1><<<dim3(4096 / 256, kT / 128), dim3(512), 0, stream>>>(
        XN1, WQKV, QKVB, kT, 4096, kHid, kHid, nullptr, nullptr);

    qknorm_rope<<<dim3(kT, 6), dim3(256), 0, stream>>>(QKVB, positions, qnw, knw, QB, KB);
    vtrans<<<dim3(kT / 32, 1024 / 32), dim3(256), 0, stream>>>(QKVB, VT);

    attn_fwd5<<<dim3(kHK, kT / 32), dim3(512), 0, stream>>>(QB, KB, VT, OATT);

    // O-proj: 256x256 split-K4 (grid 8x8x4 = 256 exact) -> partials
    gemm256<4><<<dim3(kHid / 256, kT / 256, 4), dim3(512), 0, stream>>>(
        OATT, WO, nullptr, kT, kHid, kHid, 512, OP0, OP1, OP2, OP3);
    // fused: H1 = sum(partials) + hidden; XN2 = rmsnorm(H1)*ln2
    rmsnorm_red4<<<dim3(kT), dim3(256), 0, stream>>>(
        OP0, OP1, OP2, OP3, hidden, ln2, H1, XN2);

    // fused gate+up GEMM: 256x96 tile, grid 64x8 = 512 (2 exact rounds)
    gemm_gu<<<dim3(kFF / 96, kT / 256), dim3(512), 0, stream>>>(XN2, WG, WU, ACT);

    // down: 256x256 split-K4 (KS=1536, grid 8x8x4 = 256 exact) -> partials
    gemm256<4><<<dim3(kHid / 256, kT / 256, 4), dim3(512), 0, stream>>>(
        ACT, WD, nullptr, kT, kHid, kFF, 1536, DP0, DP1, DP2, DP3);
    reduce4<<<dim3(kT * kHid / 4 / 256), dim3(256), 0, stream>>>(
        DP0, DP1, DP2, DP3, H1, (float*)d_out, kT * kHid / 4);
}

// Round 18
// 373.966 us; speedup vs baseline: 1.0312x; 1.0312x over previous
//
#include <hip/hip_runtime.h>
#include <hip/hip_bf16.h>
#include <stdint.h>

namespace {

constexpr int kT   = 2048;
constexpr int kHid = 2048;
constexpr int kH   = 16;
constexpr int kHK  = 8;
constexpr int kD   = 128;
constexpr int kFF  = 6144;

using bf16x8 = __attribute__((ext_vector_type(8))) short;
using f32x4  = __attribute__((ext_vector_type(4))) float;

__device__ __forceinline__ float bf2f(unsigned short u) {
    return __uint_as_float(((unsigned)u) << 16);
}
__device__ __forceinline__ unsigned short f2bf(float f) {
    unsigned u = __float_as_uint(f);
    return (unsigned short)((u + 0x7fffu + ((u >> 16) & 1u)) >> 16);
}
__device__ __forceinline__ void gload_lds16(const void* g, void* l) {
    __builtin_amdgcn_global_load_lds(
        (__attribute__((address_space(1))) void*)g,
        (__attribute__((address_space(3))) void*)l, 16, 0, 0);
}
__device__ __forceinline__ f32x4 mf(bf16x8 a, bf16x8 b, f32x4 c) {
    return __builtin_amdgcn_mfma_f32_16x16x32_bf16(a, b, c, 0, 0, 0);
}

// One-shot fp32->bf16 conversion of all seven weight matrices into the
// contiguous ws prefix. Region boundaries in float4 units:
//   wq [0,1048576) wk [..,1572864) wv [..,2097152) wo [..,3145728)
//   wg [..,6291456) wu [..,9437184) wd [..,12582912)
__global__ __launch_bounds__(256)
void cvt_all(const float* __restrict__ wq, const float* __restrict__ wk,
             const float* __restrict__ wv, const float* __restrict__ wo,
             const float* __restrict__ wg, const float* __restrict__ wu,
             const float* __restrict__ wd, ushort4* __restrict__ dst) {
    int i = blockIdx.x * 256 + threadIdx.x;
    if (i >= 12582912) return;
    const float4* src;
    int base;
    if (i < 3145728) {
        if (i < 1048576)      { src = (const float4*)wq; base = 0; }
        else if (i < 1572864) { src = (const float4*)wk; base = 1048576; }
        else if (i < 2097152) { src = (const float4*)wv; base = 1572864; }
        else                  { src = (const float4*)wo; base = 2097152; }
    } else {
        if (i < 6291456)      { src = (const float4*)wg; base = 3145728; }
        else if (i < 9437184) { src = (const float4*)wu; base = 6291456; }
        else                  { src = (const float4*)wd; base = 9437184; }
    }
    float4 v = src[i - base];
    ushort4 o;
    o.x = f2bf(v.x); o.y = f2bf(v.y); o.z = f2bf(v.z); o.w = f2bf(v.w);
    dst[i] = o;
}

// out = p0+p1+p2+p3+res (all fp32), vectorized x4
__global__ __launch_bounds__(256)
void reduce4(const float* __restrict__ p0, const float* __restrict__ p1,
             const float* __restrict__ p2, const float* __restrict__ p3,
             const float* __restrict__ res, float* __restrict__ out, int n4) {
    int i = blockIdx.x * 256 + threadIdx.x;
    if (i < n4) {
        float4 a = ((const float4*)p0)[i];
        float4 b = ((const float4*)p1)[i];
        float4 c = ((const float4*)p2)[i];
        float4 d = ((const float4*)p3)[i];
        float4 r = ((const float4*)res)[i];
        float4 o;
        o.x = a.x + b.x + c.x + d.x + r.x;
        o.y = a.y + b.y + c.y + d.y + r.y;
        o.z = a.z + b.z + c.z + d.z + r.z;
        o.w = a.w + b.w + c.w + d.w + r.w;
        ((float4*)out)[i] = o;
    }
}

// RMSNorm over HID=2048, fp32 in -> bf16 out. 1 block per row.
__global__ __launch_bounds__(256)
void rmsnorm_k(const float* __restrict__ x, const float* __restrict__ w,
               unsigned short* __restrict__ out) {
    const int row = blockIdx.x;
    const int tid = threadIdx.x;
    const float4* xr = (const float4*)(x + (size_t)row * kHid);
    float4 v0 = xr[tid];
    float4 v1 = xr[tid + 256];
    float ss = v0.x*v0.x + v0.y*v0.y + v0.z*v0.z + v0.w*v0.w
             + v1.x*v1.x + v1.y*v1.y + v1.z*v1.z + v1.w*v1.w;
#pragma unroll
    for (int m = 1; m < 64; m <<= 1) ss += __shfl_xor(ss, m);
    __shared__ float red[4];
    if ((tid & 63) == 0) red[tid >> 6] = ss;
    __syncthreads();
    float tot = red[0] + red[1] + red[2] + red[3];
    float rs = rsqrtf(tot * (1.0f / kHid) + 1e-6f);
    const float4* wv = (const float4*)w;
    float4 w0 = wv[tid], w1 = wv[tid + 256];
    ushort4 o0, o1;
    o0.x = f2bf(v0.x * rs * w0.x); o0.y = f2bf(v0.y * rs * w0.y);
    o0.z = f2bf(v0.z * rs * w0.z); o0.w = f2bf(v0.w * rs * w0.w);
    o1.x = f2bf(v1.x * rs * w1.x); o1.y = f2bf(v1.y * rs * w1.y);
    o1.z = f2bf(v1.z * rs * w1.z); o1.w = f2bf(v1.w * rs * w1.w);
    ushort4* orow = (ushort4*)(out + (size_t)row * kHid);
    orow[tid] = o0;
    orow[tid + 256] = o1;
}

// Fused: h = p0+p1+p2+p3+res -> H1; XN2 = rmsnorm(h)*w (bf16). 1 block/row.
__global__ __launch_bounds__(256)
void rmsnorm_red4(const float* __restrict__ p0, const float* __restrict__ p1,
                  const float* __restrict__ p2, const float* __restrict__ p3,
                  const float* __restrict__ res, const float* __restrict__ w,
                  float* __restrict__ H, unsigned short* __restrict__ out) {
    const int row = blockIdx.x;
    const int tid = threadIdx.x;
    const size_t base = (size_t)row * kHid;
    float4 v0, v1;
    {
        const float4* a = (const float4*)(p0 + base);
        const float4* b = (const float4*)(p1 + base);
        const float4* c = (const float4*)(p2 + base);
        const float4* d = (const float4*)(p3 + base);
        const float4* r = (const float4*)(res + base);
        float4 a0 = a[tid], b0 = b[tid], c0 = c[tid], d0 = d[tid], r0 = r[tid];
        v0.x = a0.x + b0.x + c0.x + d0.x + r0.x;
        v0.y = a0.y + b0.y + c0.y + d0.y + r0.y;
        v0.z = a0.z + b0.z + c0.z + d0.z + r0.z;
        v0.w = a0.w + b0.w + c0.w + d0.w + r0.w;
        float4 a1 = a[tid + 256], b1 = b[tid + 256], c1 = c[tid + 256],
               d1 = d[tid + 256], r1 = r[tid + 256];
        v1.x = a1.x + b1.x + c1.x + d1.x + r1.x;
        v1.y = a1.y + b1.y + c1.y + d1.y + r1.y;
        v1.z = a1.z + b1.z + c1.z + d1.z + r1.z;
        v1.w = a1.w + b1.w + c1.w + d1.w + r1.w;
    }
    ((float4*)(H + base))[tid] = v0;
    ((float4*)(H + base))[tid + 256] = v1;
    float ss = v0.x*v0.x + v0.y*v0.y + v0.z*v0.z + v0.w*v0.w
             + v1.x*v1.x + v1.y*v1.y + v1.z*v1.z + v1.w*v1.w;
#pragma unroll
    for (int m = 1; m < 64; m <<= 1) ss += __shfl_xor(ss, m);
    __shared__ float red[4];
    if ((tid & 63) == 0) red[tid >> 6] = ss;
    __syncthreads();
    float tot = red[0] + red[1] + red[2] + red[3];
    float rs = rsqrtf(tot * (1.0f / kHid) + 1e-6f);
    const float4* wv = (const float4*)w;
    float4 w0 = wv[tid], w1 = wv[tid + 256];
    ushort4 o0, o1;
    o0.x = f2bf(v0.x * rs * w0.x); o0.y = f2bf(v0.y * rs * w0.y);
    o0.z = f2bf(v0.z * rs * w0.z); o0.w = f2bf(v0.w * rs * w0.w);
    o1.x = f2bf(v1.x * rs * w1.x); o1.y = f2bf(v1.y * rs * w1.y);
    o1.z = f2bf(v1.z * rs * w1.z); o1.w = f2bf(v1.w * rs * w1.w);
    ushort4* orow = (ushort4*)(out + base);
    orow[tid] = o0;
    orow[tid + 256] = o1;
}

// -------- 256x256 8-phase GEMM (proven; EPI4 split-K partials) --------------
template <int EPI>
__global__ __launch_bounds__(512, 2)
void gemm256(const unsigned short* __restrict__ A,
             const unsigned short* __restrict__ B,
             void* __restrict__ C,
             int M, int N, int K, int KS,
             float* __restrict__ p0, float* __restrict__ p1,
             float* __restrict__ p2, float* __restrict__ p3) {
    __shared__ unsigned short smem[2][4][128 * 64];  // 128 KiB

    const int tid  = threadIdx.x;
    const int lane = tid & 63;
    const int l15  = lane & 15;
    const int g4   = lane >> 4;
    const int wid  = tid >> 6;
    const int wr   = wid >> 2;
    const int wc   = wid & 3;
    const int bm   = blockIdx.y * 256;
    const int bn   = blockIdx.x * 256;
    const int kb   = (EPI == 4) ? blockIdx.z * KS : 0;
    const int NT   = ((EPI == 4) ? KS : K) >> 6;
    const int NI   = NT >> 1;

    f32x4 acc[8][4] = {};

    auto stage = [&](int b, int reg, int t) {
        const unsigned short* Base = (reg < 2) ? A : B;
        const int br = ((reg < 2) ? bm : bn) + (reg & 1) * 128;
#pragma unroll
        for (int i = 0; i < 2; ++i) {
            int ch   = tid + i * 512;
            int row  = ch >> 3;
            int slot = (ch & 7) ^ (row & 7);
            gload_lds16(Base + (size_t)(br + row) * K + kb + t * 64 + slot * 8,
                        (char*)&smem[b][reg][0] + ch * 16);
        }
    };
    auto rdA = [&](int b, int m, int ks) {
        int row = m * 16 + l15;
        return *(const bf16x8*)((const char*)&smem[b][wr][0]
               + row * 128 + (((ks * 4 + g4) ^ (row & 7)) * 16));
    };
    auto rdB = [&](int b, int n, int ks) {
        int row = wc * 64 + n * 16 + l15;
        return *(const bf16x8*)((const char*)&smem[b][2 + (row >> 7)][0]
               + (row & 127) * 128 + (((ks * 4 + g4) ^ (row & 7)) * 16));
    };

    stage(0, 2, 0); stage(0, 3, 0); stage(0, 0, 0); stage(0, 1, 0);
    stage(1, 2, 1); stage(1, 3, 1); stage(1, 0, 1);
    asm volatile("s_waitcnt vmcnt(6)" ::: "memory");
    __builtin_amdgcn_s_barrier();

    for (int i = 0; i < NI; ++i) {
        const int e  = 2 * i;
        const int o  = e + 1;
        const bool pf = (e + 2 < NT);
        bf16x8 af[4][2], bfr[4][2];

#pragma unroll
        for (int m = 0; m < 4; ++m) { af[m][0] = rdA(0, m, 0); af[m][1] = rdA(0, m, 1); }
#pragma unroll
        for (int n = 0; n < 4; ++n) { bfr[n][0] = rdB(0, n, 0); bfr[n][1] = rdB(0, n, 1); }
        stage(1, 1, o);
        __builtin_amdgcn_s_barrier();
        asm volatile("s_waitcnt lgkmcnt(0)" ::: "memory");
        __builtin_amdgcn_sched_barrier(0);
        __builtin_amdgcn_s_setprio(1);
#pragma unroll
        for (int m = 0; m < 4; ++m)
#pragma unroll
            for (int n = 0; n < 2; ++n) {
                acc[m][n] = mf(af[m][0], bfr[n][0], acc[m][n]);
                acc[m][n] = mf(af[m][1], bfr[n][1], acc[m][n]);
            }
        __builtin_amdgcn_s_setprio(0);
        __builtin_amdgcn_s_barrier();

        if (pf) stage(0, 2, e + 2);
        __builtin_amdgcn_s_barrier();
        __builtin_amdgcn_s_setprio(1);
#pragma unroll
        for (int m = 0; m < 4; ++m)
#pragma unroll
            for (int n = 2; n < 4; ++n) {
                acc[m][n] = mf(af[m][0], bfr[n][0], acc[m][n]);
                acc[m][n] = mf(af[m][1], bfr[n][1], acc[m][n]);
            }
        __builtin_amdgcn_s_setprio(0);
        __builtin_amdgcn_s_barrier();

#pragma unroll
        for (int m = 0; m < 4; ++m) { af[m][0] = rdA(0, 4 + m, 0); af[m][1] = rdA(0, 4 + m, 1); }
        if (pf) stage(0, 3, e + 2);
        __builtin_amdgcn_s_barrier();
        asm volatile("s_waitcnt lgkmcnt(0)" ::: "memory");
        __builtin_amdgcn_sched_barrier(0);
        __builtin_amdgcn_s_setprio(1);
#pragma unroll
        for (int m = 0; m < 4; ++m)
#pragma unroll
            for (int n = 0; n < 2; ++n) {
                acc[4 + m][n] = mf(af[m][0], bfr[n][0], acc[4 + m][n]);
                acc[4 + m][n] = mf(af[m][1], bfr[n][1], acc[4 + m][n]);
            }
        __builtin_amdgcn_s_setprio(0);
        __builtin_amdgcn_s_barrier();

        if (pf) stage(0, 0, e + 2);
        __builtin_amdgcn_s_barrier();
        __builtin_amdgcn_s_setprio(1);
#pragma unroll
        for (int m = 0; m < 4; ++m)
#pragma unroll
            for (int n = 2; n < 4; ++n) {
                acc[4 + m][n] = mf(af[m][0], bfr[n][0], acc[4 + m][n]);
                acc[4 + m][n] = mf(af[m][1], bfr[n][1], acc[4 + m][n]);
            }
        __builtin_amdgcn_s_setprio(0);
        if (pf) asm volatile("s_waitcnt vmcnt(6)" ::: "memory");
        else    asm volatile("s_waitcnt vmcnt(0)" ::: "memory");
        __builtin_amdgcn_s_barrier();

#pragma unroll
        for (int m = 0; m < 4; ++m) { af[m][0] = rdA(1, m, 0); af[m][1] = rdA(1, m, 1); }
#pragma unroll
        for (int n = 0; n < 4; ++n) { bfr[n][0] = rdB(1, n, 0); bfr[n][1] = rdB(1, n, 1); }
        if (pf) stage(0, 1, e + 2);
        __builtin_amdgcn_s_barrier();
        asm volatile("s_waitcnt lgkmcnt(0)" ::: "memory");
        __builtin_amdgcn_sched_barrier(0);
        __builtin_amdgcn_s_setprio(1);
#pragma unroll
        for (int m = 0; m < 4; ++m)
#pragma unroll
            for (int n = 0; n < 2; ++n) {
                acc[m][n] = mf(af[m][0], bfr[n][0], acc[m][n]);
                acc[m][n] = mf(af[m][1], bfr[n][1], acc[m][n]);
            }
        __builtin_amdgcn_s_setprio(0);
        __builtin_amdgcn_s_barrier();

        if (pf) stage(1, 2, o + 2);
        __builtin_amdgcn_s_barrier();
        __builtin_amdgcn_s_setprio(1);
#pragma unroll
        for (int m = 0; m < 4; ++m)
#pragma unroll
            for (int n = 2; n < 4; ++n) {
                acc[m][n] = mf(af[m][0], bfr[n][0], acc[m][n]);
                acc[m][n] = mf(af[m][1], bfr[n][1], acc[m][n]);
            }
        __builtin_amdgcn_s_setprio(0);
        __builtin_amdgcn_s_barrier();

#pragma unroll
        for (int m = 0; m < 4; ++m) { af[m][0] = rdA(1, 4 + m, 0); af[m][1] = rdA(1, 4 + m, 1); }
        if (pf) stage(1, 3, o + 2);
        __builtin_amdgcn_s_barrier();
        asm volatile("s_waitcnt lgkmcnt(0)" ::: "memory");
        __builtin_amdgcn_sched_barrier(0);
        __builtin_amdgcn_s_setprio(1);
#pragma unroll
        for (int m = 0; m < 4; ++m)
#pragma unroll
            for (int n = 0; n < 2; ++n) {
                acc[4 + m][n] = mf(af[m][0], bfr[n][0], acc[4 + m][n]);
                acc[4 + m][n] = mf(af[m][1], bfr[n][1], acc[4 + m][n]);
            }
        __builtin_amdgcn_s_setprio(0);
        __builtin_amdgcn_s_barrier();

        if (pf) stage(1, 0, o + 2);
        __builtin_amdgcn_s_barrier();
        __builtin_amdgcn_s_setprio(1);
#pragma unroll
        for (int m = 0; m < 4; ++m)
#pragma unroll
            for (int n = 2; n < 4; ++n) {
                acc[4 + m][n] = mf(af[m][0], bfr[n][0], acc[4 + m][n]);
                acc[4 + m][n] = mf(af[m][1], bfr[n][1], acc[4 + m][n]);
            }
        __builtin_amdgcn_s_setprio(0);
        if (pf) asm volatile("s_waitcnt vmcnt(6)" ::: "memory");
        __builtin_amdgcn_s_barrier();
    }

    float* P = nullptr;
    if (EPI == 4) {
        const int z = blockIdx.z;
        P = (z == 0) ? p0 : (z == 1) ? p1 : (z == 2) ? p2 : p3;
    }
#pragma unroll
    for (int m = 0; m < 8; ++m) {
#pragma unroll
        for (int n = 0; n < 4; ++n) {
            int row = bm + wr * 128 + m * 16 + g4 * 4;
            int col = bn + wc * 64 + n * 16 + l15;
#pragma unroll
            for (int r = 0; r < 4; ++r) {
                size_t idx = (size_t)(row + r) * N + col;
                float v = acc[m][n][r];
                if (EPI == 0) ((float*)C)[idx] = v;
                else          P[idx] = v;
            }
        }
    }
}

// -------- 128M x 256N 8-phase GEMM (proven; used for QKV) ------------------
// EPI: 0 = fp32 store, 1 = bf16 store, 4 = split-K2 fp32 partials.
template <int EPI>
__global__ __launch_bounds__(512, 2)
void gemm128(const unsigned short* __restrict__ A,
             const unsigned short* __restrict__ B,
             void* __restrict__ C,
             int M, int N, int K, int KS,
             float* __restrict__ p0, float* __restrict__ p1) {
    __shared__ unsigned short smem[2][3][128 * 64];  // 96 KiB

    const int tid  = threadIdx.x;
    const int lane = tid & 63;
    const int l15  = lane & 15;
    const int g4   = lane >> 4;
    const int wid  = tid >> 6;
    const int wr   = wid >> 2;
    const int wc   = wid & 3;
    const int bm   = blockIdx.y * 128;
    const int bn   = blockIdx.x * 256;
    const int kb   = (EPI == 4) ? blockIdx.z * KS : 0;
    const int NT   = ((EPI == 4) ? KS : K) >> 6;
    const int NI   = NT >> 1;

    f32x4 acc[4][4] = {};

    auto stage = [&](int b, int reg, int t) {
        const unsigned short* Base = (reg == 0) ? A : B;
        const int br = (reg == 0) ? bm : bn + (reg - 1) * 128;
#pragma unroll
        for (int i = 0; i < 2; ++i) {
            int ch   = tid + i * 512;
            int row  = ch >> 3;
            int slot = (ch & 7) ^ (row & 7);
            gload_lds16(Base + (size_t)(br + row) * K + kb + t * 64 + slot * 8,
                        (char*)&smem[b][reg][0] + ch * 16);
        }
    };
    auto rdA = [&](int b, int m, int ks) {
        int row = wr * 64 + m * 16 + l15;
        return *(const bf16x8*)((const char*)&smem[b][0][0]
               + row * 128 + (((ks * 4 + g4) ^ (row & 7)) * 16));
    };
    auto rdB = [&](int b, int n, int ks) {
        int row = wc * 64 + n * 16 + l15;
        return *(const bf16x8*)((const char*)&smem[b][1 + (row >> 7)][0]
               + (row & 127) * 128 + (((ks * 4 + g4) ^ (row & 7)) * 16));
    };

    stage(0, 1, 0); stage(0, 2, 0); stage(0, 0, 0);
    stage(1, 1, 1); stage(1, 2, 1);
    asm volatile("s_waitcnt vmcnt(4)" ::: "memory");
    __builtin_amdgcn_s_barrier();

    for (int i = 0; i < NI; ++i) {
        const int e  = 2 * i;
        const int o  = e + 1;
        const bool pf = (e + 2 < NT);
        bf16x8 af[4][2], bfr[4][2];

#pragma unroll
        for (int m = 0; m < 4; ++m) { af[m][0] = rdA(0, m, 0); af[m][1] = rdA(0, m, 1); }
#pragma unroll
        for (int n = 0; n < 4; ++n) { bfr[n][0] = rdB(0, n, 0); bfr[n][1] = rdB(0, n, 1); }
        stage(1, 0, o);
        __builtin_amdgcn_s_barrier();
        asm volatile("s_waitcnt lgkmcnt(0)" ::: "memory");
        __builtin_amdgcn_sched_barrier(0);
        __builtin_amdgcn_s_setprio(1);
#pragma unroll
        for (int m = 0; m < 4; ++m) {
            acc[m][0] = mf(af[m][0], bfr[0][0], acc[m][0]);
            acc[m][0] = mf(af[m][1], bfr[0][1], acc[m][0]);
        }
        __builtin_amdgcn_s_setprio(0);
        __builtin_amdgcn_s_barrier();

        if (pf) stage(0, 1, e + 2);
        __builtin_amdgcn_s_barrier();
        __builtin_amdgcn_s_setprio(1);
#pragma unroll
        for (int m = 0; m < 4; ++m) {
            acc[m][1] = mf(af[m][0], bfr[1][0], acc[m][1]);
            acc[m][1] = mf(af[m][1], bfr[1][1], acc[m][1]);
        }
        __builtin_amdgcn_s_setprio(0);
        __builtin_amdgcn_s_barrier();

        if (pf) stage(0, 2, e + 2);
        __builtin_amdgcn_s_barrier();
        __builtin_amdgcn_s_setprio(1);
#pragma unroll
        for (int m = 0; m < 4; ++m) {
            acc[m][2] = mf(af[m][0], bfr[2][0], acc[m][2]);
            acc[m][2] = mf(af[m][1], bfr[2][1], acc[m][2]);
        }
        __builtin_amdgcn_s_setprio(0);
        __builtin_amdgcn_s_barrier();

        __builtin_amdgcn_s_setprio(1);
#pragma unroll
        for (int m = 0; m < 4; ++m) {
            acc[m][3] = mf(af[m][0], bfr[3][0], acc[m][3]);
            acc[m][3] = mf(af[m][1], bfr[3][1], acc[m][3]);
        }
        __builtin_amdgcn_s_setprio(0);
        if (pf) asm volatile("s_waitcnt vmcnt(4)" ::: "memory");
        else    asm volatile("s_waitcnt vmcnt(0)" ::: "memory");
        __builtin_amdgcn_s_barrier();

#pragma unroll
        for (int m = 0; m < 4; ++m) { af[m][0] = rdA(1, m, 0); af[m][1] = rdA(1, m, 1); }
#pragma unroll
        for (int n = 0; n < 4; ++n) { bfr[n][0] = rdB(1, n, 0); bfr[n][1] = rdB(1, n, 1); }
        if (pf) stage(0, 0, e + 2);
        __builtin_amdgcn_s_barrier();
        asm volatile("s_waitcnt lgkmcnt(0)" ::: "memory");
        __builtin_amdgcn_sched_barrier(0);
        __builtin_amdgcn_s_setprio(1);
#pragma unroll
        for (int m = 0; m < 4; ++m) {
            acc[m][0] = mf(af[m][0], bfr[0][0], acc[m][0]);
            acc[m][0] = mf(af[m][1], bfr[0][1], acc[m][0]);
        }
        __builtin_amdgcn_s_setprio(0);
        __builtin_amdgcn_s_barrier();

        if (pf) stage(1, 1, o + 2);
        __builtin_amdgcn_s_barrier();
        __builtin_amdgcn_s_setprio(1);
#pragma unroll
        for (int m = 0; m < 4; ++m) {
            acc[m][1] = mf(af[m][0], bfr[1][0], acc[m][1]);
            acc[m][1] = mf(af[m][1], bfr[1][1], acc[m][1]);
        }
        __builtin_amdgcn_s_setprio(0);
        __builtin_amdgcn_s_barrier();

        if (pf) stage(1, 2, o + 2);
        __builtin_amdgcn_s_barrier();
        __builtin_amdgcn_s_setprio(1);
#pragma unroll
        for (int m = 0; m < 4; ++m) {
            acc[m][2] = mf(af[m][0], bfr[2][0], acc[m][2]);
            acc[m][2] = mf(af[m][1], bfr[2][1], acc[m][2]);
        }
        __builtin_amdgcn_s_setprio(0);
        __builtin_amdgcn_s_barrier();

        __builtin_amdgcn_s_setprio(1);
#pragma unroll
        for (int m = 0; m < 4; ++m) {
            acc[m][3] = mf(af[m][0], bfr[3][0], acc[m][3]);
            acc[m][3] = mf(af[m][1], bfr[3][1], acc[m][3]);
        }
        __builtin_amdgcn_s_setprio(0);
        if (pf) asm volatile("s_waitcnt vmcnt(4)" ::: "memory");
        __builtin_amdgcn_s_barrier();
    }

    float* P = nullptr;
    if (EPI == 4) P = (blockIdx.z == 0) ? p0 : p1;
#pragma unroll
    for (int m = 0; m < 4; ++m) {
#pragma unroll
        for (int n = 0; n < 4; ++n) {
            int row = bm + wr * 64 + m * 16 + g4 * 4;
            int col = bn + wc * 64 + n * 16 + l15;
#pragma unroll
            for (int r = 0; r < 4; ++r) {
                size_t idx = (size_t)(row + r) * N + col;
                float v = acc[m][n][r];
                if (EPI == 0)      ((float*)C)[idx] = v;
                else if (EPI == 1) ((unsigned short*)C)[idx] = f2bf(v);
                else               P[idx] = v;
            }
        }
    }
}

// -------- fused gate+up GEMM v2: tile 256M x 96FF, grid 64x8 = 512 ---------
// T1 A-panel-resident remap: flat id -> byl = id & 7 (A panel pinned per
// XCD), bxl = id >> 3. Bijective (512 = 64*8 exact).
__global__ __launch_bounds__(512, 2)
void gemm_gu(const unsigned short* __restrict__ A,
             const unsigned short* __restrict__ WGp,
             const unsigned short* __restrict__ WUp,
             unsigned short* __restrict__ OUT) {
    __shared__ unsigned short smem[2][28672];  // 112 KiB

    const int tid  = threadIdx.x;
    const int lane = tid & 63;
    const int l15  = lane & 15;
    const int g4   = lane >> 4;
    const int wid  = tid >> 6;   // 0..7
    const int wr   = wid >> 1;   // 0..3  (64-row slice)
    const int wc   = wid & 1;    // 0..1  (48-col slice)
    const int id   = blockIdx.y * gridDim.x + blockIdx.x;
    const int byl  = id & 7;     // A panel (one per XCD)
    const int bxl  = id >> 3;    // 0..63
    const int bm   = byl * 256;
    const int bn   = bxl * 96;
    const int K    = kHid;
    const int NT   = K >> 6;     // 32
    const int NI   = NT >> 1;

    f32x4 accg[4][3] = {};
    f32x4 accu[4][3] = {};

    constexpr int OFF_A0 = 0;
    constexpr int OFF_A1 = 16384;
    constexpr int OFF_GU = 32768;

    auto stage_a = [&](int b, int half, int t) {
#pragma unroll
        for (int i = 0; i < 2; ++i) {
            int ch   = tid + i * 512;
            int row  = ch >> 3;
            int slot = (ch & 7) ^ (row & 7);
            gload_lds16(A + (size_t)(bm + half * 128 + row) * K + t * 64 + slot * 8,
                        (char*)&smem[b][0] + (half ? OFF_A1 : OFF_A0) + ch * 16);
        }
    };
    auto stage_gu = [&](int b, int t) {
#pragma unroll
        for (int i = 0; i < 3; ++i) {
            int ch   = tid + i * 512;
            int row  = ch >> 3;
            int slot = (ch & 7) ^ (row & 7);
            const unsigned short* Base = (row >= 96) ? WUp : WGp;
            int srow = bn + (row >= 96 ? row - 96 : row);
            gload_lds16(Base + (size_t)srow * K + t * 64 + slot * 8,
                        (char*)&smem[b][0] + OFF_GU + ch * 16);
        }
    };
    auto rdA = [&](int b, int m, int ks) {
        int rt  = wr * 64 + m * 16 + l15;
        int row = rt & 127;
        return *(const bf16x8*)((const char*)&smem[b][0]
               + (rt >> 7 ? OFF_A1 : OFF_A0)
               + row * 128 + (((ks * 4 + g4) ^ (row & 7)) * 16));
    };
    auto rdG = [&](int b, int n, int ks) {
        int row = wc * 48 + n * 16 + l15;
        return *(const bf16x8*)((const char*)&smem[b][0] + OFF_GU
               + row * 128 + (((ks * 4 + g4) ^ (row & 7)) * 16));
    };
    auto rdU = [&](int b, int n, int ks) {
        int row = 96 + wc * 48 + n * 16 + l15;
        return *(const bf16x8*)((const char*)&smem[b][0] + OFF_GU
               + row * 128 + (((ks * 4 + g4) ^ (row & 7)) * 16));
    };

    stage_a(0, 0, 0); stage_a(0, 1, 0); stage_gu(0, 0);
    stage_a(1, 0, 1); stage_a(1, 1, 1);
    asm volatile("s_waitcnt vmcnt(4)" ::: "memory");
    __builtin_amdgcn_s_barrier();

    for (int i = 0; i < NI; ++i) {
        const int e  = 2 * i;
        const int o  = e + 1;
        const bool pf = (e + 2 < NT);
        bf16x8 af[4][2], bg[3][2], bu[3][2];

#pragma unroll
        for (int m = 0; m < 4; ++m) { af[m][0] = rdA(0, m, 0); af[m][1] = rdA(0, m, 1); }
#pragma unroll
        for (int n = 0; n < 3; ++n) { bg[n][0] = rdG(0, n, 0); bg[n][1] = rdG(0, n, 1); }
        stage_gu(1, o);
        __builtin_amdgcn_s_barrier();
        asm volatile("s_waitcnt lgkmcnt(0)" ::: "memory");
        __builtin_amdgcn_sched_barrier(0);
        __builtin_amdgcn_s_setprio(1);
#pragma unroll
        for (int m = 0; m < 4; ++m)
#pragma unroll
            for (int n = 0; n < 3; ++n)
                accg[m][n] = mf(af[m][0], bg[n][0], accg[m][n]);
        __builtin_amdgcn_s_setprio(0);
        __builtin_amdgcn_s_barrier();

        if (pf) stage_a(0, 0, e + 2);
        __builtin_amdgcn_s_barrier();
        __builtin_amdgcn_s_setprio(1);
#pragma unroll
        for (int m = 0; m < 4; ++m)
#pragma unroll
            for (int n = 0; n < 3; ++n)
                accg[m][n] = mf(af[m][1], bg[n][1], accg[m][n]);
        __builtin_amdgcn_s_setprio(0);
        __builtin_amdgcn_s_barrier();

#pragma unroll
        for (int n = 0; n < 3; ++n) { bu[n][0] = rdU(0, n, 0); bu[n][1] = rdU(0, n, 1); }
        if (pf) stage_a(0, 1, e + 2);
        __builtin_amdgcn_s_barrier();
        asm volatile("s_waitcnt lgkmcnt(0)" ::: "memory");
        __builtin_amdgcn_sched_barrier(0);
        __builtin_amdgcn_s_setprio(1);
#pragma unroll
        for (int m = 0; m < 4; ++m)
#pragma unroll
            for (int n = 0; n < 3; ++n)
                accu[m][n] = mf(af[m][0], bu[n][0], accu[m][n]);
        __builtin_amdgcn_s_setprio(0);
        __builtin_amdgcn_s_barrier();

        if (pf) stage_gu(0, e + 2);
        __builtin_amdgcn_s_barrier();
        __builtin_amdgcn_s_setprio(1);
#pragma unroll
        for (int m = 0; m < 4; ++m)
#pragma unroll
            for (int n = 0; n < 3; ++n)
                accu[m][n] = mf(af[m][1], bu[n][1], accu[m][n]);
        __builtin_amdgcn_s_setprio(0);
        if (pf) asm volatile("s_waitcnt vmcnt(7)" ::: "memory");
        else    asm volatile("s_waitcnt vmcnt(0)" ::: "memory");
        __builtin_amdgcn_s_barrier();

#pragma unroll
        for (int m = 0; m < 4; ++m) { af[m][0] = rdA(1, m, 0); af[m][1] = rdA(1, m, 1); }
#pragma unroll
        for (int n = 0; n < 3; ++n) { bg[n][0] = rdG(1, n, 0); bg[n][1] = rdG(1, n, 1); }
        __builtin_amdgcn_s_barrier();
        asm volatile("s_waitcnt lgkmcnt(0)" ::: "memory");
        __builtin_amdgcn_sched_barrier(0);
        __builtin_amdgcn_s_setprio(1);
#pragma unroll
        for (int m = 0; m < 4; ++m)
#pragma unroll
            for (int n = 0; n < 3; ++n)
                accg[m][n] = mf(af[m][0], bg[n][0], accg[m][n]);
        __builtin_amdgcn_s_setprio(0);
        __builtin_amdgcn_s_barrier();

        if (pf) stage_a(1, 0, o + 2);
        __builtin_amdgcn_s_barrier();
        __builtin_amdgcn_s_setprio(1);
#pragma unroll
        for (int m = 0; m < 4; ++m)
#pragma unroll
            for (int n = 0; n < 3; ++n)
                accg[m][n] = mf(af[m][1], bg[n][1], accg[m][n]);
        __builtin_amdgcn_s_setprio(0);
        __builtin_amdgcn_s_barrier();

#pragma unroll
        for (int n = 0; n < 3; ++n) { bu[n][0] = rdU(1, n, 0); bu[n][1] = rdU(1, n, 1); }
        if (pf) stage_a(1, 1, o + 2);
        __builtin_amdgcn_s_barrier();
        asm volatile("s_waitcnt lgkmcnt(0)" ::: "memory");
        __builtin_amdgcn_sched_barrier(0);
        __builtin_amdgcn_s_setprio(1);
#pragma unroll
        for (int m = 0; m < 4; ++m)
#pragma unroll
            for (int n = 0; n < 3; ++n)
                accu[m][n] = mf(af[m][0], bu[n][0], accu[m][n]);
        __builtin_amdgcn_s_setprio(0);
        __builtin_amdgcn_s_barrier();

        __builtin_amdgcn_s_setprio(1);
#pragma unroll
        for (int m = 0; m < 4; ++m)
#pragma unroll
            for (int n = 0; n < 3; ++n)
                accu[m][n] = mf(af[m][1], bu[n][1], accu[m][n]);
        __builtin_amdgcn_s_setprio(0);
        if (pf) asm volatile("s_waitcnt vmcnt(4)" ::: "memory");
        __builtin_amdgcn_s_barrier();
    }

#pragma unroll
    for (int m = 0; m < 4; ++m) {
#pragma unroll
        for (int n = 0; n < 3; ++n) {
            int row = bm + wr * 64 + m * 16 + g4 * 4;
            int col = bn + wc * 48 + n * 16 + l15;
#pragma unroll
            for (int r = 0; r < 4; ++r) {
                float g = accg[m][n][r];
                float u = accu[m][n][r];
                OUT[(size_t)(row + r) * kFF + col] = f2bf(g / (1.0f + __expf(-g)) * u);
            }
        }
    }
}

// Fused per-head RMSNorm (D=128) + RoPE for q and k. Reads bf16 QKV.
__global__ __launch_bounds__(256)
void qknorm_rope(const unsigned short* __restrict__ qkv, const int* __restrict__ positions,
                 const float* __restrict__ qnw, const float* __restrict__ knw,
                 unsigned short* __restrict__ Qo, unsigned short* __restrict__ Ko) {
    const int t    = blockIdx.x;
    const int j    = blockIdx.y * 4 + (threadIdx.x >> 6);  // 0..23
    const int lane = threadIdx.x & 63;
    const unsigned short* src = qkv + (size_t)t * 4096 + j * 128;
    float x1 = bf2f(src[lane]);
    float x2 = bf2f(src[lane + 64]);
    float ss = x1 * x1 + x2 * x2;
#pragma unroll
    for (int m = 1; m < 64; m <<= 1) ss += __shfl_xor(ss, m);
    float rs = rsqrtf(ss * (1.0f / 128.0f) + 1e-6f);
    const float* w = (j < 16) ? qnw : knw;
    float n1 = x1 * rs * w[lane];
    float n2 = x2 * rs * w[lane + 64];
    float inv = powf(1.0e6f, -(float)lane * (1.0f / 64.0f));
    float fr = (float)positions[t] * inv;
    float sn, cs;
    sincosf(fr, &sn, &cs);
    float o1 = n1 * cs - n2 * sn;
    float o2 = n2 * cs + n1 * sn;
    if (j < 16) {
        unsigned short* d = Qo + (size_t)t * (kH * kD) + j * kD;
        d[lane] = f2bf(o1);
        d[lane + 64] = f2bf(o2);
    } else {
        unsigned short* d = Ko + (size_t)t * (kHK * kD) + (j - 16) * kD;
        d[lane] = f2bf(o1);
        d[lane + 64] = f2bf(o2);
    }
}

// V transpose: bf16 qkv v-part -> Vt bf16 (1024 x T), pure pass-through.
__global__ __launch_bounds__(256)
void vtrans(const unsigned short* __restrict__ qkv, unsigned short* __restrict__ Vt) {
    __shared__ unsigned short tile[32][33];
    const int t0 = blockIdx.x * 32;
    const int d0 = blockIdx.y * 32;
    const int tc = threadIdx.x & 31;
    const int tr = threadIdx.x >> 5;  // 0..7
#pragma unroll
    for (int i = 0; i < 4; ++i) {
        int trow = tr + i * 8;
        tile[trow][tc] = qkv[(size_t)(t0 + trow) * 4096 + 3072 + d0 + tc];
    }
    __syncthreads();
#pragma unroll
    for (int i = 0; i < 4; ++i) {
        int drow = tr + i * 8;
        Vt[(size_t)(d0 + drow) * kT + t0 + tc] = tile[tc][drow];
    }
}

// Causal flash attention v5: kv-split-2 with in-kernel merge (proven R8-R11).
__global__ __launch_bounds__(512, 4)
void attn_fwd5(const unsigned short* __restrict__ Q,   // T x (H*D)
               const unsigned short* __restrict__ Kc,  // T x (HK*D)
               const unsigned short* __restrict__ Vt,  // (HK*D) x T
               unsigned short* __restrict__ O) {       // T x (H*D)
    __shared__ unsigned short Kb[2][64 * 128];
    __shared__ unsigned short Vb[2][128 * 64];
    __shared__ float MergeML[4][2][64];

    const int tid  = threadIdx.x;
    const int lane = tid & 63;
    const int l15  = lane & 15;
    const int g4   = lane >> 4;
    const int wid  = tid >> 6;       // 0..7
    const int s    = wid & 1;        // kv split
    const int grp  = wid >> 1;       // 0..3 = (hs, qsub)
    const int hs   = grp >> 1;
    const int qsub = grp & 1;
    const int hkk  = blockIdx.x;
    const int h    = hkk * 2 + hs;
    const int nby  = gridDim.y;
    const int by   = blockIdx.y;
    const int byl  = (by & 1) ? (nby - 1 - (by >> 1)) : (by >> 1);
    const int q0   = byl * 32 + qsub * 16;
    const int nch  = byl / 2 + 1;
    const int c0   = (nch + 1) >> 1;
    const int myn  = s ? (nch - c0) : c0;
    const int qi   = q0 + l15;
    const int vt   = grp * 64 + lane;

    const int addrA = ((g4 & 1) * 32 + l15) * 4;
    const int addrB = addrA + 64;
    const int addrQ = g4 * 80;
    const bool hb   = (g4 >> 1) != 0;

    bf16x8 qf[4];
#pragma unroll
    for (int ks = 0; ks < 4; ++ks)
        qf[ks] = *(const bf16x8*)(Q + (size_t)(q0 + l15) * (kH * kD) + h * kD + ks * 32 + g4 * 8);

    f32x4 oacc[8] = {};
    float mrun = -3e38f, lrun = 0.f;
    const float scale = 0.08838834764831845f;  // 1/sqrt(128)

    auto stage = [&](int kv0) {
#pragma unroll
        for (int i = 0; i < 4; ++i) {
            int ch  = vt + i * 256;
            int row = ch >> 4;
            int c16 = ch & 15;
            gload_lds16(Kc + (size_t)(kv0 + row) * (kHK * kD) + hkk * kD
                            + ((c16 ^ (row & 7)) * 8),
                        (char*)Kb[s] + ch * 16);
        }
#pragma unroll
        for (int i = 0; i < 4; ++i) {
            int ch  = vt + i * 256;
            int row = ch >> 3;
            int c8  = ch & 7;
            gload_lds16(Vt + (size_t)(hkk * kD + row) * kT + kv0
                            + ((c8 ^ (row & 7)) * 8),
                        (char*)Vb[s] + ch * 16);
        }
    };

    for (int c = 0; c < c0; ++c) {
        const bool act = c < myn;
        const int kv0 = (s ? (c0 + c) : c) * 64;
        if (act) stage(kv0);
        asm volatile("s_waitcnt vmcnt(0)" ::: "memory");
        __builtin_amdgcn_s_barrier();
        __builtin_amdgcn_sched_barrier(0);

        if (act) {
            f32x4 sa[4] = {};
            __builtin_amdgcn_s_setprio(1);
#pragma unroll
            for (int hh = 0; hh < 4; ++hh) {
                const int row = hh * 16 + l15;
#pragma unroll
                for (int ks = 0; ks < 4; ++ks) {
                    bf16x8 kf = *(const bf16x8*)((const char*)Kb[s]
                                  + row * 256 + (((ks * 4 + g4) ^ (row & 7)) * 16));
                    sa[hh] = mf(kf, qf[ks], sa[hh]);
                }
            }
            __builtin_amdgcn_s_setprio(0);

            float sv[4][4];
#pragma unroll
            for (int hh = 0; hh < 4; ++hh)
#pragma unroll
                for (int r = 0; r < 4; ++r)
                    sv[hh][r] = sa[hh][r] * scale;
            if (kv0 + 63 > q0) {
#pragma unroll
                for (int hh = 0; hh < 4; ++hh)
#pragma unroll
                    for (int r = 0; r < 4; ++r) {
                        int ki = kv0 + hh * 16 + g4 * 4 + r;
                        if (ki > qi) sv[hh][r] = -3e38f;
                    }
            }

            float m16;
            {
                float a = fmaxf(fmaxf(sv[0][0], sv[0][1]), fmaxf(sv[0][2], sv[0][3]));
                float b2 = fmaxf(fmaxf(sv[1][0], sv[1][1]), fmaxf(sv[1][2], sv[1][3]));
                float c2 = fmaxf(fmaxf(sv[2][0], sv[2][1]), fmaxf(sv[2][2], sv[2][3]));
                float d2 = fmaxf(fmaxf(sv[3][0], sv[3][1]), fmaxf(sv[3][2], sv[3][3]));
                m16 = fmaxf(fmaxf(a, b2), fmaxf(c2, d2));
            }
            m16 = fmaxf(m16, __shfl_xor(m16, 16));
            m16 = fmaxf(m16, __shfl_xor(m16, 32));

            if (__any(m16 > mrun)) {
                float mnew = fmaxf(mrun, m16);
                float corr = __expf(mrun - mnew);
                mrun = mnew;
                lrun *= corr;
                float cr[4];
#pragma unroll
                for (int r = 0; r < 4; ++r)
                    cr[r] = __int_as_float(__builtin_amdgcn_ds_bpermute(
                                addrQ + 4 * r, __float_as_int(corr)));
#pragma unroll
                for (int c2 = 0; c2 < 8; ++c2)
#pragma unroll
                    for (int r = 0; r < 4; ++r)
                        oacc[c2][r] *= cr[r];
            }

            float p[4][4];
            float ps = 0.f;
#pragma unroll
            for (int hh = 0; hh < 4; ++hh)
#pragma unroll
                for (int r = 0; r < 4; ++r) {
                    float pe = __expf(sv[hh][r] - mrun);
                    p[hh][r] = pe;
                    ps += pe;
                }
            ps += __shfl_xor(ps, 16);
            ps += __shfl_xor(ps, 32);
            lrun += ps;

            unsigned pk[4][2];
#pragma unroll
            for (int hh = 0; hh < 4; ++hh) {
                asm("v_cvt_pk_bf16_f32 %0, %1, %2"
                    : "=v"(pk[hh][0]) : "v"(p[hh][0]), "v"(p[hh][1]));
                asm("v_cvt_pk_bf16_f32 %0, %1, %2"
                    : "=v"(pk[hh][1]) : "v"(p[hh][2]), "v"(p[hh][3]));
            }
            int ex[4][2][2];
#pragma unroll
            for (int hh = 0; hh < 4; ++hh)
#pragma unroll
                for (int ii = 0; ii < 2; ++ii) {
                    ex[hh][ii][0] = __builtin_amdgcn_ds_bpermute(addrA, (int)pk[hh][ii]);
                    ex[hh][ii][1] = __builtin_amdgcn_ds_bpermute(addrB, (int)pk[hh][ii]);
                }
            union { int w[4]; bf16x8 v; } pu0, pu1;
#pragma unroll
            for (int jw = 0; jw < 4; ++jw) {
                pu0.w[jw] = hb ? ex[1][jw & 1][jw >> 1] : ex[0][jw & 1][jw >> 1];
                pu1.w[jw] = hb ? ex[3][jw & 1][jw >> 1] : ex[2][jw & 1][jw >> 1];
            }
            bf16x8 pa0 = pu0.v;
            bf16x8 pa1 = pu1.v;

            __builtin_amdgcn_s_setprio(1);
#pragma unroll
            for (int c2 = 0; c2 < 8; ++c2) {
                const int d = c2 * 16 + l15;
                bf16x8 vf0 = *(const bf16x8*)((const char*)Vb[s]
                              + d * 128 + ((g4 ^ (d & 7)) * 16));
                oacc[c2] = mf(pa0, vf0, oacc[c2]);
                bf16x8 vf1 = *(const bf16x8*)((const char*)Vb[s]
                              + d * 128 + ((((4 + g4) ^ (d & 7))) * 16));
                oacc[c2] = mf(pa1, vf1, oacc[c2]);
            }
            __builtin_amdgcn_s_setprio(0);
        }
        __builtin_amdgcn_s_barrier();
    }

    float* KbF = (float*)&Kb[0][0];
    if (s == 1) {
        MergeML[grp][0][lane] = mrun;
        MergeML[grp][1][lane] = lrun;
#pragma unroll
        for (int c2 = 0; c2 < 8; ++c2)
#pragma unroll
            for (int r = 0; r < 4; ++r)
                KbF[grp * 2048 + (c2 * 4 + r) * 64 + lane] = oacc[c2][r];
    }
    asm volatile("s_waitcnt lgkmcnt(0)" ::: "memory");
    __builtin_amdgcn_s_barrier();

    if (s == 0) {
        float m1 = MergeML[grp][0][lane];
        float l1 = MergeML[grp][1][lane];
        float mg = fmaxf(mrun, m1);
        float a0 = __expf(mrun - mg);
        float a1 = __expf(m1 - mg);
        float L  = lrun * a0 + l1 * a1;
        float ar0[4], ar1[4], Lr[4];
#pragma unroll
        for (int r = 0; r < 4; ++r) {
            ar0[r] = __int_as_float(__builtin_amdgcn_ds_bpermute(
                         addrQ + 4 * r, __float_as_int(a0)));
            ar1[r] = __int_as_float(__builtin_amdgcn_ds_bpermute(
                         addrQ + 4 * r, __float_as_int(a1)));
            Lr[r]  = __int_as_float(__builtin_amdgcn_ds_bpermute(
                         addrQ + 4 * r, __float_as_int(L)));
        }
#pragma unroll
        for (int c2 = 0; c2 < 8; ++c2)
#pragma unroll
            for (int r = 0; r < 4; ++r) {
                float oex = KbF[grp * 2048 + (c2 * 4 + r) * 64 + lane];
                float v = (oacc[c2][r] * ar0[r] + oex * ar1[r]) / Lr[r];
                O[(size_t)(q0 + g4 * 4 + r) * (kH * kD) + h * kD + c2 * 16 + l15] = f2bf(v);
            }
    }
}

}  // namespace

extern "C" void kernel_launch(void* const* d_in, const int* in_sizes, int n_in,
                              void* d_out, int out_size, void* d_ws, size_t ws_size,
                              hipStream_t stream) {
    (void)in_sizes; (void)n_in; (void)out_size; (void)ws_size;

    const int*   positions = (const int*)  d_in[0];
    const float* hidden    = (const float*)d_in[1];
    const float* wq  = (const float*)d_in[2];
    const float* wk  = (const float*)d_in[3];
    const float* wv  = (const float*)d_in[4];
    const float* wo  = (const float*)d_in[5];
    const float* qnw = (const float*)d_in[6];
    const float* knw = (const float*)d_in[7];
    const float* ln1 = (const float*)d_in[8];
    const float* ln2 = (const float*)d_in[9];
    const float* wg  = (const float*)d_in[10];
    const float* wu  = (const float*)d_in[11];
    const float* wd  = (const float*)d_in[12];

    char* ws = (char*)d_ws;
    unsigned short* WQKV = (unsigned short*)(ws + 0);          // 4096x2048 bf16
    unsigned short* WO   = (unsigned short*)(ws + 16777216);   // 2048x2048
    unsigned short* WG   = (unsigned short*)(ws + 25165824);   // 6144x2048
    unsigned short* WU   = (unsigned short*)(ws + 50331648);   // 6144x2048
    unsigned short* WD   = (unsigned short*)(ws + 75497472);   // 2048x6144
    unsigned short* XN1  = (unsigned short*)(ws + 100663296);  // T x 2048
    unsigned short* OATT = (unsigned short*)(ws + 109051904);  // T x 2048
    float*          H1   = (float*)(ws + 117440512);           // T x 2048 fp32
    unsigned short* XN2  = (unsigned short*)(ws + 134217728);  // T x 2048
    unsigned short* QKVB = (unsigned short*)(ws + 142606336);  // T x 4096 bf16
    unsigned short* QB   = (unsigned short*)(ws + 176160768);  // T x 2048
    unsigned short* KB   = (unsigned short*)(ws + 184549376);  // T x 1024
    unsigned short* VT   = (unsigned short*)(ws + 188743680);  // 1024 x T
    unsigned short* ACT  = (unsigned short*)(ws + 167772160);  // T x 6144

    // O-proj split-K4 partials (QKVB span + QB/KB + WQKV dead at that point)
    float* OP0 = (float*)(ws + 142606336);
    float* OP1 = (float*)(ws + 159383552);
    float* OP2 = (float*)(ws + 176160768);
    float* OP3 = (float*)(ws + 0);
    // down split-K4 partials (WQKV / WO / WG-mid / OP0-span dead by then)
    float* DP0 = (float*)(ws + 0);
    float* DP1 = (float*)(ws + 16777216);
    float* DP2 = (float*)(ws + 33554432);
    float* DP3 = (float*)(ws + 142606336);

    // single fused weight conversion (wq|wk|wv|wo|wg|wu|wd -> ws bf16 prefix)
    cvt_all<<<dim3(49152), dim3(256), 0, stream>>>(
        wq, wk, wv, wo, wg, wu, wd, (ushort4*)ws);

    rmsnorm_k<<<dim3(kT), dim3(256), 0, stream>>>(hidden, ln1, XN1);

    // QKV GEMM: 128x256 tile, grid 16x16 = 256 exact, bf16 output
    gemm128<1><<<dim3(4096 / 256, kT / 128), dim3(512), 0, stream>>>(
        XN1, WQKV, QKVB, kT, 4096, kHid, kHid, nullptr, nullptr);

    qknorm_rope<<<dim3(kT, 6), dim3(256), 0, stream>>>(QKVB, positions, qnw, knw, QB, KB);
    vtrans<<<dim3(kT / 32, 1024 / 32), dim3(256), 0, stream>>>(QKVB, VT);

    attn_fwd5<<<dim3(kHK, kT / 32), dim3(512), 0, stream>>>(QB, KB, VT, OATT);

    // O-proj: 256x256 split-K4 (grid 8x8x4 = 256 exact) -> partials
    gemm256<4><<<dim3(kHid / 256, kT / 256, 4), dim3(512), 0, stream>>>(
        OATT, WO, nullptr, kT, kHid, kHid, 512, OP0, OP1, OP2, OP3);
    // fused: H1 = sum(partials) + hidden; XN2 = rmsnorm(H1)*ln2
    rmsnorm_red4<<<dim3(kT), dim3(256), 0, stream>>>(
        OP0, OP1, OP2, OP3, hidden, ln2, H1, XN2);

    // fused gate+up GEMM: 256x96 tile, grid 64x8 = 512 (A-panel XCD swizzle)
    gemm_gu<<<dim3(kFF / 96, kT / 256), dim3(512), 0, stream>>>(XN2, WG, WU, ACT);

    // down: 256x256 split-K4 (KS=1536, grid 8x8x4 = 256 exact) -> partials
    gemm256<4><<<dim3(kHid / 256, kT / 256, 4), dim3(512), 0, stream>>>(
        ACT, WD, nullptr, kT, kHid, kFF, 1536, DP0, DP1, DP2, DP3);
    reduce4<<<dim3(kT * kHid / 4 / 256), dim3(256), 0, stream>>>(
        DP0, DP1, DP2, DP3, H1, (float*)d_out, kT * kHid / 4);
}

// Round 19
// 363.547 us; speedup vs baseline: 1.0608x; 1.0287x over previous
//
#include <hip/hip_runtime.h>
#include <hip/hip_bf16.h>
#include <stdint.h>

namespace {

constexpr int kT   = 2048;
constexpr int kHid = 2048;
constexpr int kH   = 16;
constexpr int kHK  = 8;
constexpr int kD   = 128;
constexpr int kFF  = 6144;

using bf16x8 = __attribute__((ext_vector_type(8))) short;
using f32x4  = __attribute__((ext_vector_type(4))) float;

__device__ __forceinline__ float bf2f(unsigned short u) {
    return __uint_as_float(((unsigned)u) << 16);
}
__device__ __forceinline__ unsigned short f2bf(float f) {
    unsigned u = __float_as_uint(f);
    return (unsigned short)((u + 0x7fffu + ((u >> 16) & 1u)) >> 16);
}
__device__ __forceinline__ void gload_lds16(const void* g, void* l) {
    __builtin_amdgcn_global_load_lds(
        (__attribute__((address_space(1))) void*)g,
        (__attribute__((address_space(3))) void*)l, 16, 0, 0);
}
__device__ __forceinline__ f32x4 mf(bf16x8 a, bf16x8 b, f32x4 c) {
    return __builtin_amdgcn_mfma_f32_16x16x32_bf16(a, b, c, 0, 0, 0);
}

// One-shot fp32->bf16 conversion of all seven weight matrices into the
// contiguous ws prefix. Region boundaries in float4 units:
//   wq [0,1048576) wk [..,1572864) wv [..,2097152) wo [..,3145728)
//   wg [..,6291456) wu [..,9437184) wd [..,12582912)
__global__ __launch_bounds__(256)
void cvt_all(const float* __restrict__ wq, const float* __restrict__ wk,
             const float* __restrict__ wv, const float* __restrict__ wo,
             const float* __restrict__ wg, const float* __restrict__ wu,
             const float* __restrict__ wd, ushort4* __restrict__ dst) {
    int i = blockIdx.x * 256 + threadIdx.x;
    if (i >= 12582912) return;
    const float4* src;
    int base;
    if (i < 3145728) {
        if (i < 1048576)      { src = (const float4*)wq; base = 0; }
        else if (i < 1572864) { src = (const float4*)wk; base = 1048576; }
        else if (i < 2097152) { src = (const float4*)wv; base = 1572864; }
        else                  { src = (const float4*)wo; base = 2097152; }
    } else {
        if (i < 6291456)      { src = (const float4*)wg; base = 3145728; }
        else if (i < 9437184) { src = (const float4*)wu; base = 6291456; }
        else                  { src = (const float4*)wd; base = 9437184; }
    }
    float4 v = src[i - base];
    ushort4 o;
    o.x = f2bf(v.x); o.y = f2bf(v.y); o.z = f2bf(v.z); o.w = f2bf(v.w);
    dst[i] = o;
}

// out = p0+p1+p2+p3+res (all fp32), vectorized x4
__global__ __launch_bounds__(256)
void reduce4(const float* __restrict__ p0, const float* __restrict__ p1,
             const float* __restrict__ p2, const float* __restrict__ p3,
             const float* __restrict__ res, float* __restrict__ out, int n4) {
    int i = blockIdx.x * 256 + threadIdx.x;
    if (i < n4) {
        float4 a = ((const float4*)p0)[i];
        float4 b = ((const float4*)p1)[i];
        float4 c = ((const float4*)p2)[i];
        float4 d = ((const float4*)p3)[i];
        float4 r = ((const float4*)res)[i];
        float4 o;
        o.x = a.x + b.x + c.x + d.x + r.x;
        o.y = a.y + b.y + c.y + d.y + r.y;
        o.z = a.z + b.z + c.z + d.z + r.z;
        o.w = a.w + b.w + c.w + d.w + r.w;
        ((float4*)out)[i] = o;
    }
}

// RMSNorm over HID=2048, fp32 in -> bf16 out. 1 block per row.
__global__ __launch_bounds__(256)
void rmsnorm_k(const float* __restrict__ x, const float* __restrict__ w,
               unsigned short* __restrict__ out) {
    const int row = blockIdx.x;
    const int tid = threadIdx.x;
    const float4* xr = (const float4*)(x + (size_t)row * kHid);
    float4 v0 = xr[tid];
    float4 v1 = xr[tid + 256];
    float ss = v0.x*v0.x + v0.y*v0.y + v0.z*v0.z + v0.w*v0.w
             + v1.x*v1.x + v1.y*v1.y + v1.z*v1.z + v1.w*v1.w;
#pragma unroll
    for (int m = 1; m < 64; m <<= 1) ss += __shfl_xor(ss, m);
    __shared__ float red[4];
    if ((tid & 63) == 0) red[tid >> 6] = ss;
    __syncthreads();
    float tot = red[0] + red[1] + red[2] + red[3];
    float rs = rsqrtf(tot * (1.0f / kHid) + 1e-6f);
    const float4* wv = (const float4*)w;
    float4 w0 = wv[tid], w1 = wv[tid + 256];
    ushort4 o0, o1;
    o0.x = f2bf(v0.x * rs * w0.x); o0.y = f2bf(v0.y * rs * w0.y);
    o0.z = f2bf(v0.z * rs * w0.z); o0.w = f2bf(v0.w * rs * w0.w);
    o1.x = f2bf(v1.x * rs * w1.x); o1.y = f2bf(v1.y * rs * w1.y);
    o1.z = f2bf(v1.z * rs * w1.z); o1.w = f2bf(v1.w * rs * w1.w);
    ushort4* orow = (ushort4*)(out + (size_t)row * kHid);
    orow[tid] = o0;
    orow[tid + 256] = o1;
}

// Fused: h = p0+p1+res -> H1; XN2 = rmsnorm(h)*w (bf16). 1 block/row.
__global__ __launch_bounds__(256)
void rmsnorm_red2(const float* __restrict__ p0, const float* __restrict__ p1,
                  const float* __restrict__ res, const float* __restrict__ w,
                  float* __restrict__ H, unsigned short* __restrict__ out) {
    const int row = blockIdx.x;
    const int tid = threadIdx.x;
    const size_t base = (size_t)row * kHid;
    float4 v0, v1;
    {
        const float4* a = (const float4*)(p0 + base);
        const float4* b = (const float4*)(p1 + base);
        const float4* r = (const float4*)(res + base);
        float4 a0 = a[tid], b0 = b[tid], r0 = r[tid];
        v0.x = a0.x + b0.x + r0.x;
        v0.y = a0.y + b0.y + r0.y;
        v0.z = a0.z + b0.z + r0.z;
        v0.w = a0.w + b0.w + r0.w;
        float4 a1 = a[tid + 256], b1 = b[tid + 256], r1 = r[tid + 256];
        v1.x = a1.x + b1.x + r1.x;
        v1.y = a1.y + b1.y + r1.y;
        v1.z = a1.z + b1.z + r1.z;
        v1.w = a1.w + b1.w + r1.w;
    }
    ((float4*)(H + base))[tid] = v0;
    ((float4*)(H + base))[tid + 256] = v1;
    float ss = v0.x*v0.x + v0.y*v0.y + v0.z*v0.z + v0.w*v0.w
             + v1.x*v1.x + v1.y*v1.y + v1.z*v1.z + v1.w*v1.w;
#pragma unroll
    for (int m = 1; m < 64; m <<= 1) ss += __shfl_xor(ss, m);
    __shared__ float red[4];
    if ((tid & 63) == 0) red[tid >> 6] = ss;
    __syncthreads();
    float tot = red[0] + red[1] + red[2] + red[3];
    float rs = rsqrtf(tot * (1.0f / kHid) + 1e-6f);
    const float4* wv = (const float4*)w;
    float4 w0 = wv[tid], w1 = wv[tid + 256];
    ushort4 o0, o1;
    o0.x = f2bf(v0.x * rs * w0.x); o0.y = f2bf(v0.y * rs * w0.y);
    o0.z = f2bf(v0.z * rs * w0.z); o0.w = f2bf(v0.w * rs * w0.w);
    o1.x = f2bf(v1.x * rs * w1.x); o1.y = f2bf(v1.y * rs * w1.y);
    o1.z = f2bf(v1.z * rs * w1.z); o1.w = f2bf(v1.w * rs * w1.w);
    ushort4* orow = (ushort4*)(out + base);
    orow[tid] = o0;
    orow[tid + 256] = o1;
}

// -------- 256x256 8-phase GEMM (proven; EPI4 split-K partials) --------------
template <int EPI>
__global__ __launch_bounds__(512, 2)
void gemm256(const unsigned short* __restrict__ A,
             const unsigned short* __restrict__ B,
             void* __restrict__ C,
             int M, int N, int K, int KS,
             float* __restrict__ p0, float* __restrict__ p1,
             float* __restrict__ p2, float* __restrict__ p3) {
    __shared__ unsigned short smem[2][4][128 * 64];  // 128 KiB

    const int tid  = threadIdx.x;
    const int lane = tid & 63;
    const int l15  = lane & 15;
    const int g4   = lane >> 4;
    const int wid  = tid >> 6;
    const int wr   = wid >> 2;
    const int wc   = wid & 3;
    const int bm   = blockIdx.y * 256;
    const int bn   = blockIdx.x * 256;
    const int kb   = (EPI == 4) ? blockIdx.z * KS : 0;
    const int NT   = ((EPI == 4) ? KS : K) >> 6;
    const int NI   = NT >> 1;

    f32x4 acc[8][4] = {};

    auto stage = [&](int b, int reg, int t) {
        const unsigned short* Base = (reg < 2) ? A : B;
        const int br = ((reg < 2) ? bm : bn) + (reg & 1) * 128;
#pragma unroll
        for (int i = 0; i < 2; ++i) {
            int ch   = tid + i * 512;
            int row  = ch >> 3;
            int slot = (ch & 7) ^ (row & 7);
            gload_lds16(Base + (size_t)(br + row) * K + kb + t * 64 + slot * 8,
                        (char*)&smem[b][reg][0] + ch * 16);
        }
    };
    auto rdA = [&](int b, int m, int ks) {
        int row = m * 16 + l15;
        return *(const bf16x8*)((const char*)&smem[b][wr][0]
               + row * 128 + (((ks * 4 + g4) ^ (row & 7)) * 16));
    };
    auto rdB = [&](int b, int n, int ks) {
        int row = wc * 64 + n * 16 + l15;
        return *(const bf16x8*)((const char*)&smem[b][2 + (row >> 7)][0]
               + (row & 127) * 128 + (((ks * 4 + g4) ^ (row & 7)) * 16));
    };

    stage(0, 2, 0); stage(0, 3, 0); stage(0, 0, 0); stage(0, 1, 0);
    stage(1, 2, 1); stage(1, 3, 1); stage(1, 0, 1);
    asm volatile("s_waitcnt vmcnt(6)" ::: "memory");
    __builtin_amdgcn_s_barrier();

    for (int i = 0; i < NI; ++i) {
        const int e  = 2 * i;
        const int o  = e + 1;
        const bool pf = (e + 2 < NT);
        bf16x8 af[4][2], bfr[4][2];

#pragma unroll
        for (int m = 0; m < 4; ++m) { af[m][0] = rdA(0, m, 0); af[m][1] = rdA(0, m, 1); }
#pragma unroll
        for (int n = 0; n < 4; ++n) { bfr[n][0] = rdB(0, n, 0); bfr[n][1] = rdB(0, n, 1); }
        stage(1, 1, o);
        __builtin_amdgcn_s_barrier();
        asm volatile("s_waitcnt lgkmcnt(0)" ::: "memory");
        __builtin_amdgcn_sched_barrier(0);
        __builtin_amdgcn_s_setprio(1);
#pragma unroll
        for (int m = 0; m < 4; ++m)
#pragma unroll
            for (int n = 0; n < 2; ++n) {
                acc[m][n] = mf(af[m][0], bfr[n][0], acc[m][n]);
                acc[m][n] = mf(af[m][1], bfr[n][1], acc[m][n]);
            }
        __builtin_amdgcn_s_setprio(0);
        __builtin_amdgcn_s_barrier();

        if (pf) stage(0, 2, e + 2);
        __builtin_amdgcn_s_barrier();
        __builtin_amdgcn_s_setprio(1);
#pragma unroll
        for (int m = 0; m < 4; ++m)
#pragma unroll
            for (int n = 2; n < 4; ++n) {
                acc[m][n] = mf(af[m][0], bfr[n][0], acc[m][n]);
                acc[m][n] = mf(af[m][1], bfr[n][1], acc[m][n]);
            }
        __builtin_amdgcn_s_setprio(0);
        __builtin_amdgcn_s_barrier();

#pragma unroll
        for (int m = 0; m < 4; ++m) { af[m][0] = rdA(0, 4 + m, 0); af[m][1] = rdA(0, 4 + m, 1); }
        if (pf) stage(0, 3, e + 2);
        __builtin_amdgcn_s_barrier();
        asm volatile("s_waitcnt lgkmcnt(0)" ::: "memory");
        __builtin_amdgcn_sched_barrier(0);
        __builtin_amdgcn_s_setprio(1);
#pragma unroll
        for (int m = 0; m < 4; ++m)
#pragma unroll
            for (int n = 0; n < 2; ++n) {
                acc[4 + m][n] = mf(af[m][0], bfr[n][0], acc[4 + m][n]);
                acc[4 + m][n] = mf(af[m][1], bfr[n][1], acc[4 + m][n]);
            }
        __builtin_amdgcn_s_setprio(0);
        __builtin_amdgcn_s_barrier();

        if (pf) stage(0, 0, e + 2);
        __builtin_amdgcn_s_barrier();
        __builtin_amdgcn_s_setprio(1);
#pragma unroll
        for (int m = 0; m < 4; ++m)
#pragma unroll
            for (int n = 2; n < 4; ++n) {
                acc[4 + m][n] = mf(af[m][0], bfr[n][0], acc[4 + m][n]);
                acc[4 + m][n] = mf(af[m][1], bfr[n][1], acc[4 + m][n]);
            }
        __builtin_amdgcn_s_setprio(0);
        if (pf) asm volatile("s_waitcnt vmcnt(6)" ::: "memory");
        else    asm volatile("s_waitcnt vmcnt(0)" ::: "memory");
        __builtin_amdgcn_s_barrier();

#pragma unroll
        for (int m = 0; m < 4; ++m) { af[m][0] = rdA(1, m, 0); af[m][1] = rdA(1, m, 1); }
#pragma unroll
        for (int n = 0; n < 4; ++n) { bfr[n][0] = rdB(1, n, 0); bfr[n][1] = rdB(1, n, 1); }
        if (pf) stage(0, 1, e + 2);
        __builtin_amdgcn_s_barrier();
        asm volatile("s_waitcnt lgkmcnt(0)" ::: "memory");
        __builtin_amdgcn_sched_barrier(0);
        __builtin_amdgcn_s_setprio(1);
#pragma unroll
        for (int m = 0; m < 4; ++m)
#pragma unroll
            for (int n = 0; n < 2; ++n) {
                acc[m][n] = mf(af[m][0], bfr[n][0], acc[m][n]);
                acc[m][n] = mf(af[m][1], bfr[n][1], acc[m][n]);
            }
        __builtin_amdgcn_s_setprio(0);
        __builtin_amdgcn_s_barrier();

        if (pf) stage(1, 2, o + 2);
        __builtin_amdgcn_s_barrier();
        __builtin_amdgcn_s_setprio(1);
#pragma unroll
        for (int m = 0; m < 4; ++m)
#pragma unroll
            for (int n = 2; n < 4; ++n) {
                acc[m][n] = mf(af[m][0], bfr[n][0], acc[m][n]);
                acc[m][n] = mf(af[m][1], bfr[n][1], acc[m][n]);
            }
        __builtin_amdgcn_s_setprio(0);
        __builtin_amdgcn_s_barrier();

#pragma unroll
        for (int m = 0; m < 4; ++m) { af[m][0] = rdA(1, 4 + m, 0); af[m][1] = rdA(1, 4 + m, 1); }
        if (pf) stage(1, 3, o + 2);
        __builtin_amdgcn_s_barrier();
        asm volatile("s_waitcnt lgkmcnt(0)" ::: "memory");
        __builtin_amdgcn_sched_barrier(0);
        __builtin_amdgcn_s_setprio(1);
#pragma unroll
        for (int m = 0; m < 4; ++m)
#pragma unroll
            for (int n = 0; n < 2; ++n) {
                acc[4 + m][n] = mf(af[m][0], bfr[n][0], acc[4 + m][n]);
                acc[4 + m][n] = mf(af[m][1], bfr[n][1], acc[4 + m][n]);
            }
        __builtin_amdgcn_s_setprio(0);
        __builtin_amdgcn_s_barrier();

        if (pf) stage(1, 0, o + 2);
        __builtin_amdgcn_s_barrier();
        __builtin_amdgcn_s_setprio(1);
#pragma unroll
        for (int m = 0; m < 4; ++m)
#pragma unroll
            for (int n = 2; n < 4; ++n) {
                acc[4 + m][n] = mf(af[m][0], bfr[n][0], acc[4 + m][n]);
                acc[4 + m][n] = mf(af[m][1], bfr[n][1], acc[4 + m][n]);
            }
        __builtin_amdgcn_s_setprio(0);
        if (pf) asm volatile("s_waitcnt vmcnt(6)" ::: "memory");
        __builtin_amdgcn_s_barrier();
    }

    float* P = nullptr;
    if (EPI == 4) {
        const int z = blockIdx.z;
        P = (z == 0) ? p0 : (z == 1) ? p1 : (z == 2) ? p2 : p3;
    }
#pragma unroll
    for (int m = 0; m < 8; ++m) {
#pragma unroll
        for (int n = 0; n < 4; ++n) {
            int row = bm + wr * 128 + m * 16 + g4 * 4;
            int col = bn + wc * 64 + n * 16 + l15;
#pragma unroll
            for (int r = 0; r < 4; ++r) {
                size_t idx = (size_t)(row + r) * N + col;
                float v = acc[m][n][r];
                if (EPI == 0) ((float*)C)[idx] = v;
                else          P[idx] = v;
            }
        }
    }
}

// -------- 128M x 256N 8-phase GEMM (proven; QKV + O-proj) ------------------
// EPI: 0 = fp32 store, 1 = bf16 store, 4 = split-K2 fp32 partials.
template <int EPI>
__global__ __launch_bounds__(512, 2)
void gemm128(const unsigned short* __restrict__ A,
             const unsigned short* __restrict__ B,
             void* __restrict__ C,
             int M, int N, int K, int KS,
             float* __restrict__ p0, float* __restrict__ p1) {
    __shared__ unsigned short smem[2][3][128 * 64];  // 96 KiB

    const int tid  = threadIdx.x;
    const int lane = tid & 63;
    const int l15  = lane & 15;
    const int g4   = lane >> 4;
    const int wid  = tid >> 6;
    const int wr   = wid >> 2;
    const int wc   = wid & 3;
    const int bm   = blockIdx.y * 128;
    const int bn   = blockIdx.x * 256;
    const int kb   = (EPI == 4) ? blockIdx.z * KS : 0;
    const int NT   = ((EPI == 4) ? KS : K) >> 6;
    const int NI   = NT >> 1;

    f32x4 acc[4][4] = {};

    auto stage = [&](int b, int reg, int t) {
        const unsigned short* Base = (reg == 0) ? A : B;
        const int br = (reg == 0) ? bm : bn + (reg - 1) * 128;
#pragma unroll
        for (int i = 0; i < 2; ++i) {
            int ch   = tid + i * 512;
            int row  = ch >> 3;
            int slot = (ch & 7) ^ (row & 7);
            gload_lds16(Base + (size_t)(br + row) * K + kb + t * 64 + slot * 8,
                        (char*)&smem[b][reg][0] + ch * 16);
        }
    };
    auto rdA = [&](int b, int m, int ks) {
        int row = wr * 64 + m * 16 + l15;
        return *(const bf16x8*)((const char*)&smem[b][0][0]
               + row * 128 + (((ks * 4 + g4) ^ (row & 7)) * 16));
    };
    auto rdB = [&](int b, int n, int ks) {
        int row = wc * 64 + n * 16 + l15;
        return *(const bf16x8*)((const char*)&smem[b][1 + (row >> 7)][0]
               + (row & 127) * 128 + (((ks * 4 + g4) ^ (row & 7)) * 16));
    };

    stage(0, 1, 0); stage(0, 2, 0); stage(0, 0, 0);
    stage(1, 1, 1); stage(1, 2, 1);
    asm volatile("s_waitcnt vmcnt(4)" ::: "memory");
    __builtin_amdgcn_s_barrier();

    for (int i = 0; i < NI; ++i) {
        const int e  = 2 * i;
        const int o  = e + 1;
        const bool pf = (e + 2 < NT);
        bf16x8 af[4][2], bfr[4][2];

#pragma unroll
        for (int m = 0; m < 4; ++m) { af[m][0] = rdA(0, m, 0); af[m][1] = rdA(0, m, 1); }
#pragma unroll
        for (int n = 0; n < 4; ++n) { bfr[n][0] = rdB(0, n, 0); bfr[n][1] = rdB(0, n, 1); }
        stage(1, 0, o);
        __builtin_amdgcn_s_barrier();
        asm volatile("s_waitcnt lgkmcnt(0)" ::: "memory");
        __builtin_amdgcn_sched_barrier(0);
        __builtin_amdgcn_s_setprio(1);
#pragma unroll
        for (int m = 0; m < 4; ++m) {
            acc[m][0] = mf(af[m][0], bfr[0][0], acc[m][0]);
            acc[m][0] = mf(af[m][1], bfr[0][1], acc[m][0]);
        }
        __builtin_amdgcn_s_setprio(0);
        __builtin_amdgcn_s_barrier();

        if (pf) stage(0, 1, e + 2);
        __builtin_amdgcn_s_barrier();
        __builtin_amdgcn_s_setprio(1);
#pragma unroll
        for (int m = 0; m < 4; ++m) {
            acc[m][1] = mf(af[m][0], bfr[1][0], acc[m][1]);
            acc[m][1] = mf(af[m][1], bfr[1][1], acc[m][1]);
        }
        __builtin_amdgcn_s_setprio(0);
        __builtin_amdgcn_s_barrier();

        if (pf) stage(0, 2, e + 2);
        __builtin_amdgcn_s_barrier();
        __builtin_amdgcn_s_setprio(1);
#pragma unroll
        for (int m = 0; m < 4; ++m) {
            acc[m][2] = mf(af[m][0], bfr[2][0], acc[m][2]);
            acc[m][2] = mf(af[m][1], bfr[2][1], acc[m][2]);
        }
        __builtin_amdgcn_s_setprio(0);
        __builtin_amdgcn_s_barrier();

        __builtin_amdgcn_s_setprio(1);
#pragma unroll
        for (int m = 0; m < 4; ++m) {
            acc[m][3] = mf(af[m][0], bfr[3][0], acc[m][3]);
            acc[m][3] = mf(af[m][1], bfr[3][1], acc[m][3]);
        }
        __builtin_amdgcn_s_setprio(0);
        if (pf) asm volatile("s_waitcnt vmcnt(4)" ::: "memory");
        else    asm volatile("s_waitcnt vmcnt(0)" ::: "memory");
        __builtin_amdgcn_s_barrier();

#pragma unroll
        for (int m = 0; m < 4; ++m) { af[m][0] = rdA(1, m, 0); af[m][1] = rdA(1, m, 1); }
#pragma unroll
        for (int n = 0; n < 4; ++n) { bfr[n][0] = rdB(1, n, 0); bfr[n][1] = rdB(1, n, 1); }
        if (pf) stage(0, 0, e + 2);
        __builtin_amdgcn_s_barrier();
        asm volatile("s_waitcnt lgkmcnt(0)" ::: "memory");
        __builtin_amdgcn_sched_barrier(0);
        __builtin_amdgcn_s_setprio(1);
#pragma unroll
        for (int m = 0; m < 4; ++m) {
            acc[m][0] = mf(af[m][0], bfr[0][0], acc[m][0]);
            acc[m][0] = mf(af[m][1], bfr[0][1], acc[m][0]);
        }
        __builtin_amdgcn_s_setprio(0);
        __builtin_amdgcn_s_barrier();

        if (pf) stage(1, 1, o + 2);
        __builtin_amdgcn_s_barrier();
        __builtin_amdgcn_s_setprio(1);
#pragma unroll
        for (int m = 0; m < 4; ++m) {
            acc[m][1] = mf(af[m][0], bfr[1][0], acc[m][1]);
            acc[m][1] = mf(af[m][1], bfr[1][1], acc[m][1]);
        }
        __builtin_amdgcn_s_setprio(0);
        __builtin_amdgcn_s_barrier();

        if (pf) stage(1, 2, o + 2);
        __builtin_amdgcn_s_barrier();
        __builtin_amdgcn_s_setprio(1);
#pragma unroll
        for (int m = 0; m < 4; ++m) {
            acc[m][2] = mf(af[m][0], bfr[2][0], acc[m][2]);
            acc[m][2] = mf(af[m][1], bfr[2][1], acc[m][2]);
        }
        __builtin_amdgcn_s_setprio(0);
        __builtin_amdgcn_s_barrier();

        __builtin_amdgcn_s_setprio(1);
#pragma unroll
        for (int m = 0; m < 4; ++m) {
            acc[m][3] = mf(af[m][0], bfr[3][0], acc[m][3]);
            acc[m][3] = mf(af[m][1], bfr[3][1], acc[m][3]);
        }
        __builtin_amdgcn_s_setprio(0);
        if (pf) asm volatile("s_waitcnt vmcnt(4)" ::: "memory");
        __builtin_amdgcn_s_barrier();
    }

    float* P = nullptr;
    if (EPI == 4) P = (blockIdx.z == 0) ? p0 : p1;
#pragma unroll
    for (int m = 0; m < 4; ++m) {
#pragma unroll
        for (int n = 0; n < 4; ++n) {
            int row = bm + wr * 64 + m * 16 + g4 * 4;
            int col = bn + wc * 64 + n * 16 + l15;
#pragma unroll
            for (int r = 0; r < 4; ++r) {
                size_t idx = (size_t)(row + r) * N + col;
                float v = acc[m][n][r];
                if (EPI == 0)      ((float*)C)[idx] = v;
                else if (EPI == 1) ((unsigned short*)C)[idx] = f2bf(v);
                else               P[idx] = v;
            }
        }
    }
}

// -------- fused gate+up GEMM v2: tile 256M x 96FF, grid 64x8 = 512 ---------
// T1 A-panel-resident remap (kept from R18: measured best-total build).
__global__ __launch_bounds__(512, 2)
void gemm_gu(const unsigned short* __restrict__ A,
             const unsigned short* __restrict__ WGp,
             const unsigned short* __restrict__ WUp,
             unsigned short* __restrict__ OUT) {
    __shared__ unsigned short smem[2][28672];  // 112 KiB

    const int tid  = threadIdx.x;
    const int lane = tid & 63;
    const int l15  = lane & 15;
    const int g4   = lane >> 4;
    const int wid  = tid >> 6;   // 0..7
    const int wr   = wid >> 1;   // 0..3  (64-row slice)
    const int wc   = wid & 1;    // 0..1  (48-col slice)
    const int id   = blockIdx.y * gridDim.x + blockIdx.x;
    const int byl  = id & 7;     // A panel (one per XCD)
    const int bxl  = id >> 3;    // 0..63
    const int bm   = byl * 256;
    const int bn   = bxl * 96;
    const int K    = kHid;
    const int NT   = K >> 6;     // 32
    const int NI   = NT >> 1;

    f32x4 accg[4][3] = {};
    f32x4 accu[4][3] = {};

    constexpr int OFF_A0 = 0;
    constexpr int OFF_A1 = 16384;
    constexpr int OFF_GU = 32768;

    auto stage_a = [&](int b, int half, int t) {
#pragma unroll
        for (int i = 0; i < 2; ++i) {
            int ch   = tid + i * 512;
            int row  = ch >> 3;
            int slot = (ch & 7) ^ (row & 7);
            gload_lds16(A + (size_t)(bm + half * 128 + row) * K + t * 64 + slot * 8,
                        (char*)&smem[b][0] + (half ? OFF_A1 : OFF_A0) + ch * 16);
        }
    };
    auto stage_gu = [&](int b, int t) {
#pragma unroll
        for (int i = 0; i < 3; ++i) {
            int ch   = tid + i * 512;
            int row  = ch >> 3;
            int slot = (ch & 7) ^ (row & 7);
            const unsigned short* Base = (row >= 96) ? WUp : WGp;
            int srow = bn + (row >= 96 ? row - 96 : row);
            gload_lds16(Base + (size_t)srow * K + t * 64 + slot * 8,
                        (char*)&smem[b][0] + OFF_GU + ch * 16);
        }
    };
    auto rdA = [&](int b, int m, int ks) {
        int rt  = wr * 64 + m * 16 + l15;
        int row = rt & 127;
        return *(const bf16x8*)((const char*)&smem[b][0]
               + (rt >> 7 ? OFF_A1 : OFF_A0)
               + row * 128 + (((ks * 4 + g4) ^ (row & 7)) * 16));
    };
    auto rdG = [&](int b, int n, int ks) {
        int row = wc * 48 + n * 16 + l15;
        return *(const bf16x8*)((const char*)&smem[b][0] + OFF_GU
               + row * 128 + (((ks * 4 + g4) ^ (row & 7)) * 16));
    };
    auto rdU = [&](int b, int n, int ks) {
        int row = 96 + wc * 48 + n * 16 + l15;
        return *(const bf16x8*)((const char*)&smem[b][0] + OFF_GU
               + row * 128 + (((ks * 4 + g4) ^ (row & 7)) * 16));
    };

    stage_a(0, 0, 0); stage_a(0, 1, 0); stage_gu(0, 0);
    stage_a(1, 0, 1); stage_a(1, 1, 1);
    asm volatile("s_waitcnt vmcnt(4)" ::: "memory");
    __builtin_amdgcn_s_barrier();

    for (int i = 0; i < NI; ++i) {
        const int e  = 2 * i;
        const int o  = e + 1;
        const bool pf = (e + 2 < NT);
        bf16x8 af[4][2], bg[3][2], bu[3][2];

#pragma unroll
        for (int m = 0; m < 4; ++m) { af[m][0] = rdA(0, m, 0); af[m][1] = rdA(0, m, 1); }
#pragma unroll
        for (int n = 0; n < 3; ++n) { bg[n][0] = rdG(0, n, 0); bg[n][1] = rdG(0, n, 1); }
        stage_gu(1, o);
        __builtin_amdgcn_s_barrier();
        asm volatile("s_waitcnt lgkmcnt(0)" ::: "memory");
        __builtin_amdgcn_sched_barrier(0);
        __builtin_amdgcn_s_setprio(1);
#pragma unroll
        for (int m = 0; m < 4; ++m)
#pragma unroll
            for (int n = 0; n < 3; ++n)
                accg[m][n] = mf(af[m][0], bg[n][0], accg[m][n]);
        __builtin_amdgcn_s_setprio(0);
        __builtin_amdgcn_s_barrier();

        if (pf) stage_a(0, 0, e + 2);
        __builtin_amdgcn_s_barrier();
        __builtin_amdgcn_s_setprio(1);
#pragma unroll
        for (int m = 0; m < 4; ++m)
#pragma unroll
            for (int n = 0; n < 3; ++n)
                accg[m][n] = mf(af[m][1], bg[n][1], accg[m][n]);
        __builtin_amdgcn_s_setprio(0);
        __builtin_amdgcn_s_barrier();

#pragma unroll
        for (int n = 0; n < 3; ++n) { bu[n][0] = rdU(0, n, 0); bu[n][1] = rdU(0, n, 1); }
        if (pf) stage_a(0, 1, e + 2);
        __builtin_amdgcn_s_barrier();
        asm volatile("s_waitcnt lgkmcnt(0)" ::: "memory");
        __builtin_amdgcn_sched_barrier(0);
        __builtin_amdgcn_s_setprio(1);
#pragma unroll
        for (int m = 0; m < 4; ++m)
#pragma unroll
            for (int n = 0; n < 3; ++n)
                accu[m][n] = mf(af[m][0], bu[n][0], accu[m][n]);
        __builtin_amdgcn_s_setprio(0);
        __builtin_amdgcn_s_barrier();

        if (pf) stage_gu(0, e + 2);
        __builtin_amdgcn_s_barrier();
        __builtin_amdgcn_s_setprio(1);
#pragma unroll
        for (int m = 0; m < 4; ++m)
#pragma unroll
            for (int n = 0; n < 3; ++n)
                accu[m][n] = mf(af[m][1], bu[n][1], accu[m][n]);
        __builtin_amdgcn_s_setprio(0);
        if (pf) asm volatile("s_waitcnt vmcnt(7)" ::: "memory");
        else    asm volatile("s_waitcnt vmcnt(0)" ::: "memory");
        __builtin_amdgcn_s_barrier();

#pragma unroll
        for (int m = 0; m < 4; ++m) { af[m][0] = rdA(1, m, 0); af[m][1] = rdA(1, m, 1); }
#pragma unroll
        for (int n = 0; n < 3; ++n) { bg[n][0] = rdG(1, n, 0); bg[n][1] = rdG(1, n, 1); }
        __builtin_amdgcn_s_barrier();
        asm volatile("s_waitcnt lgkmcnt(0)" ::: "memory");
        __builtin_amdgcn_sched_barrier(0);
        __builtin_amdgcn_s_setprio(1);
#pragma unroll
        for (int m = 0; m < 4; ++m)
#pragma unroll
            for (int n = 0; n < 3; ++n)
                accg[m][n] = mf(af[m][0], bg[n][0], accg[m][n]);
        __builtin_amdgcn_s_setprio(0);
        __builtin_amdgcn_s_barrier();

        if (pf) stage_a(1, 0, o + 2);
        __builtin_amdgcn_s_barrier();
        __builtin_amdgcn_s_setprio(1);
#pragma unroll
        for (int m = 0; m < 4; ++m)
#pragma unroll
            for (int n = 0; n < 3; ++n)
                accg[m][n] = mf(af[m][1], bg[n][1], accg[m][n]);
        __builtin_amdgcn_s_setprio(0);
        __builtin_amdgcn_s_barrier();

#pragma unroll
        for (int n = 0; n < 3; ++n) { bu[n][0] = rdU(1, n, 0); bu[n][1] = rdU(1, n, 1); }
        if (pf) stage_a(1, 1, o + 2);
        __builtin_amdgcn_s_barrier();
        asm volatile("s_waitcnt lgkmcnt(0)" ::: "memory");
        __builtin_amdgcn_sched_barrier(0);
        __builtin_amdgcn_s_setprio(1);
#pragma unroll
        for (int m = 0; m < 4; ++m)
#pragma unroll
            for (int n = 0; n < 3; ++n)
                accu[m][n] = mf(af[m][0], bu[n][0], accu[m][n]);
        __builtin_amdgcn_s_setprio(0);
        __builtin_amdgcn_s_barrier();

        __builtin_amdgcn_s_setprio(1);
#pragma unroll
        for (int m = 0; m < 4; ++m)
#pragma unroll
            for (int n = 0; n < 3; ++n)
                accu[m][n] = mf(af[m][1], bu[n][1], accu[m][n]);
        __builtin_amdgcn_s_setprio(0);
        if (pf) asm volatile("s_waitcnt vmcnt(4)" ::: "memory");
        __builtin_amdgcn_s_barrier();
    }

#pragma unroll
    for (int m = 0; m < 4; ++m) {
#pragma unroll
        for (int n = 0; n < 3; ++n) {
            int row = bm + wr * 64 + m * 16 + g4 * 4;
            int col = bn + wc * 48 + n * 16 + l15;
#pragma unroll
            for (int r = 0; r < 4; ++r) {
                float g = accg[m][n][r];
                float u = accu[m][n][r];
                OUT[(size_t)(row + r) * kFF + col] = f2bf(g / (1.0f + __expf(-g)) * u);
            }
        }
    }
}

// Fused per-head RMSNorm (D=128) + RoPE for q and k. Reads bf16 QKV.
__global__ __launch_bounds__(256)
void qknorm_rope(const unsigned short* __restrict__ qkv, const int* __restrict__ positions,
                 const float* __restrict__ qnw, const float* __restrict__ knw,
                 unsigned short* __restrict__ Qo, unsigned short* __restrict__ Ko) {
    const int t    = blockIdx.x;
    const int j    = blockIdx.y * 4 + (threadIdx.x >> 6);  // 0..23
    const int lane = threadIdx.x & 63;
    const unsigned short* src = qkv + (size_t)t * 4096 + j * 128;
    float x1 = bf2f(src[lane]);
    float x2 = bf2f(src[lane + 64]);
    float ss = x1 * x1 + x2 * x2;
#pragma unroll
    for (int m = 1; m < 64; m <<= 1) ss += __shfl_xor(ss, m);
    float rs = rsqrtf(ss * (1.0f / 128.0f) + 1e-6f);
    const float* w = (j < 16) ? qnw : knw;
    float n1 = x1 * rs * w[lane];
    float n2 = x2 * rs * w[lane + 64];
    float inv = powf(1.0e6f, -(float)lane * (1.0f / 64.0f));
    float fr = (float)positions[t] * inv;
    float sn, cs;
    sincosf(fr, &sn, &cs);
    float o1 = n1 * cs - n2 * sn;
    float o2 = n2 * cs + n1 * sn;
    if (j < 16) {
        unsigned short* d = Qo + (size_t)t * (kH * kD) + j * kD;
        d[lane] = f2bf(o1);
        d[lane + 64] = f2bf(o2);
    } else {
        unsigned short* d = Ko + (size_t)t * (kHK * kD) + (j - 16) * kD;
        d[lane] = f2bf(o1);
        d[lane + 64] = f2bf(o2);
    }
}

// V transpose: bf16 qkv v-part -> Vt bf16 (1024 x T), pure pass-through.
__global__ __launch_bounds__(256)
void vtrans(const unsigned short* __restrict__ qkv, unsigned short* __restrict__ Vt) {
    __shared__ unsigned short tile[32][33];
    const int t0 = blockIdx.x * 32;
    const int d0 = blockIdx.y * 32;
    const int tc = threadIdx.x & 31;
    const int tr = threadIdx.x >> 5;  // 0..7
#pragma unroll
    for (int i = 0; i < 4; ++i) {
        int trow = tr + i * 8;
        tile[trow][tc] = qkv[(size_t)(t0 + trow) * 4096 + 3072 + d0 + tc];
    }
    __syncthreads();
#pragma unroll
    for (int i = 0; i < 4; ++i) {
        int drow = tr + i * 8;
        Vt[(size_t)(d0 + drow) * kT + t0 + tc] = tile[tc][drow];
    }
}

// Causal flash attention v5: kv-split-2 with in-kernel merge (proven R8-R11).
__global__ __launch_bounds__(512, 4)
void attn_fwd5(const unsigned short* __restrict__ Q,   // T x (H*D)
               const unsigned short* __restrict__ Kc,  // T x (HK*D)
               const unsigned short* __restrict__ Vt,  // (HK*D) x T
               unsigned short* __restrict__ O) {       // T x (H*D)
    __shared__ unsigned short Kb[2][64 * 128];
    __shared__ unsigned short Vb[2][128 * 64];
    __shared__ float MergeML[4][2][64];

    const int tid  = threadIdx.x;
    const int lane = tid & 63;
    const int l15  = lane & 15;
    const int g4   = lane >> 4;
    const int wid  = tid >> 6;       // 0..7
    const int s    = wid & 1;        // kv split
    const int grp  = wid >> 1;       // 0..3 = (hs, qsub)
    const int hs   = grp >> 1;
    const int qsub = grp & 1;
    const int hkk  = blockIdx.x;
    const int h    = hkk * 2 + hs;
    const int nby  = gridDim.y;
    const int by   = blockIdx.y;
    const int byl  = (by & 1) ? (nby - 1 - (by >> 1)) : (by >> 1);
    const int q0   = byl * 32 + qsub * 16;
    const int nch  = byl / 2 + 1;
    const int c0   = (nch + 1) >> 1;
    const int myn  = s ? (nch - c0) : c0;
    const int qi   = q0 + l15;
    const int vt   = grp * 64 + lane;

    const int addrA = ((g4 & 1) * 32 + l15) * 4;
    const int addrB = addrA + 64;
    const int addrQ = g4 * 80;
    const bool hb   = (g4 >> 1) != 0;

    bf16x8 qf[4];
#pragma unroll
    for (int ks = 0; ks < 4; ++ks)
        qf[ks] = *(const bf16x8*)(Q + (size_t)(q0 + l15) * (kH * kD) + h * kD + ks * 32 + g4 * 8);

    f32x4 oacc[8] = {};
    float mrun = -3e38f, lrun = 0.f;
    const float scale = 0.08838834764831845f;  // 1/sqrt(128)

    auto stage = [&](int kv0) {
#pragma unroll
        for (int i = 0; i < 4; ++i) {
            int ch  = vt + i * 256;
            int row = ch >> 4;
            int c16 = ch & 15;
            gload_lds16(Kc + (size_t)(kv0 + row) * (kHK * kD) + hkk * kD
                            + ((c16 ^ (row & 7)) * 8),
                        (char*)Kb[s] + ch * 16);
        }
#pragma unroll
        for (int i = 0; i < 4; ++i) {
            int ch  = vt + i * 256;
            int row = ch >> 3;
            int c8  = ch & 7;
            gload_lds16(Vt + (size_t)(hkk * kD + row) * kT + kv0
                            + ((c8 ^ (row & 7)) * 8),
                        (char*)Vb[s] + ch * 16);
        }
    };

    for (int c = 0; c < c0; ++c) {
        const bool act = c < myn;
        const int kv0 = (s ? (c0 + c) : c) * 64;
        if (act) stage(kv0);
        asm volatile("s_waitcnt vmcnt(0)" ::: "memory");
        __builtin_amdgcn_s_barrier();
        __builtin_amdgcn_sched_barrier(0);

        if (act) {
            f32x4 sa[4] = {};
            __builtin_amdgcn_s_setprio(1);
#pragma unroll
            for (int hh = 0; hh < 4; ++hh) {
                const int row = hh * 16 + l15;
#pragma unroll
                for (int ks = 0; ks < 4; ++ks) {
                    bf16x8 kf = *(const bf16x8*)((const char*)Kb[s]
                                  + row * 256 + (((ks * 4 + g4) ^ (row & 7)) * 16));
                    sa[hh] = mf(kf, qf[ks], sa[hh]);
                }
            }
            __builtin_amdgcn_s_setprio(0);

            float sv[4][4];
#pragma unroll
            for (int hh = 0; hh < 4; ++hh)
#pragma unroll
                for (int r = 0; r < 4; ++r)
                    sv[hh][r] = sa[hh][r] * scale;
            if (kv0 + 63 > q0) {
#pragma unroll
                for (int hh = 0; hh < 4; ++hh)
#pragma unroll
                    for (int r = 0; r < 4; ++r) {
                        int ki = kv0 + hh * 16 + g4 * 4 + r;
                        if (ki > qi) sv[hh][r] = -3e38f;
                    }
            }

            float m16;
            {
                float a = fmaxf(fmaxf(sv[0][0], sv[0][1]), fmaxf(sv[0][2], sv[0][3]));
                float b2 = fmaxf(fmaxf(sv[1][0], sv[1][1]), fmaxf(sv[1][2], sv[1][3]));
                float c2 = fmaxf(fmaxf(sv[2][0], sv[2][1]), fmaxf(sv[2][2], sv[2][3]));
                float d2 = fmaxf(fmaxf(sv[3][0], sv[3][1]), fmaxf(sv[3][2], sv[3][3]));
                m16 = fmaxf(fmaxf(a, b2), fmaxf(c2, d2));
            }
            m16 = fmaxf(m16, __shfl_xor(m16, 16));
            m16 = fmaxf(m16, __shfl_xor(m16, 32));

            if (__any(m16 > mrun)) {
                float mnew = fmaxf(mrun, m16);
                float corr = __expf(mrun - mnew);
                mrun = mnew;
                lrun *= corr;
                float cr[4];
#pragma unroll
                for (int r = 0; r < 4; ++r)
                    cr[r] = __int_as_float(__builtin_amdgcn_ds_bpermute(
                                addrQ + 4 * r, __float_as_int(corr)));
#pragma unroll
                for (int c2 = 0; c2 < 8; ++c2)
#pragma unroll
                    for (int r = 0; r < 4; ++r)
                        oacc[c2][r] *= cr[r];
            }

            float p[4][4];
            float ps = 0.f;
#pragma unroll
            for (int hh = 0; hh < 4; ++hh)
#pragma unroll
                for (int r = 0; r < 4; ++r) {
                    float pe = __expf(sv[hh][r] - mrun);
                    p[hh][r] = pe;
                    ps += pe;
                }
            ps += __shfl_xor(ps, 16);
            ps += __shfl_xor(ps, 32);
            lrun += ps;

            unsigned pk[4][2];
#pragma unroll
            for (int hh = 0; hh < 4; ++hh) {
                asm("v_cvt_pk_bf16_f32 %0, %1, %2"
                    : "=v"(pk[hh][0]) : "v"(p[hh][0]), "v"(p[hh][1]));
                asm("v_cvt_pk_bf16_f32 %0, %1, %2"
                    : "=v"(pk[hh][1]) : "v"(p[hh][2]), "v"(p[hh][3]));
            }
            int ex[4][2][2];
#pragma unroll
            for (int hh = 0; hh < 4; ++hh)
#pragma unroll
                for (int ii = 0; ii < 2; ++ii) {
                    ex[hh][ii][0] = __builtin_amdgcn_ds_bpermute(addrA, (int)pk[hh][ii]);
                    ex[hh][ii][1] = __builtin_amdgcn_ds_bpermute(addrB, (int)pk[hh][ii]);
                }
            union { int w[4]; bf16x8 v; } pu0, pu1;
#pragma unroll
            for (int jw = 0; jw < 4; ++jw) {
                pu0.w[jw] = hb ? ex[1][jw & 1][jw >> 1] : ex[0][jw & 1][jw >> 1];
                pu1.w[jw] = hb ? ex[3][jw & 1][jw >> 1] : ex[2][jw & 1][jw >> 1];
            }
            bf16x8 pa0 = pu0.v;
            bf16x8 pa1 = pu1.v;

            __builtin_amdgcn_s_setprio(1);
#pragma unroll
            for (int c2 = 0; c2 < 8; ++c2) {
                const int d = c2 * 16 + l15;
                bf16x8 vf0 = *(const bf16x8*)((const char*)Vb[s]
                              + d * 128 + ((g4 ^ (d & 7)) * 16));
                oacc[c2] = mf(pa0, vf0, oacc[c2]);
                bf16x8 vf1 = *(const bf16x8*)((const char*)Vb[s]
                              + d * 128 + ((((4 + g4) ^ (d & 7))) * 16));
                oacc[c2] = mf(pa1, vf1, oacc[c2]);
            }
            __builtin_amdgcn_s_setprio(0);
        }
        __builtin_amdgcn_s_barrier();
    }

    float* KbF = (float*)&Kb[0][0];
    if (s == 1) {
        MergeML[grp][0][lane] = mrun;
        MergeML[grp][1][lane] = lrun;
#pragma unroll
        for (int c2 = 0; c2 < 8; ++c2)
#pragma unroll
            for (int r = 0; r < 4; ++r)
                KbF[grp * 2048 + (c2 * 4 + r) * 64 + lane] = oacc[c2][r];
    }
    asm volatile("s_waitcnt lgkmcnt(0)" ::: "memory");
    __builtin_amdgcn_s_barrier();

    if (s == 0) {
        float m1 = MergeML[grp][0][lane];
        float l1 = MergeML[grp][1][lane];
        float mg = fmaxf(mrun, m1);
        float a0 = __expf(mrun - mg);
        float a1 = __expf(m1 - mg);
        float L  = lrun * a0 + l1 * a1;
        float ar0[4], ar1[4], Lr[4];
#pragma unroll
        for (int r = 0; r < 4; ++r) {
            ar0[r] = __int_as_float(__builtin_amdgcn_ds_bpermute(
                         addrQ + 4 * r, __float_as_int(a0)));
            ar1[r] = __int_as_float(__builtin_amdgcn_ds_bpermute(
                         addrQ + 4 * r, __float_as_int(a1)));
            Lr[r]  = __int_as_float(__builtin_amdgcn_ds_bpermute(
                         addrQ + 4 * r, __float_as_int(L)));
        }
#pragma unroll
        for (int c2 = 0; c2 < 8; ++c2)
#pragma unroll
            for (int r = 0; r < 4; ++r) {
                float oex = KbF[grp * 2048 + (c2 * 4 + r) * 64 + lane];
                float v = (oacc[c2][r] * ar0[r] + oex * ar1[r]) / Lr[r];
                O[(size_t)(q0 + g4 * 4 + r) * (kH * kD) + h * kD + c2 * 16 + l15] = f2bf(v);
            }
    }
}

}  // namespace

extern "C" void kernel_launch(void* const* d_in, const int* in_sizes, int n_in,
                              void* d_out, int out_size, void* d_ws, size_t ws_size,
                              hipStream_t stream) {
    (void)in_sizes; (void)n_in; (void)out_size; (void)ws_size;

    const int*   positions = (const int*)  d_in[0];
    const float* hidden    = (const float*)d_in[1];
    const float* wq  = (const float*)d_in[2];
    const float* wk  = (const float*)d_in[3];
    const float* wv  = (const float*)d_in[4];
    const float* wo  = (const float*)d_in[5];
    const float* qnw = (const float*)d_in[6];
    const float* knw = (const float*)d_in[7];
    const float* ln1 = (const float*)d_in[8];
    const float* ln2 = (const float*)d_in[9];
    const float* wg  = (const float*)d_in[10];
    const float* wu  = (const float*)d_in[11];
    const float* wd  = (const float*)d_in[12];

    char* ws = (char*)d_ws;
    unsigned short* WQKV = (unsigned short*)(ws + 0);          // 4096x2048 bf16
    unsigned short* WO   = (unsigned short*)(ws + 16777216);   // 2048x2048
    unsigned short* WG   = (unsigned short*)(ws + 25165824);   // 6144x2048
    unsigned short* WU   = (unsigned short*)(ws + 50331648);   // 6144x2048
    unsigned short* WD   = (unsigned short*)(ws + 75497472);   // 2048x6144
    unsigned short* XN1  = (unsigned short*)(ws + 100663296);  // T x 2048
    unsigned short* OATT = (unsigned short*)(ws + 109051904);  // T x 2048
    float*          H1   = (float*)(ws + 117440512);           // T x 2048 fp32
    unsigned short* XN2  = (unsigned short*)(ws + 134217728);  // T x 2048
    unsigned short* QKVB = (unsigned short*)(ws + 142606336);  // T x 4096 bf16
    unsigned short* QB   = (unsigned short*)(ws + 176160768);  // T x 2048
    unsigned short* KB   = (unsigned short*)(ws + 184549376);  // T x 1024
    unsigned short* VT   = (unsigned short*)(ws + 188743680);  // 1024 x T
    unsigned short* ACT  = (unsigned short*)(ws + 167772160);  // T x 6144

    // O-proj split-K2 partials (QKVB span + QB/KB + WQKV dead at that point)
    float* OP0 = (float*)(ws + 142606336);
    float* OP1 = (float*)(ws + 159383552);
    // down split-K4 partials (WQKV / WO / WG-mid / OP0-span dead by then)
    float* DP0 = (float*)(ws + 0);
    float* DP1 = (float*)(ws + 16777216);
    float* DP2 = (float*)(ws + 33554432);
    float* DP3 = (float*)(ws + 142606336);

    // single fused weight conversion (wq|wk|wv|wo|wg|wu|wd -> ws bf16 prefix)
    cvt_all<<<dim3(49152), dim3(256), 0, stream>>>(
        wq, wk, wv, wo, wg, wu, wd, (ushort4*)ws);

    rmsnorm_k<<<dim3(kT), dim3(256), 0, stream>>>(hidden, ln1, XN1);

    // QKV GEMM: 128x256 tile, grid 16x16 = 256 exact, bf16 output
    gemm128<1><<<dim3(4096 / 256, kT / 128), dim3(512), 0, stream>>>(
        XN1, WQKV, QKVB, kT, 4096, kHid, kHid, nullptr, nullptr);

    qknorm_rope<<<dim3(kT, 6), dim3(256), 0, stream>>>(QKVB, positions, qnw, knw, QB, KB);
    vtrans<<<dim3(kT / 32, 1024 / 32), dim3(256), 0, stream>>>(QKVB, VT);

    attn_fwd5<<<dim3(kHK, kT / 32), dim3(512), 0, stream>>>(QB, KB, VT, OATT);

    // O-proj: 128x256 split-K2 (grid 8x16x2 = 256 exact, NT=16) -> partials
    gemm128<4><<<dim3(kHid / 256, kT / 128, 2), dim3(512), 0, stream>>>(
        OATT, WO, nullptr, kT, kHid, kHid, 1024, OP0, OP1);
    // fused: H1 = p0+p1+hidden; XN2 = rmsnorm(H1)*ln2
    rmsnorm_red2<<<dim3(kT), dim3(256), 0, stream>>>(
        OP0, OP1, hidden, ln2, H1, XN2);

    // fused gate+up GEMM: 256x96 tile, grid 64x8 = 512 (A-panel XCD swizzle)
    gemm_gu<<<dim3(kFF / 96, kT / 256), dim3(512), 0, stream>>>(XN2, WG, WU, ACT);

    // down: 256x256 split-K4 (KS=1536, grid 8x8x4 = 256 exact) -> partials
    gemm256<4><<<dim3(kHid / 256, kT / 256, 4), dim3(512), 0, stream>>>(
        ACT, WD, nullptr, kT, kHid, kFF, 1536, DP0, DP1, DP2, DP3);
    reduce4<<<dim3(kT * kHid / 4 / 256), dim3(256), 0, stream>>>(
        DP0, DP1, DP2, DP3, H1, (float*)d_out, kT * kHid / 4);
}

// Round 20
// 354.934 us; speedup vs baseline: 1.0865x; 1.0243x over previous
//
#include <hip/hip_runtime.h>
#include <hip/hip_bf16.h>
#include <stdint.h>

namespace {

constexpr int kT   = 2048;
constexpr int kHid = 2048;
constexpr int kH   = 16;
constexpr int kHK  = 8;
constexpr int kD   = 128;
constexpr int kFF  = 6144;

using bf16x8 = __attribute__((ext_vector_type(8))) short;
using f32x4  = __attribute__((ext_vector_type(4))) float;

__device__ __forceinline__ float bf2f(unsigned short u) {
    return __uint_as_float(((unsigned)u) << 16);
}
__device__ __forceinline__ unsigned short f2bf(float f) {
    unsigned u = __float_as_uint(f);
    return (unsigned short)((u + 0x7fffu + ((u >> 16) & 1u)) >> 16);
}
__device__ __forceinline__ void gload_lds16(const void* g, void* l) {
    __builtin_amdgcn_global_load_lds(
        (__attribute__((address_space(1))) void*)g,
        (__attribute__((address_space(3))) void*)l, 16, 0, 0);
}
__device__ __forceinline__ f32x4 mf(bf16x8 a, bf16x8 b, f32x4 c) {
    return __builtin_amdgcn_mfma_f32_16x16x32_bf16(a, b, c, 0, 0, 0);
}

// One-shot fp32->bf16 conversion of all seven weight matrices into the
// contiguous ws prefix. Region boundaries in float4 units:
//   wq [0,1048576) wk [..,1572864) wv [..,2097152) wo [..,3145728)
//   wg [..,6291456) wu [..,9437184) wd [..,12582912)
__global__ __launch_bounds__(256)
void cvt_all(const float* __restrict__ wq, const float* __restrict__ wk,
             const float* __restrict__ wv, const float* __restrict__ wo,
             const float* __restrict__ wg, const float* __restrict__ wu,
             const float* __restrict__ wd, ushort4* __restrict__ dst) {
    int i = blockIdx.x * 256 + threadIdx.x;
    if (i >= 12582912) return;
    const float4* src;
    int base;
    if (i < 3145728) {
        if (i < 1048576)      { src = (const float4*)wq; base = 0; }
        else if (i < 1572864) { src = (const float4*)wk; base = 1048576; }
        else if (i < 2097152) { src = (const float4*)wv; base = 1572864; }
        else                  { src = (const float4*)wo; base = 2097152; }
    } else {
        if (i < 6291456)      { src = (const float4*)wg; base = 3145728; }
        else if (i < 9437184) { src = (const float4*)wu; base = 6291456; }
        else                  { src = (const float4*)wd; base = 9437184; }
    }
    float4 v = src[i - base];
    ushort4 o;
    o.x = f2bf(v.x); o.y = f2bf(v.y); o.z = f2bf(v.z); o.w = f2bf(v.w);
    dst[i] = o;
}

// out = bf16(p0)+bf16(p1)+bf16(p2)+bf16(p3)+res(fp32); 8 elems/thread.
__global__ __launch_bounds__(256)
void reduce4b(const unsigned int* __restrict__ p0, const unsigned int* __restrict__ p1,
              const unsigned int* __restrict__ p2, const unsigned int* __restrict__ p3,
              const float* __restrict__ res, float* __restrict__ out, int n8) {
    int i = blockIdx.x * 256 + threadIdx.x;
    if (i >= n8) return;
    uint4 a = ((const uint4*)p0)[i];
    uint4 b = ((const uint4*)p1)[i];
    uint4 c = ((const uint4*)p2)[i];
    uint4 d = ((const uint4*)p3)[i];
    const float4* rr = (const float4*)res;
    float4 r0 = rr[2 * i], r1 = rr[2 * i + 1];
    unsigned aw[4] = {a.x, a.y, a.z, a.w};
    unsigned bw[4] = {b.x, b.y, b.z, b.w};
    unsigned cw[4] = {c.x, c.y, c.z, c.w};
    unsigned dw[4] = {d.x, d.y, d.z, d.w};
    float rv[8] = {r0.x, r0.y, r0.z, r0.w, r1.x, r1.y, r1.z, r1.w};
    float ov[8];
#pragma unroll
    for (int w = 0; w < 4; ++w) {
        ov[2 * w]     = bf2f((unsigned short)(aw[w] & 0xffff))
                      + bf2f((unsigned short)(bw[w] & 0xffff))
                      + bf2f((unsigned short)(cw[w] & 0xffff))
                      + bf2f((unsigned short)(dw[w] & 0xffff)) + rv[2 * w];
        ov[2 * w + 1] = bf2f((unsigned short)(aw[w] >> 16))
                      + bf2f((unsigned short)(bw[w] >> 16))
                      + bf2f((unsigned short)(cw[w] >> 16))
                      + bf2f((unsigned short)(dw[w] >> 16)) + rv[2 * w + 1];
    }
    float4* oo = (float4*)out;
    oo[2 * i]     = make_float4(ov[0], ov[1], ov[2], ov[3]);
    oo[2 * i + 1] = make_float4(ov[4], ov[5], ov[6], ov[7]);
}

// RMSNorm over HID=2048, fp32 in -> bf16 out. 1 block per row.
__global__ __launch_bounds__(256)
void rmsnorm_k(const float* __restrict__ x, const float* __restrict__ w,
               unsigned short* __restrict__ out) {
    const int row = blockIdx.x;
    const int tid = threadIdx.x;
    const float4* xr = (const float4*)(x + (size_t)row * kHid);
    float4 v0 = xr[tid];
    float4 v1 = xr[tid + 256];
    float ss = v0.x*v0.x + v0.y*v0.y + v0.z*v0.z + v0.w*v0.w
             + v1.x*v1.x + v1.y*v1.y + v1.z*v1.z + v1.w*v1.w;
#pragma unroll
    for (int m = 1; m < 64; m <<= 1) ss += __shfl_xor(ss, m);
    __shared__ float red[4];
    if ((tid & 63) == 0) red[tid >> 6] = ss;
    __syncthreads();
    float tot = red[0] + red[1] + red[2] + red[3];
    float rs = rsqrtf(tot * (1.0f / kHid) + 1e-6f);
    const float4* wv = (const float4*)w;
    float4 w0 = wv[tid], w1 = wv[tid + 256];
    ushort4 o0, o1;
    o0.x = f2bf(v0.x * rs * w0.x); o0.y = f2bf(v0.y * rs * w0.y);
    o0.z = f2bf(v0.z * rs * w0.z); o0.w = f2bf(v0.w * rs * w0.w);
    o1.x = f2bf(v1.x * rs * w1.x); o1.y = f2bf(v1.y * rs * w1.y);
    o1.z = f2bf(v1.z * rs * w1.z); o1.w = f2bf(v1.w * rs * w1.w);
    ushort4* orow = (ushort4*)(out + (size_t)row * kHid);
    orow[tid] = o0;
    orow[tid + 256] = o1;
}

// Fused: h = bf16(p0)+bf16(p1)+res -> H1; XN2 = rmsnorm(h)*w. 1 block/row.
__global__ __launch_bounds__(256)
void rmsnorm_red2b(const unsigned short* __restrict__ p0,
                   const unsigned short* __restrict__ p1,
                   const float* __restrict__ res, const float* __restrict__ w,
                   float* __restrict__ H, unsigned short* __restrict__ out) {
    const int row = blockIdx.x;
    const int tid = threadIdx.x;
    const size_t base = (size_t)row * kHid;
    float4 v0, v1;
    {
        const ushort4* a = (const ushort4*)(p0 + base);
        const ushort4* b = (const ushort4*)(p1 + base);
        const float4*  r = (const float4*)(res + base);
        ushort4 a0 = a[tid], b0 = b[tid];
        float4 r0 = r[tid];
        v0.x = bf2f(a0.x) + bf2f(b0.x) + r0.x;
        v0.y = bf2f(a0.y) + bf2f(b0.y) + r0.y;
        v0.z = bf2f(a0.z) + bf2f(b0.z) + r0.z;
        v0.w = bf2f(a0.w) + bf2f(b0.w) + r0.w;
        ushort4 a1 = a[tid + 256], b1 = b[tid + 256];
        float4 r1 = r[tid + 256];
        v1.x = bf2f(a1.x) + bf2f(b1.x) + r1.x;
        v1.y = bf2f(a1.y) + bf2f(b1.y) + r1.y;
        v1.z = bf2f(a1.z) + bf2f(b1.z) + r1.z;
        v1.w = bf2f(a1.w) + bf2f(b1.w) + r1.w;
    }
    ((float4*)(H + base))[tid] = v0;
    ((float4*)(H + base))[tid + 256] = v1;
    float ss = v0.x*v0.x + v0.y*v0.y + v0.z*v0.z + v0.w*v0.w
             + v1.x*v1.x + v1.y*v1.y + v1.z*v1.z + v1.w*v1.w;
#pragma unroll
    for (int m = 1; m < 64; m <<= 1) ss += __shfl_xor(ss, m);
    __shared__ float red[4];
    if ((tid & 63) == 0) red[tid >> 6] = ss;
    __syncthreads();
    float tot = red[0] + red[1] + red[2] + red[3];
    float rs = rsqrtf(tot * (1.0f / kHid) + 1e-6f);
    const float4* wv = (const float4*)w;
    float4 w0 = wv[tid], w1 = wv[tid + 256];
    ushort4 o0, o1;
    o0.x = f2bf(v0.x * rs * w0.x); o0.y = f2bf(v0.y * rs * w0.y);
    o0.z = f2bf(v0.z * rs * w0.z); o0.w = f2bf(v0.w * rs * w0.w);
    o1.x = f2bf(v1.x * rs * w1.x); o1.y = f2bf(v1.y * rs * w1.y);
    o1.z = f2bf(v1.z * rs * w1.z); o1.w = f2bf(v1.w * rs * w1.w);
    ushort4* orow = (ushort4*)(out + base);
    orow[tid] = o0;
    orow[tid + 256] = o1;
}

// -------- 256x256 8-phase GEMM (proven; EPI4 split-K bf16 partials) --------
template <int EPI>
__global__ __launch_bounds__(512, 2)
void gemm256(const unsigned short* __restrict__ A,
             const unsigned short* __restrict__ B,
             void* __restrict__ C,
             int M, int N, int K, int KS,
             unsigned short* __restrict__ p0, unsigned short* __restrict__ p1,
             unsigned short* __restrict__ p2, unsigned short* __restrict__ p3) {
    __shared__ unsigned short smem[2][4][128 * 64];  // 128 KiB

    const int tid  = threadIdx.x;
    const int lane = tid & 63;
    const int l15  = lane & 15;
    const int g4   = lane >> 4;
    const int wid  = tid >> 6;
    const int wr   = wid >> 2;
    const int wc   = wid & 3;
    const int bm   = blockIdx.y * 256;
    const int bn   = blockIdx.x * 256;
    const int kb   = (EPI == 4) ? blockIdx.z * KS : 0;
    const int NT   = ((EPI == 4) ? KS : K) >> 6;
    const int NI   = NT >> 1;

    f32x4 acc[8][4] = {};

    auto stage = [&](int b, int reg, int t) {
        const unsigned short* Base = (reg < 2) ? A : B;
        const int br = ((reg < 2) ? bm : bn) + (reg & 1) * 128;
#pragma unroll
        for (int i = 0; i < 2; ++i) {
            int ch   = tid + i * 512;
            int row  = ch >> 3;
            int slot = (ch & 7) ^ (row & 7);
            gload_lds16(Base + (size_t)(br + row) * K + kb + t * 64 + slot * 8,
                        (char*)&smem[b][reg][0] + ch * 16);
        }
    };
    auto rdA = [&](int b, int m, int ks) {
        int row = m * 16 + l15;
        return *(const bf16x8*)((const char*)&smem[b][wr][0]
               + row * 128 + (((ks * 4 + g4) ^ (row & 7)) * 16));
    };
    auto rdB = [&](int b, int n, int ks) {
        int row = wc * 64 + n * 16 + l15;
        return *(const bf16x8*)((const char*)&smem[b][2 + (row >> 7)][0]
               + (row & 127) * 128 + (((ks * 4 + g4) ^ (row & 7)) * 16));
    };

    stage(0, 2, 0); stage(0, 3, 0); stage(0, 0, 0); stage(0, 1, 0);
    stage(1, 2, 1); stage(1, 3, 1); stage(1, 0, 1);
    asm volatile("s_waitcnt vmcnt(6)" ::: "memory");
    __builtin_amdgcn_s_barrier();

    for (int i = 0; i < NI; ++i) {
        const int e  = 2 * i;
        const int o  = e + 1;
        const bool pf = (e + 2 < NT);
        bf16x8 af[4][2], bfr[4][2];

#pragma unroll
        for (int m = 0; m < 4; ++m) { af[m][0] = rdA(0, m, 0); af[m][1] = rdA(0, m, 1); }
#pragma unroll
        for (int n = 0; n < 4; ++n) { bfr[n][0] = rdB(0, n, 0); bfr[n][1] = rdB(0, n, 1); }
        stage(1, 1, o);
        __builtin_amdgcn_s_barrier();
        asm volatile("s_waitcnt lgkmcnt(0)" ::: "memory");
        __builtin_amdgcn_sched_barrier(0);
        __builtin_amdgcn_s_setprio(1);
#pragma unroll
        for (int m = 0; m < 4; ++m)
#pragma unroll
            for (int n = 0; n < 2; ++n) {
                acc[m][n] = mf(af[m][0], bfr[n][0], acc[m][n]);
                acc[m][n] = mf(af[m][1], bfr[n][1], acc[m][n]);
            }
        __builtin_amdgcn_s_setprio(0);
        __builtin_amdgcn_s_barrier();

        if (pf) stage(0, 2, e + 2);
        __builtin_amdgcn_s_barrier();
        __builtin_amdgcn_s_setprio(1);
#pragma unroll
        for (int m = 0; m < 4; ++m)
#pragma unroll
            for (int n = 2; n < 4; ++n) {
                acc[m][n] = mf(af[m][0], bfr[n][0], acc[m][n]);
                acc[m][n] = mf(af[m][1], bfr[n][1], acc[m][n]);
            }
        __builtin_amdgcn_s_setprio(0);
        __builtin_amdgcn_s_barrier();

#pragma unroll
        for (int m = 0; m < 4; ++m) { af[m][0] = rdA(0, 4 + m, 0); af[m][1] = rdA(0, 4 + m, 1); }
        if (pf) stage(0, 3, e + 2);
        __builtin_amdgcn_s_barrier();
        asm volatile("s_waitcnt lgkmcnt(0)" ::: "memory");
        __builtin_amdgcn_sched_barrier(0);
        __builtin_amdgcn_s_setprio(1);
#pragma unroll
        for (int m = 0; m < 4; ++m)
#pragma unroll
            for (int n = 0; n < 2; ++n) {
                acc[4 + m][n] = mf(af[m][0], bfr[n][0], acc[4 + m][n]);
                acc[4 + m][n] = mf(af[m][1], bfr[n][1], acc[4 + m][n]);
            }
        __builtin_amdgcn_s_setprio(0);
        __builtin_amdgcn_s_barrier();

        if (pf) stage(0, 0, e + 2);
        __builtin_amdgcn_s_barrier();
        __builtin_amdgcn_s_setprio(1);
#pragma unroll
        for (int m = 0; m < 4; ++m)
#pragma unroll
            for (int n = 2; n < 4; ++n) {
                acc[4 + m][n] = mf(af[m][0], bfr[n][0], acc[4 + m][n]);
                acc[4 + m][n] = mf(af[m][1], bfr[n][1], acc[4 + m][n]);
            }
        __builtin_amdgcn_s_setprio(0);
        if (pf) asm volatile("s_waitcnt vmcnt(6)" ::: "memory");
        else    asm volatile("s_waitcnt vmcnt(0)" ::: "memory");
        __builtin_amdgcn_s_barrier();

#pragma unroll
        for (int m = 0; m < 4; ++m) { af[m][0] = rdA(1, m, 0); af[m][1] = rdA(1, m, 1); }
#pragma unroll
        for (int n = 0; n < 4; ++n) { bfr[n][0] = rdB(1, n, 0); bfr[n][1] = rdB(1, n, 1); }
        if (pf) stage(0, 1, e + 2);
        __builtin_amdgcn_s_barrier();
        asm volatile("s_waitcnt lgkmcnt(0)" ::: "memory");
        __builtin_amdgcn_sched_barrier(0);
        __builtin_amdgcn_s_setprio(1);
#pragma unroll
        for (int m = 0; m < 4; ++m)
#pragma unroll
            for (int n = 0; n < 2; ++n) {
                acc[m][n] = mf(af[m][0], bfr[n][0], acc[m][n]);
                acc[m][n] = mf(af[m][1], bfr[n][1], acc[m][n]);
            }
        __builtin_amdgcn_s_setprio(0);
        __builtin_amdgcn_s_barrier();

        if (pf) stage(1, 2, o + 2);
        __builtin_amdgcn_s_barrier();
        __builtin_amdgcn_s_setprio(1);
#pragma unroll
        for (int m = 0; m < 4; ++m)
#pragma unroll
            for (int n = 2; n < 4; ++n) {
                acc[m][n] = mf(af[m][0], bfr[n][0], acc[m][n]);
                acc[m][n] = mf(af[m][1], bfr[n][1], acc[m][n]);
            }
        __builtin_amdgcn_s_setprio(0);
        __builtin_amdgcn_s_barrier();

#pragma unroll
        for (int m = 0; m < 4; ++m) { af[m][0] = rdA(1, 4 + m, 0); af[m][1] = rdA(1, 4 + m, 1); }
        if (pf) stage(1, 3, o + 2);
        __builtin_amdgcn_s_barrier();
        asm volatile("s_waitcnt lgkmcnt(0)" ::: "memory");
        __builtin_amdgcn_sched_barrier(0);
        __builtin_amdgcn_s_setprio(1);
#pragma unroll
        for (int m = 0; m < 4; ++m)
#pragma unroll
            for (int n = 0; n < 2; ++n) {
                acc[4 + m][n] = mf(af[m][0], bfr[n][0], acc[4 + m][n]);
                acc[4 + m][n] = mf(af[m][1], bfr[n][1], acc[4 + m][n]);
            }
        __builtin_amdgcn_s_setprio(0);
        __builtin_amdgcn_s_barrier();

        if (pf) stage(1, 0, o + 2);
        __builtin_amdgcn_s_barrier();
        __builtin_amdgcn_s_setprio(1);
#pragma unroll
        for (int m = 0; m < 4; ++m)
#pragma unroll
            for (int n = 2; n < 4; ++n) {
                acc[4 + m][n] = mf(af[m][0], bfr[n][0], acc[4 + m][n]);
                acc[4 + m][n] = mf(af[m][1], bfr[n][1], acc[4 + m][n]);
            }
        __builtin_amdgcn_s_setprio(0);
        if (pf) asm volatile("s_waitcnt vmcnt(6)" ::: "memory");
        __builtin_amdgcn_s_barrier();
    }

    unsigned short* P = nullptr;
    if (EPI == 4) {
        const int z = blockIdx.z;
        P = (z == 0) ? p0 : (z == 1) ? p1 : (z == 2) ? p2 : p3;
    }
#pragma unroll
    for (int m = 0; m < 8; ++m) {
#pragma unroll
        for (int n = 0; n < 4; ++n) {
            int row = bm + wr * 128 + m * 16 + g4 * 4;
            int col = bn + wc * 64 + n * 16 + l15;
#pragma unroll
            for (int r = 0; r < 4; ++r) {
                size_t idx = (size_t)(row + r) * N + col;
                float v = acc[m][n][r];
                if (EPI == 0) ((float*)C)[idx] = v;
                else          P[idx] = f2bf(v);
            }
        }
    }
}

// -------- 128M x 256N 8-phase GEMM (proven; QKV + O-proj) ------------------
// EPI: 0 = fp32 store, 1 = bf16 store, 4 = split-K2 bf16 partials.
template <int EPI>
__global__ __launch_bounds__(512, 2)
void gemm128(const unsigned short* __restrict__ A,
             const unsigned short* __restrict__ B,
             void* __restrict__ C,
             int M, int N, int K, int KS,
             unsigned short* __restrict__ p0, unsigned short* __restrict__ p1) {
    __shared__ unsigned short smem[2][3][128 * 64];  // 96 KiB

    const int tid  = threadIdx.x;
    const int lane = tid & 63;
    const int l15  = lane & 15;
    const int g4   = lane >> 4;
    const int wid  = tid >> 6;
    const int wr   = wid >> 2;
    const int wc   = wid & 3;
    const int bm   = blockIdx.y * 128;
    const int bn   = blockIdx.x * 256;
    const int kb   = (EPI == 4) ? blockIdx.z * KS : 0;
    const int NT   = ((EPI == 4) ? KS : K) >> 6;
    const int NI   = NT >> 1;

    f32x4 acc[4][4] = {};

    auto stage = [&](int b, int reg, int t) {
        const unsigned short* Base = (reg == 0) ? A : B;
        const int br = (reg == 0) ? bm : bn + (reg - 1) * 128;
#pragma unroll
        for (int i = 0; i < 2; ++i) {
            int ch   = tid + i * 512;
            int row  = ch >> 3;
            int slot = (ch & 7) ^ (row & 7);
            gload_lds16(Base + (size_t)(br + row) * K + kb + t * 64 + slot * 8,
                        (char*)&smem[b][reg][0] + ch * 16);
        }
    };
    auto rdA = [&](int b, int m, int ks) {
        int row = wr * 64 + m * 16 + l15;
        return *(const bf16x8*)((const char*)&smem[b][0][0]
               + row * 128 + (((ks * 4 + g4) ^ (row & 7)) * 16));
    };
    auto rdB = [&](int b, int n, int ks) {
        int row = wc * 64 + n * 16 + l15;
        return *(const bf16x8*)((const char*)&smem[b][1 + (row >> 7)][0]
               + (row & 127) * 128 + (((ks * 4 + g4) ^ (row & 7)) * 16));
    };

    stage(0, 1, 0); stage(0, 2, 0); stage(0, 0, 0);
    stage(1, 1, 1); stage(1, 2, 1);
    asm volatile("s_waitcnt vmcnt(4)" ::: "memory");
    __builtin_amdgcn_s_barrier();

    for (int i = 0; i < NI; ++i) {
        const int e  = 2 * i;
        const int o  = e + 1;
        const bool pf = (e + 2 < NT);
        bf16x8 af[4][2], bfr[4][2];

#pragma unroll
        for (int m = 0; m < 4; ++m) { af[m][0] = rdA(0, m, 0); af[m][1] = rdA(0, m, 1); }
#pragma unroll
        for (int n = 0; n < 4; ++n) { bfr[n][0] = rdB(0, n, 0); bfr[n][1] = rdB(0, n, 1); }
        stage(1, 0, o);
        __builtin_amdgcn_s_barrier();
        asm volatile("s_waitcnt lgkmcnt(0)" ::: "memory");
        __builtin_amdgcn_sched_barrier(0);
        __builtin_amdgcn_s_setprio(1);
#pragma unroll
        for (int m = 0; m < 4; ++m) {
            acc[m][0] = mf(af[m][0], bfr[0][0], acc[m][0]);
            acc[m][0] = mf(af[m][1], bfr[0][1], acc[m][0]);
        }
        __builtin_amdgcn_s_setprio(0);
        __builtin_amdgcn_s_barrier();

        if (pf) stage(0, 1, e + 2);
        __builtin_amdgcn_s_barrier();
        __builtin_amdgcn_s_setprio(1);
#pragma unroll
        for (int m = 0; m < 4; ++m) {
            acc[m][1] = mf(af[m][0], bfr[1][0], acc[m][1]);
            acc[m][1] = mf(af[m][1], bfr[1][1], acc[m][1]);
        }
        __builtin_amdgcn_s_setprio(0);
        __builtin_amdgcn_s_barrier();

        if (pf) stage(0, 2, e + 2);
        __builtin_amdgcn_s_barrier();
        __builtin_amdgcn_s_setprio(1);
#pragma unroll
        for (int m = 0; m < 4; ++m) {
            acc[m][2] = mf(af[m][0], bfr[2][0], acc[m][2]);
            acc[m][2] = mf(af[m][1], bfr[2][1], acc[m][2]);
        }
        __builtin_amdgcn_s_setprio(0);
        __builtin_amdgcn_s_barrier();

        __builtin_amdgcn_s_setprio(1);
#pragma unroll
        for (int m = 0; m < 4; ++m) {
            acc[m][3] = mf(af[m][0], bfr[3][0], acc[m][3]);
            acc[m][3] = mf(af[m][1], bfr[3][1], acc[m][3]);
        }
        __builtin_amdgcn_s_setprio(0);
        if (pf) asm volatile("s_waitcnt vmcnt(4)" ::: "memory");
        else    asm volatile("s_waitcnt vmcnt(0)" ::: "memory");
        __builtin_amdgcn_s_barrier();

#pragma unroll
        for (int m = 0; m < 4; ++m) { af[m][0] = rdA(1, m, 0); af[m][1] = rdA(1, m, 1); }
#pragma unroll
        for (int n = 0; n < 4; ++n) { bfr[n][0] = rdB(1, n, 0); bfr[n][1] = rdB(1, n, 1); }
        if (pf) stage(0, 0, e + 2);
        __builtin_amdgcn_s_barrier();
        asm volatile("s_waitcnt lgkmcnt(0)" ::: "memory");
        __builtin_amdgcn_sched_barrier(0);
        __builtin_amdgcn_s_setprio(1);
#pragma unroll
        for (int m = 0; m < 4; ++m) {
            acc[m][0] = mf(af[m][0], bfr[0][0], acc[m][0]);
            acc[m][0] = mf(af[m][1], bfr[0][1], acc[m][0]);
        }
        __builtin_amdgcn_s_setprio(0);
        __builtin_amdgcn_s_barrier();

        if (pf) stage(1, 1, o + 2);
        __builtin_amdgcn_s_barrier();
        __builtin_amdgcn_s_setprio(1);
#pragma unroll
        for (int m = 0; m < 4; ++m) {
            acc[m][1] = mf(af[m][0], bfr[1][0], acc[m][1]);
            acc[m][1] = mf(af[m][1], bfr[1][1], acc[m][1]);
        }
        __builtin_amdgcn_s_setprio(0);
        __builtin_amdgcn_s_barrier();

        if (pf) stage(1, 2, o + 2);
        __builtin_amdgcn_s_barrier();
        __builtin_amdgcn_s_setprio(1);
#pragma unroll
        for (int m = 0; m < 4; ++m) {
            acc[m][2] = mf(af[m][0], bfr[2][0], acc[m][2]);
            acc[m][2] = mf(af[m][1], bfr[2][1], acc[m][2]);
        }
        __builtin_amdgcn_s_setprio(0);
        __builtin_amdgcn_s_barrier();

        __builtin_amdgcn_s_setprio(1);
#pragma unroll
        for (int m = 0; m < 4; ++m) {
            acc[m][3] = mf(af[m][0], bfr[3][0], acc[m][3]);
            acc[m][3] = mf(af[m][1], bfr[3][1], acc[m][3]);
        }
        __builtin_amdgcn_s_setprio(0);
        if (pf) asm volatile("s_waitcnt vmcnt(4)" ::: "memory");
        __builtin_amdgcn_s_barrier();
    }

    unsigned short* P = nullptr;
    if (EPI == 4) P = (blockIdx.z == 0) ? p0 : p1;
#pragma unroll
    for (int m = 0; m < 4; ++m) {
#pragma unroll
        for (int n = 0; n < 4; ++n) {
            int row = bm + wr * 64 + m * 16 + g4 * 4;
            int col = bn + wc * 64 + n * 16 + l15;
#pragma unroll
            for (int r = 0; r < 4; ++r) {
                size_t idx = (size_t)(row + r) * N + col;
                float v = acc[m][n][r];
                if (EPI == 0)      ((float*)C)[idx] = v;
                else if (EPI == 1) ((unsigned short*)C)[idx] = f2bf(v);
                else               P[idx] = f2bf(v);
            }
        }
    }
}

// -------- fused gate+up GEMM v2: tile 256M x 96FF, grid 64x8 = 512 ---------
// T1 A-panel-resident remap (kept from R18: measured best-total build).
__global__ __launch_bounds__(512, 2)
void gemm_gu(const unsigned short* __restrict__ A,
             const unsigned short* __restrict__ WGp,
             const unsigned short* __restrict__ WUp,
             unsigned short* __restrict__ OUT) {
    __shared__ unsigned short smem[2][28672];  // 112 KiB

    const int tid  = threadIdx.x;
    const int lane = tid & 63;
    const int l15  = lane & 15;
    const int g4   = lane >> 4;
    const int wid  = tid >> 6;   // 0..7
    const int wr   = wid >> 1;   // 0..3  (64-row slice)
    const int wc   = wid & 1;    // 0..1  (48-col slice)
    const int id   = blockIdx.y * gridDim.x + blockIdx.x;
    const int byl  = id & 7;     // A panel (one per XCD)
    const int bxl  = id >> 3;    // 0..63
    const int bm   = byl * 256;
    const int bn   = bxl * 96;
    const int K    = kHid;
    const int NT   = K >> 6;     // 32
    const int NI   = NT >> 1;

    f32x4 accg[4][3] = {};
    f32x4 accu[4][3] = {};

    constexpr int OFF_A0 = 0;
    constexpr int OFF_A1 = 16384;
    constexpr int OFF_GU = 32768;

    auto stage_a = [&](int b, int half, int t) {
#pragma unroll
        for (int i = 0; i < 2; ++i) {
            int ch   = tid + i * 512;
            int row  = ch >> 3;
            int slot = (ch & 7) ^ (row & 7);
            gload_lds16(A + (size_t)(bm + half * 128 + row) * K + t * 64 + slot * 8,
                        (char*)&smem[b][0] + (half ? OFF_A1 : OFF_A0) + ch * 16);
        }
    };
    auto stage_gu = [&](int b, int t) {
#pragma unroll
        for (int i = 0; i < 3; ++i) {
            int ch   = tid + i * 512;
            int row  = ch >> 3;
            int slot = (ch & 7) ^ (row & 7);
            const unsigned short* Base = (row >= 96) ? WUp : WGp;
            int srow = bn + (row >= 96 ? row - 96 : row);
            gload_lds16(Base + (size_t)srow * K + t * 64 + slot * 8,
                        (char*)&smem[b][0] + OFF_GU + ch * 16);
        }
    };
    auto rdA = [&](int b, int m, int ks) {
        int rt  = wr * 64 + m * 16 + l15;
        int row = rt & 127;
        return *(const bf16x8*)((const char*)&smem[b][0]
               + (rt >> 7 ? OFF_A1 : OFF_A0)
               + row * 128 + (((ks * 4 + g4) ^ (row & 7)) * 16));
    };
    auto rdG = [&](int b, int n, int ks) {
        int row = wc * 48 + n * 16 + l15;
        return *(const bf16x8*)((const char*)&smem[b][0] + OFF_GU
               + row * 128 + (((ks * 4 + g4) ^ (row & 7)) * 16));
    };
    auto rdU = [&](int b, int n, int ks) {
        int row = 96 + wc * 48 + n * 16 + l15;
        return *(const bf16x8*)((const char*)&smem[b][0] + OFF_GU
               + row * 128 + (((ks * 4 + g4) ^ (row & 7)) * 16));
    };

    stage_a(0, 0, 0); stage_a(0, 1, 0); stage_gu(0, 0);
    stage_a(1, 0, 1); stage_a(1, 1, 1);
    asm volatile("s_waitcnt vmcnt(4)" ::: "memory");
    __builtin_amdgcn_s_barrier();

    for (int i = 0; i < NI; ++i) {
        const int e  = 2 * i;
        const int o  = e + 1;
        const bool pf = (e + 2 < NT);
        bf16x8 af[4][2], bg[3][2], bu[3][2];

#pragma unroll
        for (int m = 0; m < 4; ++m) { af[m][0] = rdA(0, m, 0); af[m][1] = rdA(0, m, 1); }
#pragma unroll
        for (int n = 0; n < 3; ++n) { bg[n][0] = rdG(0, n, 0); bg[n][1] = rdG(0, n, 1); }
        stage_gu(1, o);
        __builtin_amdgcn_s_barrier();
        asm volatile("s_waitcnt lgkmcnt(0)" ::: "memory");
        __builtin_amdgcn_sched_barrier(0);
        __builtin_amdgcn_s_setprio(1);
#pragma unroll
        for (int m = 0; m < 4; ++m)
#pragma unroll
            for (int n = 0; n < 3; ++n)
                accg[m][n] = mf(af[m][0], bg[n][0], accg[m][n]);
        __builtin_amdgcn_s_setprio(0);
        __builtin_amdgcn_s_barrier();

        if (pf) stage_a(0, 0, e + 2);
        __builtin_amdgcn_s_barrier();
        __builtin_amdgcn_s_setprio(1);
#pragma unroll
        for (int m = 0; m < 4; ++m)
#pragma unroll
            for (int n = 0; n < 3; ++n)
                accg[m][n] = mf(af[m][1], bg[n][1], accg[m][n]);
        __builtin_amdgcn_s_setprio(0);
        __builtin_amdgcn_s_barrier();

#pragma unroll
        for (int n = 0; n < 3; ++n) { bu[n][0] = rdU(0, n, 0); bu[n][1] = rdU(0, n, 1); }
        if (pf) stage_a(0, 1, e + 2);
        __builtin_amdgcn_s_barrier();
        asm volatile("s_waitcnt lgkmcnt(0)" ::: "memory");
        __builtin_amdgcn_sched_barrier(0);
        __builtin_amdgcn_s_setprio(1);
#pragma unroll
        for (int m = 0; m < 4; ++m)
#pragma unroll
            for (int n = 0; n < 3; ++n)
                accu[m][n] = mf(af[m][0], bu[n][0], accu[m][n]);
        __builtin_amdgcn_s_setprio(0);
        __builtin_amdgcn_s_barrier();

        if (pf) stage_gu(0, e + 2);
        __builtin_amdgcn_s_barrier();
        __builtin_amdgcn_s_setprio(1);
#pragma unroll
        for (int m = 0; m < 4; ++m)
#pragma unroll
            for (int n = 0; n < 3; ++n)
                accu[m][n] = mf(af[m][1], bu[n][1], accu[m][n]);
        __builtin_amdgcn_s_setprio(0);
        if (pf) asm volatile("s_waitcnt vmcnt(7)" ::: "memory");
        else    asm volatile("s_waitcnt vmcnt(0)" ::: "memory");
        __builtin_amdgcn_s_barrier();

#pragma unroll
        for (int m = 0; m < 4; ++m) { af[m][0] = rdA(1, m, 0); af[m][1] = rdA(1, m, 1); }
#pragma unroll
        for (int n = 0; n < 3; ++n) { bg[n][0] = rdG(1, n, 0); bg[n][1] = rdG(1, n, 1); }
        __builtin_amdgcn_s_barrier();
        asm volatile("s_waitcnt lgkmcnt(0)" ::: "memory");
        __builtin_amdgcn_sched_barrier(0);
        __builtin_amdgcn_s_setprio(1);
#pragma unroll
        for (int m = 0; m < 4; ++m)
#pragma unroll
            for (int n = 0; n < 3; ++n)
                accg[m][n] = mf(af[m][0], bg[n][0], accg[m][n]);
        __builtin_amdgcn_s_setprio(0);
        __builtin_amdgcn_s_barrier();

        if (pf) stage_a(1, 0, o + 2);
        __builtin_amdgcn_s_barrier();
        __builtin_amdgcn_s_setprio(1);
#pragma unroll
        for (int m = 0; m < 4; ++m)
#pragma unroll
            for (int n = 0; n < 3; ++n)
                accg[m][n] = mf(af[m][1], bg[n][1], accg[m][n]);
        __builtin_amdgcn_s_setprio(0);
        __builtin_amdgcn_s_barrier();

#pragma unroll
        for (int n = 0; n < 3; ++n) { bu[n][0] = rdU(1, n, 0); bu[n][1] = rdU(1, n, 1); }
        if (pf) stage_a(1, 1, o + 2);
        __builtin_amdgcn_s_barrier();
        asm volatile("s_waitcnt lgkmcnt(0)" ::: "memory");
        __builtin_amdgcn_sched_barrier(0);
        __builtin_amdgcn_s_setprio(1);
#pragma unroll
        for (int m = 0; m < 4; ++m)
#pragma unroll
            for (int n = 0; n < 3; ++n)
                accu[m][n] = mf(af[m][0], bu[n][0], accu[m][n]);
        __builtin_amdgcn_s_setprio(0);
        __builtin_amdgcn_s_barrier();

        __builtin_amdgcn_s_setprio(1);
#pragma unroll
        for (int m = 0; m < 4; ++m)
#pragma unroll
            for (int n = 0; n < 3; ++n)
                accu[m][n] = mf(af[m][1], bu[n][1], accu[m][n]);
        __builtin_amdgcn_s_setprio(0);
        if (pf) asm volatile("s_waitcnt vmcnt(4)" ::: "memory");
        __builtin_amdgcn_s_barrier();
    }

#pragma unroll
    for (int m = 0; m < 4; ++m) {
#pragma unroll
        for (int n = 0; n < 3; ++n) {
            int row = bm + wr * 64 + m * 16 + g4 * 4;
            int col = bn + wc * 48 + n * 16 + l15;
#pragma unroll
            for (int r = 0; r < 4; ++r) {
                float g = accg[m][n][r];
                float u = accu[m][n][r];
                OUT[(size_t)(row + r) * kFF + col] = f2bf(g / (1.0f + __expf(-g)) * u);
            }
        }
    }
}

// Fused per-head RMSNorm (D=128) + RoPE for q and k. Reads bf16 QKV.
__global__ __launch_bounds__(256)
void qknorm_rope(const unsigned short* __restrict__ qkv, const int* __restrict__ positions,
                 const float* __restrict__ qnw, const float* __restrict__ knw,
                 unsigned short* __restrict__ Qo, unsigned short* __restrict__ Ko) {
    const int t    = blockIdx.x;
    const int j    = blockIdx.y * 4 + (threadIdx.x >> 6);  // 0..23
    const int lane = threadIdx.x & 63;
    const unsigned short* src = qkv + (size_t)t * 4096 + j * 128;
    float x1 = bf2f(src[lane]);
    float x2 = bf2f(src[lane + 64]);
    float ss = x1 * x1 + x2 * x2;
#pragma unroll
    for (int m = 1; m < 64; m <<= 1) ss += __shfl_xor(ss, m);
    float rs = rsqrtf(ss * (1.0f / 128.0f) + 1e-6f);
    const float* w = (j < 16) ? qnw : knw;
    float n1 = x1 * rs * w[lane];
    float n2 = x2 * rs * w[lane + 64];
    float inv = powf(1.0e6f, -(float)lane * (1.0f / 64.0f));
    float fr = (float)positions[t] * inv;
    float sn, cs;
    sincosf(fr, &sn, &cs);
    float o1 = n1 * cs - n2 * sn;
    float o2 = n2 * cs + n1 * sn;
    if (j < 16) {
        unsigned short* d = Qo + (size_t)t * (kH * kD) + j * kD;
        d[lane] = f2bf(o1);
        d[lane + 64] = f2bf(o2);
    } else {
        unsigned short* d = Ko + (size_t)t * (kHK * kD) + (j - 16) * kD;
        d[lane] = f2bf(o1);
        d[lane + 64] = f2bf(o2);
    }
}

// V transpose: bf16 qkv v-part -> Vt bf16 (1024 x T), pure pass-through.
__global__ __launch_bounds__(256)
void vtrans(const unsigned short* __restrict__ qkv, unsigned short* __restrict__ Vt) {
    __shared__ unsigned short tile[32][33];
    const int t0 = blockIdx.x * 32;
    const int d0 = blockIdx.y * 32;
    const int tc = threadIdx.x & 31;
    const int tr = threadIdx.x >> 5;  // 0..7
#pragma unroll
    for (int i = 0; i < 4; ++i) {
        int trow = tr + i * 8;
        tile[trow][tc] = qkv[(size_t)(t0 + trow) * 4096 + 3072 + d0 + tc];
    }
    __syncthreads();
#pragma unroll
    for (int i = 0; i < 4; ++i) {
        int drow = tr + i * 8;
        Vt[(size_t)(d0 + drow) * kT + t0 + tc] = tile[tc][drow];
    }
}

// Causal flash attention v5: kv-split-2 with in-kernel merge (proven R8-R11).
__global__ __launch_bounds__(512, 4)
void attn_fwd5(const unsigned short* __restrict__ Q,   // T x (H*D)
               const unsigned short* __restrict__ Kc,  // T x (HK*D)
               const unsigned short* __restrict__ Vt,  // (HK*D) x T
               unsigned short* __restrict__ O) {       // T x (H*D)
    __shared__ unsigned short Kb[2][64 * 128];
    __shared__ unsigned short Vb[2][128 * 64];
    __shared__ float MergeML[4][2][64];

    const int tid  = threadIdx.x;
    const int lane = tid & 63;
    const int l15  = lane & 15;
    const int g4   = lane >> 4;
    const int wid  = tid >> 6;       // 0..7
    const int s    = wid & 1;        // kv split
    const int grp  = wid >> 1;       // 0..3 = (hs, qsub)
    const int hs   = grp >> 1;
    const int qsub = grp & 1;
    const int hkk  = blockIdx.x;
    const int h    = hkk * 2 + hs;
    const int nby  = gridDim.y;
    const int by   = blockIdx.y;
    const int byl  = (by & 1) ? (nby - 1 - (by >> 1)) : (by >> 1);
    const int q0   = byl * 32 + qsub * 16;
    const int nch  = byl / 2 + 1;
    const int c0   = (nch + 1) >> 1;
    const int myn  = s ? (nch - c0) : c0;
    const int qi   = q0 + l15;
    const int vt   = grp * 64 + lane;

    const int addrA = ((g4 & 1) * 32 + l15) * 4;
    const int addrB = addrA + 64;
    const int addrQ = g4 * 80;
    const bool hb   = (g4 >> 1) != 0;

    bf16x8 qf[4];
#pragma unroll
    for (int ks = 0; ks < 4; ++ks)
        qf[ks] = *(const bf16x8*)(Q + (size_t)(q0 + l15) * (kH * kD) + h * kD + ks * 32 + g4 * 8);

    f32x4 oacc[8] = {};
    float mrun = -3e38f, lrun = 0.f;
    const float scale = 0.08838834764831845f;  // 1/sqrt(128)

    auto stage = [&](int kv0) {
#pragma unroll
        for (int i = 0; i < 4; ++i) {
            int ch  = vt + i * 256;
            int row = ch >> 4;
            int c16 = ch & 15;
            gload_lds16(Kc + (size_t)(kv0 + row) * (kHK * kD) + hkk * kD
                            + ((c16 ^ (row & 7)) * 8),
                        (char*)Kb[s] + ch * 16);
        }
#pragma unroll
        for (int i = 0; i < 4; ++i) {
            int ch  = vt + i * 256;
            int row = ch >> 3;
            int c8  = ch & 7;
            gload_lds16(Vt + (size_t)(hkk * kD + row) * kT + kv0
                            + ((c8 ^ (row & 7)) * 8),
                        (char*)Vb[s] + ch * 16);
        }
    };

    for (int c = 0; c < c0; ++c) {
        const bool act = c < myn;
        const int kv0 = (s ? (c0 + c) : c) * 64;
        if (act) stage(kv0);
        asm volatile("s_waitcnt vmcnt(0)" ::: "memory");
        __builtin_amdgcn_s_barrier();
        __builtin_amdgcn_sched_barrier(0);

        if (act) {
            f32x4 sa[4] = {};
            __builtin_amdgcn_s_setprio(1);
#pragma unroll
            for (int hh = 0; hh < 4; ++hh) {
                const int row = hh * 16 + l15;
#pragma unroll
                for (int ks = 0; ks < 4; ++ks) {
                    bf16x8 kf = *(const bf16x8*)((const char*)Kb[s]
                                  + row * 256 + (((ks * 4 + g4) ^ (row & 7)) * 16));
                    sa[hh] = mf(kf, qf[ks], sa[hh]);
                }
            }
            __builtin_amdgcn_s_setprio(0);

            float sv[4][4];
#pragma unroll
            for (int hh = 0; hh < 4; ++hh)
#pragma unroll
                for (int r = 0; r < 4; ++r)
                    sv[hh][r] = sa[hh][r] * scale;
            if (kv0 + 63 > q0) {
#pragma unroll
                for (int hh = 0; hh < 4; ++hh)
#pragma unroll
                    for (int r = 0; r < 4; ++r) {
                        int ki = kv0 + hh * 16 + g4 * 4 + r;
                        if (ki > qi) sv[hh][r] = -3e38f;
                    }
            }

            float m16;
            {
                float a = fmaxf(fmaxf(sv[0][0], sv[0][1]), fmaxf(sv[0][2], sv[0][3]));
                float b2 = fmaxf(fmaxf(sv[1][0], sv[1][1]), fmaxf(sv[1][2], sv[1][3]));
                float c2 = fmaxf(fmaxf(sv[2][0], sv[2][1]), fmaxf(sv[2][2], sv[2][3]));
                float d2 = fmaxf(fmaxf(sv[3][0], sv[3][1]), fmaxf(sv[3][2], sv[3][3]));
                m16 = fmaxf(fmaxf(a, b2), fmaxf(c2, d2));
            }
            m16 = fmaxf(m16, __shfl_xor(m16, 16));
            m16 = fmaxf(m16, __shfl_xor(m16, 32));

            if (__any(m16 > mrun)) {
                float mnew = fmaxf(mrun, m16);
                float corr = __expf(mrun - mnew);
                mrun = mnew;
                lrun *= corr;
                float cr[4];
#pragma unroll
                for (int r = 0; r < 4; ++r)
                    cr[r] = __int_as_float(__builtin_amdgcn_ds_bpermute(
                                addrQ + 4 * r, __float_as_int(corr)));
#pragma unroll
                for (int c2 = 0; c2 < 8; ++c2)
#pragma unroll
                    for (int r = 0; r < 4; ++r)
                        oacc[c2][r] *= cr[r];
            }

            float p[4][4];
            float ps = 0.f;
#pragma unroll
            for (int hh = 0; hh < 4; ++hh)
#pragma unroll
                for (int r = 0; r < 4; ++r) {
                    float pe = __expf(sv[hh][r] - mrun);
                    p[hh][r] = pe;
                    ps += pe;
                }
            ps += __shfl_xor(ps, 16);
            ps += __shfl_xor(ps, 32);
            lrun += ps;

            unsigned pk[4][2];
#pragma unroll
            for (int hh = 0; hh < 4; ++hh) {
                asm("v_cvt_pk_bf16_f32 %0, %1, %2"
                    : "=v"(pk[hh][0]) : "v"(p[hh][0]), "v"(p[hh][1]));
                asm("v_cvt_pk_bf16_f32 %0, %1, %2"
                    : "=v"(pk[hh][1]) : "v"(p[hh][2]), "v"(p[hh][3]));
            }
            int ex[4][2][2];
#pragma unroll
            for (int hh = 0; hh < 4; ++hh)
#pragma unroll
                for (int ii = 0; ii < 2; ++ii) {
                    ex[hh][ii][0] = __builtin_amdgcn_ds_bpermute(addrA, (int)pk[hh][ii]);
                    ex[hh][ii][1] = __builtin_amdgcn_ds_bpermute(addrB, (int)pk[hh][ii]);
                }
            union { int w[4]; bf16x8 v; } pu0, pu1;
#pragma unroll
            for (int jw = 0; jw < 4; ++jw) {
                pu0.w[jw] = hb ? ex[1][jw & 1][jw >> 1] : ex[0][jw & 1][jw >> 1];
                pu1.w[jw] = hb ? ex[3][jw & 1][jw >> 1] : ex[2][jw & 1][jw >> 1];
            }
            bf16x8 pa0 = pu0.v;
            bf16x8 pa1 = pu1.v;

            __builtin_amdgcn_s_setprio(1);
#pragma unroll
            for (int c2 = 0; c2 < 8; ++c2) {
                const int d = c2 * 16 + l15;
                bf16x8 vf0 = *(const bf16x8*)((const char*)Vb[s]
                              + d * 128 + ((g4 ^ (d & 7)) * 16));
                oacc[c2] = mf(pa0, vf0, oacc[c2]);
                bf16x8 vf1 = *(const bf16x8*)((const char*)Vb[s]
                              + d * 128 + ((((4 + g4) ^ (d & 7))) * 16));
                oacc[c2] = mf(pa1, vf1, oacc[c2]);
            }
            __builtin_amdgcn_s_setprio(0);
        }
        __builtin_amdgcn_s_barrier();
    }

    float* KbF = (float*)&Kb[0][0];
    if (s == 1) {
        MergeML[grp][0][lane] = mrun;
        MergeML[grp][1][lane] = lrun;
#pragma unroll
        for (int c2 = 0; c2 < 8; ++c2)
#pragma unroll
            for (int r = 0; r < 4; ++r)
                KbF[grp * 2048 + (c2 * 4 + r) * 64 + lane] = oacc[c2][r];
    }
    asm volatile("s_waitcnt lgkmcnt(0)" ::: "memory");
    __builtin_amdgcn_s_barrier();

    if (s == 0) {
        float m1 = MergeML[grp][0][lane];
        float l1 = MergeML[grp][1][lane];
        float mg = fmaxf(mrun, m1);
        float a0 = __expf(mrun - mg);
        float a1 = __expf(m1 - mg);
        float L  = lrun * a0 + l1 * a1;
        float ar0[4], ar1[4], Lr[4];
#pragma unroll
        for (int r = 0; r < 4; ++r) {
            ar0[r] = __int_as_float(__builtin_amdgcn_ds_bpermute(
                         addrQ + 4 * r, __float_as_int(a0)));
            ar1[r] = __int_as_float(__builtin_amdgcn_ds_bpermute(
                         addrQ + 4 * r, __float_as_int(a1)));
            Lr[r]  = __int_as_float(__builtin_amdgcn_ds_bpermute(
                         addrQ + 4 * r, __float_as_int(L)));
        }
#pragma unroll
        for (int c2 = 0; c2 < 8; ++c2)
#pragma unroll
            for (int r = 0; r < 4; ++r) {
                float oex = KbF[grp * 2048 + (c2 * 4 + r) * 64 + lane];
                float v = (oacc[c2][r] * ar0[r] + oex * ar1[r]) / Lr[r];
                O[(size_t)(q0 + g4 * 4 + r) * (kH * kD) + h * kD + c2 * 16 + l15] = f2bf(v);
            }
    }
}

}  // namespace

extern "C" void kernel_launch(void* const* d_in, const int* in_sizes, int n_in,
                              void* d_out, int out_size, void* d_ws, size_t ws_size,
                              hipStream_t stream) {
    (void)in_sizes; (void)n_in; (void)out_size; (void)ws_size;

    const int*   positions = (const int*)  d_in[0];
    const float* hidden    = (const float*)d_in[1];
    const float* wq  = (const float*)d_in[2];
    const float* wk  = (const float*)d_in[3];
    const float* wv  = (const float*)d_in[4];
    const float* wo  = (const float*)d_in[5];
    const float* qnw = (const float*)d_in[6];
    const float* knw = (const float*)d_in[7];
    const float* ln1 = (const float*)d_in[8];
    const float* ln2 = (const float*)d_in[9];
    const float* wg  = (const float*)d_in[10];
    const float* wu  = (const float*)d_in[11];
    const float* wd  = (const float*)d_in[12];

    char* ws = (char*)d_ws;
    unsigned short* WQKV = (unsigned short*)(ws + 0);          // 4096x2048 bf16
    unsigned short* WO   = (unsigned short*)(ws + 16777216);   // 2048x2048
    unsigned short* WG   = (unsigned short*)(ws + 25165824);   // 6144x2048
    unsigned short* WU   = (unsigned short*)(ws + 50331648);   // 6144x2048
    unsigned short* WD   = (unsigned short*)(ws + 75497472);   // 2048x6144
    unsigned short* XN1  = (unsigned short*)(ws + 100663296);  // T x 2048
    unsigned short* OATT = (unsigned short*)(ws + 109051904);  // T x 2048
    float*          H1   = (float*)(ws + 117440512);           // T x 2048 fp32
    unsigned short* XN2  = (unsigned short*)(ws + 134217728);  // T x 2048
    unsigned short* QKVB = (unsigned short*)(ws + 142606336);  // T x 4096 bf16
    unsigned short* QB   = (unsigned short*)(ws + 176160768);  // T x 2048
    unsigned short* KB   = (unsigned short*)(ws + 184549376);  // T x 1024
    unsigned short* VT   = (unsigned short*)(ws + 188743680);  // 1024 x T
    unsigned short* ACT  = (unsigned short*)(ws + 167772160);  // T x 6144

    // O-proj split-K2 bf16 partials (8 MB each; QKVB span dead then)
    unsigned short* OP0 = (unsigned short*)(ws + 142606336);
    unsigned short* OP1 = (unsigned short*)(ws + 159383552);
    // down split-K4 bf16 partials (8 MB each; dead regions audited)
    unsigned short* DP0 = (unsigned short*)(ws + 0);
    unsigned short* DP1 = (unsigned short*)(ws + 16777216);
    unsigned short* DP2 = (unsigned short*)(ws + 33554432);
    unsigned short* DP3 = (unsigned short*)(ws + 142606336);

    // single fused weight conversion (wq|wk|wv|wo|wg|wu|wd -> ws bf16 prefix)
    cvt_all<<<dim3(49152), dim3(256), 0, stream>>>(
        wq, wk, wv, wo, wg, wu, wd, (ushort4*)ws);

    rmsnorm_k<<<dim3(kT), dim3(256), 0, stream>>>(hidden, ln1, XN1);

    // QKV GEMM: 128x256 tile, grid 16x16 = 256 exact, bf16 output
    gemm128<1><<<dim3(4096 / 256, kT / 128), dim3(512), 0, stream>>>(
        XN1, WQKV, QKVB, kT, 4096, kHid, kHid, nullptr, nullptr);

    qknorm_rope<<<dim3(kT, 6), dim3(256), 0, stream>>>(QKVB, positions, qnw, knw, QB, KB);
    vtrans<<<dim3(kT / 32, 1024 / 32), dim3(256), 0, stream>>>(QKVB, VT);

    attn_fwd5<<<dim3(kHK, kT / 32), dim3(512), 0, stream>>>(QB, KB, VT, OATT);

    // O-proj: 128x256 split-K2 (grid 8x16x2 = 256 exact) -> bf16 partials
    gemm128<4><<<dim3(kHid / 256, kT / 128, 2), dim3(512), 0, stream>>>(
        OATT, WO, nullptr, kT, kHid, kHid, 1024, OP0, OP1);
    // fused: H1 = p0+p1+hidden; XN2 = rmsnorm(H1)*ln2
    rmsnorm_red2b<<<dim3(kT), dim3(256), 0, stream>>>(
        OP0, OP1, hidden, ln2, H1, XN2);

    // fused gate+up GEMM: 256x96 tile, grid 64x8 = 512 (A-panel XCD swizzle)
    gemm_gu<<<dim3(kFF / 96, kT / 256), dim3(512), 0, stream>>>(XN2, WG, WU, ACT);

    // down: 256x256 split-K4 (KS=1536, grid 8x8x4 = 256 exact) -> bf16 partials
    gemm256<4><<<dim3(kHid / 256, kT / 256, 4), dim3(512), 0, stream>>>(
        ACT, WD, nullptr, kT, kHid, kFF, 1536, DP0, DP1, DP2, DP3);
    reduce4b<<<dim3(kT * kHid / 8 / 256), dim3(256), 0, stream>>>(
        (const unsigned int*)DP0, (const unsigned int*)DP1,
        (const unsigned int*)DP2, (const unsigned int*)DP3,
        H1, (float*)d_out, kT * kHid / 8);
}

// Round 21
// 351.171 us; speedup vs baseline: 1.0982x; 1.0107x over previous
//
#include <hip/hip_runtime.h>
#include <hip/hip_bf16.h>
#include <stdint.h>

namespace {

constexpr int kT   = 2048;
constexpr int kHid = 2048;
constexpr int kH   = 16;
constexpr int kHK  = 8;
constexpr int kD   = 128;
constexpr int kFF  = 6144;

using bf16x8 = __attribute__((ext_vector_type(8))) short;
using f32x4  = __attribute__((ext_vector_type(4))) float;

__device__ __forceinline__ float bf2f(unsigned short u) {
    return __uint_as_float(((unsigned)u) << 16);
}
__device__ __forceinline__ unsigned short f2bf(float f) {
    unsigned u = __float_as_uint(f);
    return (unsigned short)((u + 0x7fffu + ((u >> 16) & 1u)) >> 16);
}
__device__ __forceinline__ void gload_lds16(const void* g, void* l) {
    __builtin_amdgcn_global_load_lds(
        (__attribute__((address_space(1))) void*)g,
        (__attribute__((address_space(3))) void*)l, 16, 0, 0);
}
__device__ __forceinline__ f32x4 mf(bf16x8 a, bf16x8 b, f32x4 c) {
    return __builtin_amdgcn_mfma_f32_16x16x32_bf16(a, b, c, 0, 0, 0);
}

// One-shot fp32->bf16 conversion of all seven weight matrices into the
// contiguous ws prefix. Grid-stride: 4096 blocks x 256 thr x 12 iters =
// 12,582,912 float4 exact. Stride 1,048,576 aligns iters to region bounds.
//   wq [0,1048576) wk [..,1572864) wv [..,2097152) wo [..,3145728)
//   wg [..,6291456) wu [..,9437184) wd [..,12582912)
__global__ __launch_bounds__(256)
void cvt_all(const float* __restrict__ wq, const float* __restrict__ wk,
             const float* __restrict__ wv, const float* __restrict__ wo,
             const float* __restrict__ wg, const float* __restrict__ wu,
             const float* __restrict__ wd, ushort4* __restrict__ dst) {
    const int j = blockIdx.x * 256 + threadIdx.x;  // 0..1048575
#pragma unroll
    for (int k = 0; k < 12; ++k) {
        int i = j + k * 1048576;
        const float4* src;
        int base;
        if (i < 3145728) {
            if (i < 1048576)      { src = (const float4*)wq; base = 0; }
            else if (i < 1572864) { src = (const float4*)wk; base = 1048576; }
            else if (i < 2097152) { src = (const float4*)wv; base = 1572864; }
            else                  { src = (const float4*)wo; base = 2097152; }
        } else {
            if (i < 6291456)      { src = (const float4*)wg; base = 3145728; }
            else if (i < 9437184) { src = (const float4*)wu; base = 6291456; }
            else                  { src = (const float4*)wd; base = 9437184; }
        }
        float4 v = src[i - base];
        ushort4 o;
        o.x = f2bf(v.x); o.y = f2bf(v.y); o.z = f2bf(v.z); o.w = f2bf(v.w);
        dst[i] = o;
    }
}

// out = bf16(p0)+bf16(p1)+bf16(p2)+bf16(p3)+res(fp32); 8 elems/thread.
__global__ __launch_bounds__(256)
void reduce4b(const unsigned int* __restrict__ p0, const unsigned int* __restrict__ p1,
              const unsigned int* __restrict__ p2, const unsigned int* __restrict__ p3,
              const float* __restrict__ res, float* __restrict__ out, int n8) {
    int i = blockIdx.x * 256 + threadIdx.x;
    if (i >= n8) return;
    uint4 a = ((const uint4*)p0)[i];
    uint4 b = ((const uint4*)p1)[i];
    uint4 c = ((const uint4*)p2)[i];
    uint4 d = ((const uint4*)p3)[i];
    const float4* rr = (const float4*)res;
    float4 r0 = rr[2 * i], r1 = rr[2 * i + 1];
    unsigned aw[4] = {a.x, a.y, a.z, a.w};
    unsigned bw[4] = {b.x, b.y, b.z, b.w};
    unsigned cw[4] = {c.x, c.y, c.z, c.w};
    unsigned dw[4] = {d.x, d.y, d.z, d.w};
    float rv[8] = {r0.x, r0.y, r0.z, r0.w, r1.x, r1.y, r1.z, r1.w};
    float ov[8];
#pragma unroll
    for (int w = 0; w < 4; ++w) {
        ov[2 * w]     = bf2f((unsigned short)(aw[w] & 0xffff))
                      + bf2f((unsigned short)(bw[w] & 0xffff))
                      + bf2f((unsigned short)(cw[w] & 0xffff))
                      + bf2f((unsigned short)(dw[w] & 0xffff)) + rv[2 * w];
        ov[2 * w + 1] = bf2f((unsigned short)(aw[w] >> 16))
                      + bf2f((unsigned short)(bw[w] >> 16))
                      + bf2f((unsigned short)(cw[w] >> 16))
                      + bf2f((unsigned short)(dw[w] >> 16)) + rv[2 * w + 1];
    }
    float4* oo = (float4*)out;
    oo[2 * i]     = make_float4(ov[0], ov[1], ov[2], ov[3]);
    oo[2 * i + 1] = make_float4(ov[4], ov[5], ov[6], ov[7]);
}

// RMSNorm over HID=2048, fp32 in -> bf16 out. 1 block per row.
__global__ __launch_bounds__(256)
void rmsnorm_k(const float* __restrict__ x, const float* __restrict__ w,
               unsigned short* __restrict__ out) {
    const int row = blockIdx.x;
    const int tid = threadIdx.x;
    const float4* xr = (const float4*)(x + (size_t)row * kHid);
    float4 v0 = xr[tid];
    float4 v1 = xr[tid + 256];
    float ss = v0.x*v0.x + v0.y*v0.y + v0.z*v0.z + v0.w*v0.w
             + v1.x*v1.x + v1.y*v1.y + v1.z*v1.z + v1.w*v1.w;
#pragma unroll
    for (int m = 1; m < 64; m <<= 1) ss += __shfl_xor(ss, m);
    __shared__ float red[4];
    if ((tid & 63) == 0) red[tid >> 6] = ss;
    __syncthreads();
    float tot = red[0] + red[1] + red[2] + red[3];
    float rs = rsqrtf(tot * (1.0f / kHid) + 1e-6f);
    const float4* wv = (const float4*)w;
    float4 w0 = wv[tid], w1 = wv[tid + 256];
    ushort4 o0, o1;
    o0.x = f2bf(v0.x * rs * w0.x); o0.y = f2bf(v0.y * rs * w0.y);
    o0.z = f2bf(v0.z * rs * w0.z); o0.w = f2bf(v0.w * rs * w0.w);
    o1.x = f2bf(v1.x * rs * w1.x); o1.y = f2bf(v1.y * rs * w1.y);
    o1.z = f2bf(v1.z * rs * w1.z); o1.w = f2bf(v1.w * rs * w1.w);
    ushort4* orow = (ushort4*)(out + (size_t)row * kHid);
    orow[tid] = o0;
    orow[tid + 256] = o1;
}

// Fused: h = bf16(p0)+bf16(p1)+res -> H1; XN2 = rmsnorm(h)*w. 1 block/row.
__global__ __launch_bounds__(256)
void rmsnorm_red2b(const unsigned short* __restrict__ p0,
                   const unsigned short* __restrict__ p1,
                   const float* __restrict__ res, const float* __restrict__ w,
                   float* __restrict__ H, unsigned short* __restrict__ out) {
    const int row = blockIdx.x;
    const int tid = threadIdx.x;
    const size_t base = (size_t)row * kHid;
    float4 v0, v1;
    {
        const ushort4* a = (const ushort4*)(p0 + base);
        const ushort4* b = (const ushort4*)(p1 + base);
        const float4*  r = (const float4*)(res + base);
        ushort4 a0 = a[tid], b0 = b[tid];
        float4 r0 = r[tid];
        v0.x = bf2f(a0.x) + bf2f(b0.x) + r0.x;
        v0.y = bf2f(a0.y) + bf2f(b0.y) + r0.y;
        v0.z = bf2f(a0.z) + bf2f(b0.z) + r0.z;
        v0.w = bf2f(a0.w) + bf2f(b0.w) + r0.w;
        ushort4 a1 = a[tid + 256], b1 = b[tid + 256];
        float4 r1 = r[tid + 256];
        v1.x = bf2f(a1.x) + bf2f(b1.x) + r1.x;
        v1.y = bf2f(a1.y) + bf2f(b1.y) + r1.y;
        v1.z = bf2f(a1.z) + bf2f(b1.z) + r1.z;
        v1.w = bf2f(a1.w) + bf2f(b1.w) + r1.w;
    }
    ((float4*)(H + base))[tid] = v0;
    ((float4*)(H + base))[tid + 256] = v1;
    float ss = v0.x*v0.x + v0.y*v0.y + v0.z*v0.z + v0.w*v0.w
             + v1.x*v1.x + v1.y*v1.y + v1.z*v1.z + v1.w*v1.w;
#pragma unroll
    for (int m = 1; m < 64; m <<= 1) ss += __shfl_xor(ss, m);
    __shared__ float red[4];
    if ((tid & 63) == 0) red[tid >> 6] = ss;
    __syncthreads();
    float tot = red[0] + red[1] + red[2] + red[3];
    float rs = rsqrtf(tot * (1.0f / kHid) + 1e-6f);
    const float4* wv = (const float4*)w;
    float4 w0 = wv[tid], w1 = wv[tid + 256];
    ushort4 o0, o1;
    o0.x = f2bf(v0.x * rs * w0.x); o0.y = f2bf(v0.y * rs * w0.y);
    o0.z = f2bf(v0.z * rs * w0.z); o0.w = f2bf(v0.w * rs * w0.w);
    o1.x = f2bf(v1.x * rs * w1.x); o1.y = f2bf(v1.y * rs * w1.y);
    o1.z = f2bf(v1.z * rs * w1.z); o1.w = f2bf(v1.w * rs * w1.w);
    ushort4* orow = (ushort4*)(out + base);
    orow[tid] = o0;
    orow[tid + 256] = o1;
}

// -------- 256x256 8-phase GEMM (proven; EPI4 split-K bf16 partials) --------
template <int EPI>
__global__ __launch_bounds__(512, 2)
void gemm256(const unsigned short* __restrict__ A,
             const unsigned short* __restrict__ B,
             void* __restrict__ C,
             int M, int N, int K, int KS,
             unsigned short* __restrict__ p0, unsigned short* __restrict__ p1,
             unsigned short* __restrict__ p2, unsigned short* __restrict__ p3) {
    __shared__ unsigned short smem[2][4][128 * 64];  // 128 KiB

    const int tid  = threadIdx.x;
    const int lane = tid & 63;
    const int l15  = lane & 15;
    const int g4   = lane >> 4;
    const int wid  = tid >> 6;
    const int wr   = wid >> 2;
    const int wc   = wid & 3;
    const int bm   = blockIdx.y * 256;
    const int bn   = blockIdx.x * 256;
    const int kb   = (EPI == 4) ? blockIdx.z * KS : 0;
    const int NT   = ((EPI == 4) ? KS : K) >> 6;
    const int NI   = NT >> 1;

    f32x4 acc[8][4] = {};

    auto stage = [&](int b, int reg, int t) {
        const unsigned short* Base = (reg < 2) ? A : B;
        const int br = ((reg < 2) ? bm : bn) + (reg & 1) * 128;
#pragma unroll
        for (int i = 0; i < 2; ++i) {
            int ch   = tid + i * 512;
            int row  = ch >> 3;
            int slot = (ch & 7) ^ (row & 7);
            gload_lds16(Base + (size_t)(br + row) * K + kb + t * 64 + slot * 8,
                        (char*)&smem[b][reg][0] + ch * 16);
        }
    };
    auto rdA = [&](int b, int m, int ks) {
        int row = m * 16 + l15;
        return *(const bf16x8*)((const char*)&smem[b][wr][0]
               + row * 128 + (((ks * 4 + g4) ^ (row & 7)) * 16));
    };
    auto rdB = [&](int b, int n, int ks) {
        int row = wc * 64 + n * 16 + l15;
        return *(const bf16x8*)((const char*)&smem[b][2 + (row >> 7)][0]
               + (row & 127) * 128 + (((ks * 4 + g4) ^ (row & 7)) * 16));
    };

    stage(0, 2, 0); stage(0, 3, 0); stage(0, 0, 0); stage(0, 1, 0);
    stage(1, 2, 1); stage(1, 3, 1); stage(1, 0, 1);
    asm volatile("s_waitcnt vmcnt(6)" ::: "memory");
    __builtin_amdgcn_s_barrier();

    for (int i = 0; i < NI; ++i) {
        const int e  = 2 * i;
        const int o  = e + 1;
        const bool pf = (e + 2 < NT);
        bf16x8 af[4][2], bfr[4][2];

#pragma unroll
        for (int m = 0; m < 4; ++m) { af[m][0] = rdA(0, m, 0); af[m][1] = rdA(0, m, 1); }
#pragma unroll
        for (int n = 0; n < 4; ++n) { bfr[n][0] = rdB(0, n, 0); bfr[n][1] = rdB(0, n, 1); }
        stage(1, 1, o);
        __builtin_amdgcn_s_barrier();
        asm volatile("s_waitcnt lgkmcnt(0)" ::: "memory");
        __builtin_amdgcn_sched_barrier(0);
        __builtin_amdgcn_s_setprio(1);
#pragma unroll
        for (int m = 0; m < 4; ++m)
#pragma unroll
            for (int n = 0; n < 2; ++n) {
                acc[m][n] = mf(af[m][0], bfr[n][0], acc[m][n]);
                acc[m][n] = mf(af[m][1], bfr[n][1], acc[m][n]);
            }
        __builtin_amdgcn_s_setprio(0);
        __builtin_amdgcn_s_barrier();

        if (pf) stage(0, 2, e + 2);
        __builtin_amdgcn_s_barrier();
        __builtin_amdgcn_s_setprio(1);
#pragma unroll
        for (int m = 0; m < 4; ++m)
#pragma unroll
            for (int n = 2; n < 4; ++n) {
                acc[m][n] = mf(af[m][0], bfr[n][0], acc[m][n]);
                acc[m][n] = mf(af[m][1], bfr[n][1], acc[m][n]);
            }
        __builtin_amdgcn_s_setprio(0);
        __builtin_amdgcn_s_barrier();

#pragma unroll
        for (int m = 0; m < 4; ++m) { af[m][0] = rdA(0, 4 + m, 0); af[m][1] = rdA(0, 4 + m, 1); }
        if (pf) stage(0, 3, e + 2);
        __builtin_amdgcn_s_barrier();
        asm volatile("s_waitcnt lgkmcnt(0)" ::: "memory");
        __builtin_amdgcn_sched_barrier(0);
        __builtin_amdgcn_s_setprio(1);
#pragma unroll
        for (int m = 0; m < 4; ++m)
#pragma unroll
            for (int n = 0; n < 2; ++n) {
                acc[4 + m][n] = mf(af[m][0], bfr[n][0], acc[4 + m][n]);
                acc[4 + m][n] = mf(af[m][1], bfr[n][1], acc[4 + m][n]);
            }
        __builtin_amdgcn_s_setprio(0);
        __builtin_amdgcn_s_barrier();

        if (pf) stage(0, 0, e + 2);
        __builtin_amdgcn_s_barrier();
        __builtin_amdgcn_s_setprio(1);
#pragma unroll
        for (int m = 0; m < 4; ++m)
#pragma unroll
            for (int n = 2; n < 4; ++n) {
                acc[4 + m][n] = mf(af[m][0], bfr[n][0], acc[4 + m][n]);
                acc[4 + m][n] = mf(af[m][1], bfr[n][1], acc[4 + m][n]);
            }
        __builtin_amdgcn_s_setprio(0);
        if (pf) asm volatile("s_waitcnt vmcnt(6)" ::: "memory");
        else    asm volatile("s_waitcnt vmcnt(0)" ::: "memory");
        __builtin_amdgcn_s_barrier();

#pragma unroll
        for (int m = 0; m < 4; ++m) { af[m][0] = rdA(1, m, 0); af[m][1] = rdA(1, m, 1); }
#pragma unroll
        for (int n = 0; n < 4; ++n) { bfr[n][0] = rdB(1, n, 0); bfr[n][1] = rdB(1, n, 1); }
        if (pf) stage(0, 1, e + 2);
        __builtin_amdgcn_s_barrier();
        asm volatile("s_waitcnt lgkmcnt(0)" ::: "memory");
        __builtin_amdgcn_sched_barrier(0);
        __builtin_amdgcn_s_setprio(1);
#pragma unroll
        for (int m = 0; m < 4; ++m)
#pragma unroll
            for (int n = 0; n < 2; ++n) {
                acc[m][n] = mf(af[m][0], bfr[n][0], acc[m][n]);
                acc[m][n] = mf(af[m][1], bfr[n][1], acc[m][n]);
            }
        __builtin_amdgcn_s_setprio(0);
        __builtin_amdgcn_s_barrier();

        if (pf) stage(1, 2, o + 2);
        __builtin_amdgcn_s_barrier();
        __builtin_amdgcn_s_setprio(1);
#pragma unroll
        for (int m = 0; m < 4; ++m)
#pragma unroll
            for (int n = 2; n < 4; ++n) {
                acc[m][n] = mf(af[m][0], bfr[n][0], acc[m][n]);
                acc[m][n] = mf(af[m][1], bfr[n][1], acc[m][n]);
            }
        __builtin_amdgcn_s_setprio(0);
        __builtin_amdgcn_s_barrier();

#pragma unroll
        for (int m = 0; m < 4; ++m) { af[m][0] = rdA(1, 4 + m, 0); af[m][1] = rdA(1, 4 + m, 1); }
        if (pf) stage(1, 3, o + 2);
        __builtin_amdgcn_s_barrier();
        asm volatile("s_waitcnt lgkmcnt(0)" ::: "memory");
        __builtin_amdgcn_sched_barrier(0);
        __builtin_amdgcn_s_setprio(1);
#pragma unroll
        for (int m = 0; m < 4; ++m)
#pragma unroll
            for (int n = 0; n < 2; ++n) {
                acc[4 + m][n] = mf(af[m][0], bfr[n][0], acc[4 + m][n]);
                acc[4 + m][n] = mf(af[m][1], bfr[n][1], acc[4 + m][n]);
            }
        __builtin_amdgcn_s_setprio(0);
        __builtin_amdgcn_s_barrier();

        if (pf) stage(1, 0, o + 2);
        __builtin_amdgcn_s_barrier();
        __builtin_amdgcn_s_setprio(1);
#pragma unroll
        for (int m = 0; m < 4; ++m)
#pragma unroll
            for (int n = 2; n < 4; ++n) {
                acc[4 + m][n] = mf(af[m][0], bfr[n][0], acc[4 + m][n]);
                acc[4 + m][n] = mf(af[m][1], bfr[n][1], acc[4 + m][n]);
            }
        __builtin_amdgcn_s_setprio(0);
        if (pf) asm volatile("s_waitcnt vmcnt(6)" ::: "memory");
        __builtin_amdgcn_s_barrier();
    }

    unsigned short* P = nullptr;
    if (EPI == 4) {
        const int z = blockIdx.z;
        P = (z == 0) ? p0 : (z == 1) ? p1 : (z == 2) ? p2 : p3;
    }
#pragma unroll
    for (int m = 0; m < 8; ++m) {
#pragma unroll
        for (int n = 0; n < 4; ++n) {
            int row = bm + wr * 128 + m * 16 + g4 * 4;
            int col = bn + wc * 64 + n * 16 + l15;
#pragma unroll
            for (int r = 0; r < 4; ++r) {
                size_t idx = (size_t)(row + r) * N + col;
                float v = acc[m][n][r];
                if (EPI == 0) ((float*)C)[idx] = v;
                else          P[idx] = f2bf(v);
            }
        }
    }
}

// -------- 128M x 256N 8-phase GEMM (proven; QKV + O-proj) ------------------
// EPI: 0 = fp32 store, 1 = bf16 store, 4 = split-K2 bf16 partials.
template <int EPI>
__global__ __launch_bounds__(512, 2)
void gemm128(const unsigned short* __restrict__ A,
             const unsigned short* __restrict__ B,
             void* __restrict__ C,
             int M, int N, int K, int KS,
             unsigned short* __restrict__ p0, unsigned short* __restrict__ p1) {
    __shared__ unsigned short smem[2][3][128 * 64];  // 96 KiB

    const int tid  = threadIdx.x;
    const int lane = tid & 63;
    const int l15  = lane & 15;
    const int g4   = lane >> 4;
    const int wid  = tid >> 6;
    const int wr   = wid >> 2;
    const int wc   = wid & 3;
    const int bm   = blockIdx.y * 128;
    const int bn   = blockIdx.x * 256;
    const int kb   = (EPI == 4) ? blockIdx.z * KS : 0;
    const int NT   = ((EPI == 4) ? KS : K) >> 6;
    const int NI   = NT >> 1;

    f32x4 acc[4][4] = {};

    auto stage = [&](int b, int reg, int t) {
        const unsigned short* Base = (reg == 0) ? A : B;
        const int br = (reg == 0) ? bm : bn + (reg - 1) * 128;
#pragma unroll
        for (int i = 0; i < 2; ++i) {
            int ch   = tid + i * 512;
            int row  = ch >> 3;
            int slot = (ch & 7) ^ (row & 7);
            gload_lds16(Base + (size_t)(br + row) * K + kb + t * 64 + slot * 8,
                        (char*)&smem[b][reg][0] + ch * 16);
        }
    };
    auto rdA = [&](int b, int m, int ks) {
        int row = wr * 64 + m * 16 + l15;
        return *(const bf16x8*)((const char*)&smem[b][0][0]
               + row * 128 + (((ks * 4 + g4) ^ (row & 7)) * 16));
    };
    auto rdB = [&](int b, int n, int ks) {
        int row = wc * 64 + n * 16 + l15;
        return *(const bf16x8*)((const char*)&smem[b][1 + (row >> 7)][0]
               + (row & 127) * 128 + (((ks * 4 + g4) ^ (row & 7)) * 16));
    };

    stage(0, 1, 0); stage(0, 2, 0); stage(0, 0, 0);
    stage(1, 1, 1); stage(1, 2, 1);
    asm volatile("s_waitcnt vmcnt(4)" ::: "memory");
    __builtin_amdgcn_s_barrier();

    for (int i = 0; i < NI; ++i) {
        const int e  = 2 * i;
        const int o  = e + 1;
        const bool pf = (e + 2 < NT);
        bf16x8 af[4][2], bfr[4][2];

#pragma unroll
        for (int m = 0; m < 4; ++m) { af[m][0] = rdA(0, m, 0); af[m][1] = rdA(0, m, 1); }
#pragma unroll
        for (int n = 0; n < 4; ++n) { bfr[n][0] = rdB(0, n, 0); bfr[n][1] = rdB(0, n, 1); }
        stage(1, 0, o);
        __builtin_amdgcn_s_barrier();
        asm volatile("s_waitcnt lgkmcnt(0)" ::: "memory");
        __builtin_amdgcn_sched_barrier(0);
        __builtin_amdgcn_s_setprio(1);
#pragma unroll
        for (int m = 0; m < 4; ++m) {
            acc[m][0] = mf(af[m][0], bfr[0][0], acc[m][0]);
            acc[m][0] = mf(af[m][1], bfr[0][1], acc[m][0]);
        }
        __builtin_amdgcn_s_setprio(0);
        __builtin_amdgcn_s_barrier();

        if (pf) stage(0, 1, e + 2);
        __builtin_amdgcn_s_barrier();
        __builtin_amdgcn_s_setprio(1);
#pragma unroll
        for (int m = 0; m < 4; ++m) {
            acc[m][1] = mf(af[m][0], bfr[1][0], acc[m][1]);
            acc[m][1] = mf(af[m][1], bfr[1][1], acc[m][1]);
        }
        __builtin_amdgcn_s_setprio(0);
        __builtin_amdgcn_s_barrier();

        if (pf) stage(0, 2, e + 2);
        __builtin_amdgcn_s_barrier();
        __builtin_amdgcn_s_setprio(1);
#pragma unroll
        for (int m = 0; m < 4; ++m) {
            acc[m][2] = mf(af[m][0], bfr[2][0], acc[m][2]);
            acc[m][2] = mf(af[m][1], bfr[2][1], acc[m][2]);
        }
        __builtin_amdgcn_s_setprio(0);
        __builtin_amdgcn_s_barrier();

        __builtin_amdgcn_s_setprio(1);
#pragma unroll
        for (int m = 0; m < 4; ++m) {
            acc[m][3] = mf(af[m][0], bfr[3][0], acc[m][3]);
            acc[m][3] = mf(af[m][1], bfr[3][1], acc[m][3]);
        }
        __builtin_amdgcn_s_setprio(0);
        if (pf) asm volatile("s_waitcnt vmcnt(4)" ::: "memory");
        else    asm volatile("s_waitcnt vmcnt(0)" ::: "memory");
        __builtin_amdgcn_s_barrier();

#pragma unroll
        for (int m = 0; m < 4; ++m) { af[m][0] = rdA(1, m, 0); af[m][1] = rdA(1, m, 1); }
#pragma unroll
        for (int n = 0; n < 4; ++n) { bfr[n][0] = rdB(1, n, 0); bfr[n][1] = rdB(1, n, 1); }
        if (pf) stage(0, 0, e + 2);
        __builtin_amdgcn_s_barrier();
        asm volatile("s_waitcnt lgkmcnt(0)" ::: "memory");
        __builtin_amdgcn_sched_barrier(0);
        __builtin_amdgcn_s_setprio(1);
#pragma unroll
        for (int m = 0; m < 4; ++m) {
            acc[m][0] = mf(af[m][0], bfr[0][0], acc[m][0]);
            acc[m][0] = mf(af[m][1], bfr[0][1], acc[m][0]);
        }
        __builtin_amdgcn_s_setprio(0);
        __builtin_amdgcn_s_barrier();

        if (pf) stage(1, 1, o + 2);
        __builtin_amdgcn_s_barrier();
        __builtin_amdgcn_s_setprio(1);
#pragma unroll
        for (int m = 0; m < 4; ++m) {
            acc[m][1] = mf(af[m][0], bfr[1][0], acc[m][1]);
            acc[m][1] = mf(af[m][1], bfr[1][1], acc[m][1]);
        }
        __builtin_amdgcn_s_setprio(0);
        __builtin_amdgcn_s_barrier();

        if (pf) stage(1, 2, o + 2);
        __builtin_amdgcn_s_barrier();
        __builtin_amdgcn_s_setprio(1);
#pragma unroll
        for (int m = 0; m < 4; ++m) {
            acc[m][2] = mf(af[m][0], bfr[2][0], acc[m][2]);
            acc[m][2] = mf(af[m][1], bfr[2][1], acc[m][2]);
        }
        __builtin_amdgcn_s_setprio(0);
        __builtin_amdgcn_s_barrier();

        __builtin_amdgcn_s_setprio(1);
#pragma unroll
        for (int m = 0; m < 4; ++m) {
            acc[m][3] = mf(af[m][0], bfr[3][0], acc[m][3]);
            acc[m][3] = mf(af[m][1], bfr[3][1], acc[m][3]);
        }
        __builtin_amdgcn_s_setprio(0);
        if (pf) asm volatile("s_waitcnt vmcnt(4)" ::: "memory");
        __builtin_amdgcn_s_barrier();
    }

    unsigned short* P = nullptr;
    if (EPI == 4) P = (blockIdx.z == 0) ? p0 : p1;
#pragma unroll
    for (int m = 0; m < 4; ++m) {
#pragma unroll
        for (int n = 0; n < 4; ++n) {
            int row = bm + wr * 64 + m * 16 + g4 * 4;
            int col = bn + wc * 64 + n * 16 + l15;
#pragma unroll
            for (int r = 0; r < 4; ++r) {
                size_t idx = (size_t)(row + r) * N + col;
                float v = acc[m][n][r];
                if (EPI == 0)      ((float*)C)[idx] = v;
                else if (EPI == 1) ((unsigned short*)C)[idx] = f2bf(v);
                else               P[idx] = f2bf(v);
            }
        }
    }
}

// -------- fused gate+up GEMM v2: tile 256M x 96FF, grid 64x8 = 512 ---------
// T1 A-panel-resident remap (kept from R18: measured best-total build).
__global__ __launch_bounds__(512, 2)
void gemm_gu(const unsigned short* __restrict__ A,
             const unsigned short* __restrict__ WGp,
             const unsigned short* __restrict__ WUp,
             unsigned short* __restrict__ OUT) {
    __shared__ unsigned short smem[2][28672];  // 112 KiB

    const int tid  = threadIdx.x;
    const int lane = tid & 63;
    const int l15  = lane & 15;
    const int g4   = lane >> 4;
    const int wid  = tid >> 6;   // 0..7
    const int wr   = wid >> 1;   // 0..3  (64-row slice)
    const int wc   = wid & 1;    // 0..1  (48-col slice)
    const int id   = blockIdx.y * gridDim.x + blockIdx.x;
    const int byl  = id & 7;     // A panel (one per XCD)
    const int bxl  = id >> 3;    // 0..63
    const int bm   = byl * 256;
    const int bn   = bxl * 96;
    const int K    = kHid;
    const int NT   = K >> 6;     // 32
    const int NI   = NT >> 1;

    f32x4 accg[4][3] = {};
    f32x4 accu[4][3] = {};

    constexpr int OFF_A0 = 0;
    constexpr int OFF_A1 = 16384;
    constexpr int OFF_GU = 32768;

    auto stage_a = [&](int b, int half, int t) {
#pragma unroll
        for (int i = 0; i < 2; ++i) {
            int ch   = tid + i * 512;
            int row  = ch >> 3;
            int slot = (ch & 7) ^ (row & 7);
            gload_lds16(A + (size_t)(bm + half * 128 + row) * K + t * 64 + slot * 8,
                        (char*)&smem[b][0] + (half ? OFF_A1 : OFF_A0) + ch * 16);
        }
    };
    auto stage_gu = [&](int b, int t) {
#pragma unroll
        for (int i = 0; i < 3; ++i) {
            int ch   = tid + i * 512;
            int row  = ch >> 3;
            int slot = (ch & 7) ^ (row & 7);
            const unsigned short* Base = (row >= 96) ? WUp : WGp;
            int srow = bn + (row >= 96 ? row - 96 : row);
            gload_lds16(Base + (size_t)srow * K + t * 64 + slot * 8,
                        (char*)&smem[b][0] + OFF_GU + ch * 16);
        }
    };
    auto rdA = [&](int b, int m, int ks) {
        int rt  = wr * 64 + m * 16 + l15;
        int row = rt & 127;
        return *(const bf16x8*)((const char*)&smem[b][0]
               + (rt >> 7 ? OFF_A1 : OFF_A0)
               + row * 128 + (((ks * 4 + g4) ^ (row & 7)) * 16));
    };
    auto rdG = [&](int b, int n, int ks) {
        int row = wc * 48 + n * 16 + l15;
        return *(const bf16x8*)((const char*)&smem[b][0] + OFF_GU
               + row * 128 + (((ks * 4 + g4) ^ (row & 7)) * 16));
    };
    auto rdU = [&](int b, int n, int ks) {
        int row = 96 + wc * 48 + n * 16 + l15;
        return *(const bf16x8*)((const char*)&smem[b][0] + OFF_GU
               + row * 128 + (((ks * 4 + g4) ^ (row & 7)) * 16));
    };

    stage_a(0, 0, 0); stage_a(0, 1, 0); stage_gu(0, 0);
    stage_a(1, 0, 1); stage_a(1, 1, 1);
    asm volatile("s_waitcnt vmcnt(4)" ::: "memory");
    __builtin_amdgcn_s_barrier();

    for (int i = 0; i < NI; ++i) {
        const int e  = 2 * i;
        const int o  = e + 1;
        const bool pf = (e + 2 < NT);
        bf16x8 af[4][2], bg[3][2], bu[3][2];

#pragma unroll
        for (int m = 0; m < 4; ++m) { af[m][0] = rdA(0, m, 0); af[m][1] = rdA(0, m, 1); }
#pragma unroll
        for (int n = 0; n < 3; ++n) { bg[n][0] = rdG(0, n, 0); bg[n][1] = rdG(0, n, 1); }
        stage_gu(1, o);
        __builtin_amdgcn_s_barrier();
        asm volatile("s_waitcnt lgkmcnt(0)" ::: "memory");
        __builtin_amdgcn_sched_barrier(0);
        __builtin_amdgcn_s_setprio(1);
#pragma unroll
        for (int m = 0; m < 4; ++m)
#pragma unroll
            for (int n = 0; n < 3; ++n)
                accg[m][n] = mf(af[m][0], bg[n][0], accg[m][n]);
        __builtin_amdgcn_s_setprio(0);
        __builtin_amdgcn_s_barrier();

        if (pf) stage_a(0, 0, e + 2);
        __builtin_amdgcn_s_barrier();
        __builtin_amdgcn_s_setprio(1);
#pragma unroll
        for (int m = 0; m < 4; ++m)
#pragma unroll
            for (int n = 0; n < 3; ++n)
                accg[m][n] = mf(af[m][1], bg[n][1], accg[m][n]);
        __builtin_amdgcn_s_setprio(0);
        __builtin_amdgcn_s_barrier();

#pragma unroll
        for (int n = 0; n < 3; ++n) { bu[n][0] = rdU(0, n, 0); bu[n][1] = rdU(0, n, 1); }
        if (pf) stage_a(0, 1, e + 2);
        __builtin_amdgcn_s_barrier();
        asm volatile("s_waitcnt lgkmcnt(0)" ::: "memory");
        __builtin_amdgcn_sched_barrier(0);
        __builtin_amdgcn_s_setprio(1);
#pragma unroll
        for (int m = 0; m < 4; ++m)
#pragma unroll
            for (int n = 0; n < 3; ++n)
                accu[m][n] = mf(af[m][0], bu[n][0], accu[m][n]);
        __builtin_amdgcn_s_setprio(0);
        __builtin_amdgcn_s_barrier();

        if (pf) stage_gu(0, e + 2);
        __builtin_amdgcn_s_barrier();
        __builtin_amdgcn_s_setprio(1);
#pragma unroll
        for (int m = 0; m < 4; ++m)
#pragma unroll
            for (int n = 0; n < 3; ++n)
                accu[m][n] = mf(af[m][1], bu[n][1], accu[m][n]);
        __builtin_amdgcn_s_setprio(0);
        if (pf) asm volatile("s_waitcnt vmcnt(7)" ::: "memory");
        else    asm volatile("s_waitcnt vmcnt(0)" ::: "memory");
        __builtin_amdgcn_s_barrier();

#pragma unroll
        for (int m = 0; m < 4; ++m) { af[m][0] = rdA(1, m, 0); af[m][1] = rdA(1, m, 1); }
#pragma unroll
        for (int n = 0; n < 3; ++n) { bg[n][0] = rdG(1, n, 0); bg[n][1] = rdG(1, n, 1); }
        __builtin_amdgcn_s_barrier();
        asm volatile("s_waitcnt lgkmcnt(0)" ::: "memory");
        __builtin_amdgcn_sched_barrier(0);
        __builtin_amdgcn_s_setprio(1);
#pragma unroll
        for (int m = 0; m < 4; ++m)
#pragma unroll
            for (int n = 0; n < 3; ++n)
                accg[m][n] = mf(af[m][0], bg[n][0], accg[m][n]);
        __builtin_amdgcn_s_setprio(0);
        __builtin_amdgcn_s_barrier();

        if (pf) stage_a(1, 0, o + 2);
        __builtin_amdgcn_s_barrier();
        __builtin_amdgcn_s_setprio(1);
#pragma unroll
        for (int m = 0; m < 4; ++m)
#pragma unroll
            for (int n = 0; n < 3; ++n)
                accg[m][n] = mf(af[m][1], bg[n][1], accg[m][n]);
        __builtin_amdgcn_s_setprio(0);
        __builtin_amdgcn_s_barrier();

#pragma unroll
        for (int n = 0; n < 3; ++n) { bu[n][0] = rdU(1, n, 0); bu[n][1] = rdU(1, n, 1); }
        if (pf) stage_a(1, 1, o + 2);
        __builtin_amdgcn_s_barrier();
        asm volatile("s_waitcnt lgkmcnt(0)" ::: "memory");
        __builtin_amdgcn_sched_barrier(0);
        __builtin_amdgcn_s_setprio(1);
#pragma unroll
        for (int m = 0; m < 4; ++m)
#pragma unroll
            for (int n = 0; n < 3; ++n)
                accu[m][n] = mf(af[m][0], bu[n][0], accu[m][n]);
        __builtin_amdgcn_s_setprio(0);
        __builtin_amdgcn_s_barrier();

        __builtin_amdgcn_s_setprio(1);
#pragma unroll
        for (int m = 0; m < 4; ++m)
#pragma unroll
            for (int n = 0; n < 3; ++n)
                accu[m][n] = mf(af[m][1], bu[n][1], accu[m][n]);
        __builtin_amdgcn_s_setprio(0);
        if (pf) asm volatile("s_waitcnt vmcnt(4)" ::: "memory");
        __builtin_amdgcn_s_barrier();
    }

#pragma unroll
    for (int m = 0; m < 4; ++m) {
#pragma unroll
        for (int n = 0; n < 3; ++n) {
            int row = bm + wr * 64 + m * 16 + g4 * 4;
            int col = bn + wc * 48 + n * 16 + l15;
#pragma unroll
            for (int r = 0; r < 4; ++r) {
                float g = accg[m][n][r];
                float u = accu[m][n][r];
                OUT[(size_t)(row + r) * kFF + col] = f2bf(g / (1.0f + __expf(-g)) * u);
            }
        }
    }
}

// Merged post-QKV kernel. Grid (2048, 7):
//   y in [0,6): fused per-head RMSNorm (D=128) + RoPE (j = y*4 + warp)
//   y == 6   : V transpose tile (t0 = (x&63)*32, d0 = (x>>6)*32)
__global__ __launch_bounds__(256)
void qkv_post(const unsigned short* __restrict__ qkv, const int* __restrict__ positions,
              const float* __restrict__ qnw, const float* __restrict__ knw,
              unsigned short* __restrict__ Qo, unsigned short* __restrict__ Ko,
              unsigned short* __restrict__ Vt) {
    __shared__ unsigned short tile[32][33];
    if (blockIdx.y == 6) {
        const int t0 = (blockIdx.x & 63) * 32;
        const int d0 = (blockIdx.x >> 6) * 32;
        const int tc = threadIdx.x & 31;
        const int tr = threadIdx.x >> 5;  // 0..7
#pragma unroll
        for (int i = 0; i < 4; ++i) {
            int trow = tr + i * 8;
            tile[trow][tc] = qkv[(size_t)(t0 + trow) * 4096 + 3072 + d0 + tc];
        }
        __syncthreads();
#pragma unroll
        for (int i = 0; i < 4; ++i) {
            int drow = tr + i * 8;
            Vt[(size_t)(d0 + drow) * kT + t0 + tc] = tile[tc][drow];
        }
        return;
    }
    const int t    = blockIdx.x;
    const int j    = blockIdx.y * 4 + (threadIdx.x >> 6);  // 0..23
    const int lane = threadIdx.x & 63;
    const unsigned short* src = qkv + (size_t)t * 4096 + j * 128;
    float x1 = bf2f(src[lane]);
    float x2 = bf2f(src[lane + 64]);
    float ss = x1 * x1 + x2 * x2;
#pragma unroll
    for (int m = 1; m < 64; m <<= 1) ss += __shfl_xor(ss, m);
    float rs = rsqrtf(ss * (1.0f / 128.0f) + 1e-6f);
    const float* w = (j < 16) ? qnw : knw;
    float n1 = x1 * rs * w[lane];
    float n2 = x2 * rs * w[lane + 64];
    float inv = powf(1.0e6f, -(float)lane * (1.0f / 64.0f));
    float fr = (float)positions[t] * inv;
    float sn, cs;
    sincosf(fr, &sn, &cs);
    float o1 = n1 * cs - n2 * sn;
    float o2 = n2 * cs + n1 * sn;
    if (j < 16) {
        unsigned short* d = Qo + (size_t)t * (kH * kD) + j * kD;
        d[lane] = f2bf(o1);
        d[lane + 64] = f2bf(o2);
    } else {
        unsigned short* d = Ko + (size_t)t * (kHK * kD) + (j - 16) * kD;
        d[lane] = f2bf(o1);
        d[lane + 64] = f2bf(o2);
    }
}

// Causal flash attention v5: kv-split-2 with in-kernel merge (proven R8-R11).
__global__ __launch_bounds__(512, 4)
void attn_fwd5(const unsigned short* __restrict__ Q,   // T x (H*D)
               const unsigned short* __restrict__ Kc,  // T x (HK*D)
               const unsigned short* __restrict__ Vt,  // (HK*D) x T
               unsigned short* __restrict__ O) {       // T x (H*D)
    __shared__ unsigned short Kb[2][64 * 128];
    __shared__ unsigned short Vb[2][128 * 64];
    __shared__ float MergeML[4][2][64];

    const int tid  = threadIdx.x;
    const int lane = tid & 63;
    const int l15  = lane & 15;
    const int g4   = lane >> 4;
    const int wid  = tid >> 6;       // 0..7
    const int s    = wid & 1;        // kv split
    const int grp  = wid >> 1;       // 0..3 = (hs, qsub)
    const int hs   = grp >> 1;
    const int qsub = grp & 1;
    const int hkk  = blockIdx.x;
    const int h    = hkk * 2 + hs;
    const int nby  = gridDim.y;
    const int by   = blockIdx.y;
    const int byl  = (by & 1) ? (nby - 1 - (by >> 1)) : (by >> 1);
    const int q0   = byl * 32 + qsub * 16;
    const int nch  = byl / 2 + 1;
    const int c0   = (nch + 1) >> 1;
    const int myn  = s ? (nch - c0) : c0;
    const int qi   = q0 + l15;
    const int vt   = grp * 64 + lane;

    const int addrA = ((g4 & 1) * 32 + l15) * 4;
    const int addrB = addrA + 64;
    const int addrQ = g4 * 80;
    const bool hb   = (g4 >> 1) != 0;

    bf16x8 qf[4];
#pragma unroll
    for (int ks = 0; ks < 4; ++ks)
        qf[ks] = *(const bf16x8*)(Q + (size_t)(q0 + l15) * (kH * kD) + h * kD + ks * 32 + g4 * 8);

    f32x4 oacc[8] = {};
    float mrun = -3e38f, lrun = 0.f;
    const float scale = 0.08838834764831845f;  // 1/sqrt(128)

    auto stage = [&](int kv0) {
#pragma unroll
        for (int i = 0; i < 4; ++i) {
            int ch  = vt + i * 256;
            int row = ch >> 4;
            int c16 = ch & 15;
            gload_lds16(Kc + (size_t)(kv0 + row) * (kHK * kD) + hkk * kD
                            + ((c16 ^ (row & 7)) * 8),
                        (char*)Kb[s] + ch * 16);
        }
#pragma unroll
        for (int i = 0; i < 4; ++i) {
            int ch  = vt + i * 256;
            int row = ch >> 3;
            int c8  = ch & 7;
            gload_lds16(Vt + (size_t)(hkk * kD + row) * kT + kv0
                            + ((c8 ^ (row & 7)) * 8),
                        (char*)Vb[s] + ch * 16);
        }
    };

    for (int c = 0; c < c0; ++c) {
        const bool act = c < myn;
        const int kv0 = (s ? (c0 + c) : c) * 64;
        if (act) stage(kv0);
        asm volatile("s_waitcnt vmcnt(0)" ::: "memory");
        __builtin_amdgcn_s_barrier();
        __builtin_amdgcn_sched_barrier(0);

        if (act) {
            f32x4 sa[4] = {};
            __builtin_amdgcn_s_setprio(1);
#pragma unroll
            for (int hh = 0; hh < 4; ++hh) {
                const int row = hh * 16 + l15;
#pragma unroll
                for (int ks = 0; ks < 4; ++ks) {
                    bf16x8 kf = *(const bf16x8*)((const char*)Kb[s]
                                  + row * 256 + (((ks * 4 + g4) ^ (row & 7)) * 16));
                    sa[hh] = mf(kf, qf[ks], sa[hh]);
                }
            }
            __builtin_amdgcn_s_setprio(0);

            float sv[4][4];
#pragma unroll
            for (int hh = 0; hh < 4; ++hh)
#pragma unroll
                for (int r = 0; r < 4; ++r)
                    sv[hh][r] = sa[hh][r] * scale;
            if (kv0 + 63 > q0) {
#pragma unroll
                for (int hh = 0; hh < 4; ++hh)
#pragma unroll
                    for (int r = 0; r < 4; ++r) {
                        int ki = kv0 + hh * 16 + g4 * 4 + r;
                        if (ki > qi) sv[hh][r] = -3e38f;
                    }
            }

            float m16;
            {
                float a = fmaxf(fmaxf(sv[0][0], sv[0][1]), fmaxf(sv[0][2], sv[0][3]));
                float b2 = fmaxf(fmaxf(sv[1][0], sv[1][1]), fmaxf(sv[1][2], sv[1][3]));
                float c2 = fmaxf(fmaxf(sv[2][0], sv[2][1]), fmaxf(sv[2][2], sv[2][3]));
                float d2 = fmaxf(fmaxf(sv[3][0], sv[3][1]), fmaxf(sv[3][2], sv[3][3]));
                m16 = fmaxf(fmaxf(a, b2), fmaxf(c2, d2));
            }
            m16 = fmaxf(m16, __shfl_xor(m16, 16));
            m16 = fmaxf(m16, __shfl_xor(m16, 32));

            if (__any(m16 > mrun)) {
                float mnew = fmaxf(mrun, m16);
                float corr = __expf(mrun - mnew);
                mrun = mnew;
                lrun *= corr;
                float cr[4];
#pragma unroll
                for (int r = 0; r < 4; ++r)
                    cr[r] = __int_as_float(__builtin_amdgcn_ds_bpermute(
                                addrQ + 4 * r, __float_as_int(corr)));
#pragma unroll
                for (int c2 = 0; c2 < 8; ++c2)
#pragma unroll
                    for (int r = 0; r < 4; ++r)
                        oacc[c2][r] *= cr[r];
            }

            float p[4][4];
            float ps = 0.f;
#pragma unroll
            for (int hh = 0; hh < 4; ++hh)
#pragma unroll
                for (int r = 0; r < 4; ++r) {
                    float pe = __expf(sv[hh][r] - mrun);
                    p[hh][r] = pe;
                    ps += pe;
                }
            ps += __shfl_xor(ps, 16);
            ps += __shfl_xor(ps, 32);
            lrun += ps;

            unsigned pk[4][2];
#pragma unroll
            for (int hh = 0; hh < 4; ++hh) {
                asm("v_cvt_pk_bf16_f32 %0, %1, %2"
                    : "=v"(pk[hh][0]) : "v"(p[hh][0]), "v"(p[hh][1]));
                asm("v_cvt_pk_bf16_f32 %0, %1, %2"
                    : "=v"(pk[hh][1]) : "v"(p[hh][2]), "v"(p[hh][3]));
            }
            int ex[4][2][2];
#pragma unroll
            for (int hh = 0; hh < 4; ++hh)
#pragma unroll
                for (int ii = 0; ii < 2; ++ii) {
                    ex[hh][ii][0] = __builtin_amdgcn_ds_bpermute(addrA, (int)pk[hh][ii]);
                    ex[hh][ii][1] = __builtin_amdgcn_ds_bpermute(addrB, (int)pk[hh][ii]);
                }
            union { int w[4]; bf16x8 v; } pu0, pu1;
#pragma unroll
            for (int jw = 0; jw < 4; ++jw) {
                pu0.w[jw] = hb ? ex[1][jw & 1][jw >> 1] : ex[0][jw & 1][jw >> 1];
                pu1.w[jw] = hb ? ex[3][jw & 1][jw >> 1] : ex[2][jw & 1][jw >> 1];
            }
            bf16x8 pa0 = pu0.v;
            bf16x8 pa1 = pu1.v;

            __builtin_amdgcn_s_setprio(1);
#pragma unroll
            for (int c2 = 0; c2 < 8; ++c2) {
                const int d = c2 * 16 + l15;
                bf16x8 vf0 = *(const bf16x8*)((const char*)Vb[s]
                              + d * 128 + ((g4 ^ (d & 7)) * 16));
                oacc[c2] = mf(pa0, vf0, oacc[c2]);
                bf16x8 vf1 = *(const bf16x8*)((const char*)Vb[s]
                              + d * 128 + ((((4 + g4) ^ (d & 7))) * 16));
                oacc[c2] = mf(pa1, vf1, oacc[c2]);
            }
            __builtin_amdgcn_s_setprio(0);
        }
        __builtin_amdgcn_s_barrier();
    }

    float* KbF = (float*)&Kb[0][0];
    if (s == 1) {
        MergeML[grp][0][lane] = mrun;
        MergeML[grp][1][lane] = lrun;
#pragma unroll
        for (int c2 = 0; c2 < 8; ++c2)
#pragma unroll
            for (int r = 0; r < 4; ++r)
                KbF[grp * 2048 + (c2 * 4 + r) * 64 + lane] = oacc[c2][r];
    }
    asm volatile("s_waitcnt lgkmcnt(0)" ::: "memory");
    __builtin_amdgcn_s_barrier();

    if (s == 0) {
        float m1 = MergeML[grp][0][lane];
        float l1 = MergeML[grp][1][lane];
        float mg = fmaxf(mrun, m1);
        float a0 = __expf(mrun - mg);
        float a1 = __expf(m1 - mg);
        float L  = lrun * a0 + l1 * a1;
        float ar0[4], ar1[4], Lr[4];
#pragma unroll
        for (int r = 0; r < 4; ++r) {
            ar0[r] = __int_as_float(__builtin_amdgcn_ds_bpermute(
                         addrQ + 4 * r, __float_as_int(a0)));
            ar1[r] = __int_as_float(__builtin_amdgcn_ds_bpermute(
                         addrQ + 4 * r, __float_as_int(a1)));
            Lr[r]  = __int_as_float(__builtin_amdgcn_ds_bpermute(
                         addrQ + 4 * r, __float_as_int(L)));
        }
#pragma unroll
        for (int c2 = 0; c2 < 8; ++c2)
#pragma unroll
            for (int r = 0; r < 4; ++r) {
                float oex = KbF[grp * 2048 + (c2 * 4 + r) * 64 + lane];
                float v = (oacc[c2][r] * ar0[r] + oex * ar1[r]) / Lr[r];
                O[(size_t)(q0 + g4 * 4 + r) * (kH * kD) + h * kD + c2 * 16 + l15] = f2bf(v);
            }
    }
}

}  // namespace

extern "C" void kernel_launch(void* const* d_in, const int* in_sizes, int n_in,
                              void* d_out, int out_size, void* d_ws, size_t ws_size,
                              hipStream_t stream) {
    (void)in_sizes; (void)n_in; (void)out_size; (void)ws_size;

    const int*   positions = (const int*)  d_in[0];
    const float* hidden    = (const float*)d_in[1];
    const float* wq  = (const float*)d_in[2];
    const float* wk  = (const float*)d_in[3];
    const float* wv  = (const float*)d_in[4];
    const float* wo  = (const float*)d_in[5];
    const float* qnw = (const float*)d_in[6];
    const float* knw = (const float*)d_in[7];
    const float* ln1 = (const float*)d_in[8];
    const float* ln2 = (const float*)d_in[9];
    const float* wg  = (const float*)d_in[10];
    const float* wu  = (const float*)d_in[11];
    const float* wd  = (const float*)d_in[12];

    char* ws = (char*)d_ws;
    unsigned short* WQKV = (unsigned short*)(ws + 0);          // 4096x2048 bf16
    unsigned short* WO   = (unsigned short*)(ws + 16777216);   // 2048x2048
    unsigned short* WG   = (unsigned short*)(ws + 25165824);   // 6144x2048
    unsigned short* WU   = (unsigned short*)(ws + 50331648);   // 6144x2048
    unsigned short* WD   = (unsigned short*)(ws + 75497472);   // 2048x6144
    unsigned short* XN1  = (unsigned short*)(ws + 100663296);  // T x 2048
    unsigned short* OATT = (unsigned short*)(ws + 109051904);  // T x 2048
    float*          H1   = (float*)(ws + 117440512);           // T x 2048 fp32
    unsigned short* XN2  = (unsigned short*)(ws + 134217728);  // T x 2048
    unsigned short* QKVB = (unsigned short*)(ws + 142606336);  // T x 4096 bf16
    unsigned short* QB   = (unsigned short*)(ws + 176160768);  // T x 2048
    unsigned short* KB   = (unsigned short*)(ws + 184549376);  // T x 1024
    unsigned short* VT   = (unsigned short*)(ws + 188743680);  // 1024 x T
    unsigned short* ACT  = (unsigned short*)(ws + 167772160);  // T x 6144

    // O-proj split-K2 bf16 partials (8 MB each; QKVB span dead then)
    unsigned short* OP0 = (unsigned short*)(ws + 142606336);
    unsigned short* OP1 = (unsigned short*)(ws + 159383552);
    // down split-K4 bf16 partials (8 MB each; dead regions audited)
    unsigned short* DP0 = (unsigned short*)(ws + 0);
    unsigned short* DP1 = (unsigned short*)(ws + 16777216);
    unsigned short* DP2 = (unsigned short*)(ws + 33554432);
    unsigned short* DP3 = (unsigned short*)(ws + 142606336);

    // fused weight conversion, grid-stride (4096 blocks x 12 float4/thread)
    cvt_all<<<dim3(4096), dim3(256), 0, stream>>>(
        wq, wk, wv, wo, wg, wu, wd, (ushort4*)ws);

    rmsnorm_k<<<dim3(kT), dim3(256), 0, stream>>>(hidden, ln1, XN1);

    // QKV GEMM: 128x256 tile, grid 16x16 = 256 exact, bf16 output
    gemm128<1><<<dim3(4096 / 256, kT / 128), dim3(512), 0, stream>>>(
        XN1, WQKV, QKVB, kT, 4096, kHid, kHid, nullptr, nullptr);

    // merged qk-norm+rope (y<6) and V-transpose (y==6)
    qkv_post<<<dim3(kT, 7), dim3(256), 0, stream>>>(
        QKVB, positions, qnw, knw, QB, KB, VT);

    attn_fwd5<<<dim3(kHK, kT / 32), dim3(512), 0, stream>>>(QB, KB, VT, OATT);

    // O-proj: 128x256 split-K2 (grid 8x16x2 = 256 exact) -> bf16 partials
    gemm128<4><<<dim3(kHid / 256, kT / 128, 2), dim3(512), 0, stream>>>(
        OATT, WO, nullptr, kT, kHid, kHid, 1024, OP0, OP1);
    // fused: H1 = p0+p1+hidden; XN2 = rmsnorm(H1)*ln2
    rmsnorm_red2b<<<dim3(kT), dim3(256), 0, stream>>>(
        OP0, OP1, hidden, ln2, H1, XN2);

    // fused gate+up GEMM: 256x96 tile, grid 64x8 = 512 (A-panel XCD swizzle)
    gemm_gu<<<dim3(kFF / 96, kT / 256), dim3(512), 0, stream>>>(XN2, WG, WU, ACT);

    // down: 256x256 split-K4 (KS=1536, grid 8x8x4 = 256 exact) -> bf16 partials
    gemm256<4><<<dim3(kHid / 256, kT / 256, 4), dim3(512), 0, stream>>>(
        ACT, WD, nullptr, kT, kHid, kFF, 1536, DP0, DP1, DP2, DP3);
    reduce4b<<<dim3(kT * kHid / 8 / 256), dim3(256), 0, stream>>>(
        (const unsigned int*)DP0, (const unsigned int*)DP1,
        (const unsigned int*)DP2, (const unsigned int*)DP3,
        H1, (float*)d_out, kT * kHid / 8);
}